// Round 2
// baseline (421.911 us; speedup 1.0000x reference)
//
#include <hip/hip_runtime.h>
#include <math.h>

#define NS 10000
#define LSEQ 32
#define DDIM 300
#define HDIM 300
#define BB 256
#define NMAX 128
#define MMAX 128
#define EPSR 0.1f
#define SITERS 50
#define KPAD 320
#define NPADW 384

typedef __attribute__((ext_vector_type(8))) short bf16x8;
typedef __attribute__((ext_vector_type(4))) float f32x4;

__device__ __forceinline__ ushort f2bf(float x) {
  union { float f; unsigned u; } c; c.f = x;
  unsigned r = (c.u + 0x7fffu + ((c.u >> 16) & 1u)) >> 16;
  return (ushort)r;
}
__device__ __forceinline__ float bf2f(ushort h) {
  union { unsigned u; float f; } c; c.u = ((unsigned)h) << 16;
  return c.f;
}

// ------- K1: embedding + masked mean pool -> enc hi/lo [NS][KPAD] bf16 -----
__global__ __launch_bounds__(256) void k_embed(const int* __restrict__ data,
                                               const float* __restrict__ emb,
                                               ushort* __restrict__ enchi,
                                               ushort* __restrict__ enclo) {
  __shared__ int ids[LSEQ];
  __shared__ __align__(16) float4 part[3][76];
  int s = blockIdx.x;
  int tid = threadIdx.x;
  if (tid < LSEQ) ids[tid] = data[s * LSEQ + tid];
  __syncthreads();
  int cnt = 0;
#pragma unroll
  for (int t = 0; t < LSEQ; ++t) cnt += (ids[t] != 0) ? 1 : 0;
  int g = tid / 75, d = tid - g * 75;
  const float4* emb4 = (const float4*)emb;
  if (g < 3) {
    float4 acc = make_float4(0.f, 0.f, 0.f, 0.f);
    for (int t = g; t < LSEQ; t += 3) {
      int id = ids[t];
      if (id != 0) {
        float4 e = emb4[(size_t)id * 75 + d];
        acc.x += e.x; acc.y += e.y; acc.z += e.z; acc.w += e.w;
      }
    }
    part[g][d] = acc;
  }
  __syncthreads();
  if (g == 0) {
    float4 a = part[0][d], b = part[1][d], c = part[2][d];
    float inv = 1.f / (float)(cnt > 0 ? cnt : 1);
    float v[4] = {(a.x + b.x + c.x) * inv, (a.y + b.y + c.y) * inv,
                  (a.z + b.z + c.z) * inv, (a.w + b.w + c.w) * inv};
    ushort4 h, l;
    h.x = f2bf(v[0]); l.x = f2bf(v[0] - bf2f(h.x));
    h.y = f2bf(v[1]); l.y = f2bf(v[1] - bf2f(h.y));
    h.z = f2bf(v[2]); l.z = f2bf(v[2] - bf2f(h.z));
    h.w = f2bf(v[3]); l.w = f2bf(v[3] - bf2f(h.w));
    *(ushort4*)&enchi[(size_t)s * KPAD + d * 4] = h;
    *(ushort4*)&enclo[(size_t)s * KPAD + d * 4] = l;
  } else if (g == 1 && d < 5) {
    ushort4 z; z.x = z.y = z.z = z.w = 0;
    *(ushort4*)&enchi[(size_t)s * KPAD + 300 + d * 4] = z;
    *(ushort4*)&enclo[(size_t)s * KPAD + 300 + d * 4] = z;
  }
}

// ------- K2: all weight converts in one dispatch ---------------------------
__global__ __launch_bounds__(256) void k_cvt_all(
    const float* __restrict__ W1, const float* __restrict__ W2,
    const float* __restrict__ Wc, ushort* __restrict__ W1hi,
    ushort* __restrict__ W1lo, ushort* __restrict__ W2hi,
    ushort* __restrict__ W2lo, ushort* __restrict__ Wchi,
    ushort* __restrict__ Wclo) {
  int i = blockIdx.x * 256 + threadIdx.x;
  const int SA = NPADW * KPAD;
  const int SC = 640 * KPAD;
  float v = 0.f;
  ushort *ph, *pl;
  int idx;
  if (i < SA) {
    idx = i;
    int n = idx / KPAD, k = idx - n * KPAD;
    if (n < HDIM && k < DDIM) v = W1[(size_t)k * HDIM + n];
    ph = W1hi; pl = W1lo;
  } else if (i < 2 * SA) {
    idx = i - SA;
    int n = idx / KPAD, k = idx - n * KPAD;
    if (n < HDIM && k < HDIM) v = W2[(size_t)k * HDIM + n];
    ph = W2hi; pl = W2lo;
  } else if (i < 2 * SA + SC) {
    idx = i - 2 * SA;
    int n = idx / KPAD, k = idx - n * KPAD;
    if (k < HDIM && n < 2 * HDIM)
      v = (n < HDIM) ? Wc[(size_t)k * HDIM + n]
                     : Wc[(size_t)(HDIM + k) * HDIM + (n - HDIM)];
    ph = Wchi; pl = Wclo;
  } else {
    return;
  }
  ushort h = f2bf(v);
  ph[idx] = h;
  pl[idx] = f2bf(v - bf2f(h));
}

// ------- K3: MFMA GEMM, hi/lo 3-term, 64x128 tile, wave = 32x64 ------------
__global__ __launch_bounds__(256) void k_gemm_mfma(
    const ushort* __restrict__ Ahi, const ushort* __restrict__ Alo,
    const ushort* __restrict__ BhiT, const ushort* __restrict__ BloT,
    const float* __restrict__ bias, int M, int N, int relu,
    float* __restrict__ Cf, ushort* __restrict__ Chi,
    ushort* __restrict__ Clo) {
  __shared__ __align__(16) ushort ldsA[2][64][40];
  __shared__ __align__(16) ushort ldsB[2][128][40];
  int tid = threadIdx.x;
  int m0 = blockIdx.x * 64, n0 = blockIdx.y * 128;
  int rowA = tid >> 2, chA = (tid & 3) * 8;
  int rowB = tid >> 1, chB = (tid & 1) * 16;
  bool mok = (m0 + rowA) < M;
  const ushort* pAh = Ahi + (size_t)(m0 + rowA) * KPAD + chA;
  const ushort* pAl = Alo + (size_t)(m0 + rowA) * KPAD + chA;
  const ushort* pBh = BhiT + (size_t)(n0 + rowB) * KPAD + chB;
  const ushort* pBl = BloT + (size_t)(n0 + rowB) * KPAD + chB;
  uint4 rAh, rAl, rBh0, rBh1, rBl0, rBl1;
  uint4 z4; z4.x = z4.y = z4.z = z4.w = 0;
  auto ld = [&](int c) {
    int o = c * 32;
    rAh = mok ? *(const uint4*)(pAh + o) : z4;
    rAl = mok ? *(const uint4*)(pAl + o) : z4;
    rBh0 = *(const uint4*)(pBh + o);
    rBh1 = *(const uint4*)(pBh + o + 8);
    rBl0 = *(const uint4*)(pBl + o);
    rBl1 = *(const uint4*)(pBl + o + 8);
  };
  auto st = [&]() {
    *(uint4*)&ldsA[0][rowA][chA] = rAh;
    *(uint4*)&ldsA[1][rowA][chA] = rAl;
    *(uint4*)&ldsB[0][rowB][chB] = rBh0;
    *(uint4*)&ldsB[0][rowB][chB + 8] = rBh1;
    *(uint4*)&ldsB[1][rowB][chB] = rBl0;
    *(uint4*)&ldsB[1][rowB][chB + 8] = rBl1;
  };
  int w = tid >> 6, lane = tid & 63;
  int q = lane >> 4, l16 = lane & 15;
  int mh = w >> 1, nh = w & 1;
  f32x4 zf = {0.f, 0.f, 0.f, 0.f};
  f32x4 acc[2][4];
#pragma unroll
  for (int s = 0; s < 2; ++s)
#pragma unroll
    for (int t = 0; t < 4; ++t) acc[s][t] = zf;
  ld(0); st(); __syncthreads();
  for (int c = 0; c < 10; ++c) {
    if (c < 9) ld(c + 1);
    bf16x8 ah0 = *(const bf16x8*)&ldsA[0][mh * 32 + l16][q * 8];
    bf16x8 ah1 = *(const bf16x8*)&ldsA[0][mh * 32 + 16 + l16][q * 8];
    bf16x8 al0 = *(const bf16x8*)&ldsA[1][mh * 32 + l16][q * 8];
    bf16x8 al1 = *(const bf16x8*)&ldsA[1][mh * 32 + 16 + l16][q * 8];
#pragma unroll
    for (int t = 0; t < 4; ++t) {
      int brow = nh * 64 + t * 16 + l16;
      bf16x8 bh = *(const bf16x8*)&ldsB[0][brow][q * 8];
      bf16x8 bl = *(const bf16x8*)&ldsB[1][brow][q * 8];
      acc[0][t] = __builtin_amdgcn_mfma_f32_16x16x32_bf16(ah0, bh, acc[0][t], 0, 0, 0);
      acc[0][t] = __builtin_amdgcn_mfma_f32_16x16x32_bf16(ah0, bl, acc[0][t], 0, 0, 0);
      acc[0][t] = __builtin_amdgcn_mfma_f32_16x16x32_bf16(al0, bh, acc[0][t], 0, 0, 0);
      acc[1][t] = __builtin_amdgcn_mfma_f32_16x16x32_bf16(ah1, bh, acc[1][t], 0, 0, 0);
      acc[1][t] = __builtin_amdgcn_mfma_f32_16x16x32_bf16(ah1, bl, acc[1][t], 0, 0, 0);
      acc[1][t] = __builtin_amdgcn_mfma_f32_16x16x32_bf16(al1, bh, acc[1][t], 0, 0, 0);
    }
    __syncthreads();
    if (c < 9) st();
    __syncthreads();
  }
#pragma unroll
  for (int t = 0; t < 4; ++t) {
    int n = n0 + nh * 64 + t * 16 + l16;
    bool nin = n < N;
    float bz = (bias && nin) ? bias[n] : 0.f;
#pragma unroll
    for (int s = 0; s < 2; ++s) {
#pragma unroll
      for (int r = 0; r < 4; ++r) {
        int m = m0 + mh * 32 + s * 16 + q * 4 + r;
        if (m >= M) continue;
        float v = acc[s][t][r] + bz;
        if (relu) v = v > 0.f ? v : 0.f;
        if (Cf && nin) Cf[(size_t)m * N + n] = v;
        if (Chi && n < KPAD) {
          ushort h = 0, l = 0;
          if (nin) { h = f2bf(v); l = f2bf(v - bf2f(h)); }
          Chi[(size_t)m * KPAD + n] = h;
          Clo[(size_t)m * KPAD + n] = l;
        }
      }
    }
  }
}

// --- K4: normalize henc (hi/lo) -> hn hi/lo [NS][KPAD] (unit rows) ---------
__global__ __launch_bounds__(256) void k_norm_split(
    const ushort* __restrict__ hehi, const ushort* __restrict__ helo,
    ushort* __restrict__ hnhi, ushort* __restrict__ hnlo) {
  int s = blockIdx.x * 4 + (threadIdx.x >> 6);
  int lane = threadIdx.x & 63;
  if (s >= NS) return;
  const ushort* ph = hehi + (size_t)s * KPAD;
  const ushort* pl = helo + (size_t)s * KPAD;
  float x[5];
  float ss = 0.f;
#pragma unroll
  for (int q = 0; q < 5; ++q) {
    int d = lane + q * 64;
    x[q] = bf2f(ph[d]) + bf2f(pl[d]);
    ss += x[q] * x[q];
  }
#pragma unroll
  for (int off = 32; off > 0; off >>= 1) ss += __shfl_down(ss, off, 64);
  ss = __shfl(ss, 0, 64);
  float inv = 1.f / (sqrtf(ss) + 1e-8f);
  ushort* qh = hnhi + (size_t)s * KPAD;
  ushort* ql = hnlo + (size_t)s * KPAD;
#pragma unroll
  for (int q = 0; q < 5; ++q) {
    int d = lane + q * 64;
    float v = x[q] * inv;
    ushort h = f2bf(v);
    qh[d] = h;
    ql[d] = f2bf(v - bf2f(h));
  }
}

// --- K5: cost as gathered MFMA GEMM (hn·hn^T) + fused exp, wave = 32x32 ----
__global__ __launch_bounds__(256) void k_cost_mfma(
    const ushort* __restrict__ hnhi, const ushort* __restrict__ hnlo,
    const int* __restrict__ ridx, const int* __restrict__ cidx,
    const int* __restrict__ rlen, const int* __restrict__ clen,
    float* __restrict__ Kmat) {
  int b = blockIdx.z;
  int r0 = blockIdx.x * 64, c0 = blockIdx.y * 64;
  int rl = rlen[b], cl = clen[b];
  float* Kg = Kmat + (size_t)b * NMAX * MMAX;
  int tid = threadIdx.x;
  if (r0 >= rl || c0 >= cl) {
    for (int l = tid; l < 64 * 16; l += 256) {
      int i = l >> 4, j = (l & 15) << 2;
      *(float4*)&Kg[(size_t)(r0 + i) * MMAX + c0 + j] =
          make_float4(0.f, 0.f, 0.f, 0.f);
    }
    return;
  }
  __shared__ int rix[64], cix[64];
  __shared__ __align__(16) ushort lds[4][64][40];  // Rhi,Rlo,Chi,Clo
  if (tid < 64) rix[tid] = ridx[b * NMAX + r0 + tid];
  else if (tid < 128) cix[tid - 64] = cidx[b * MMAX + c0 + tid - 64];
  __syncthreads();
  int row = tid >> 2, ch = tid & 3;
  const ushort* pRh = hnhi + (size_t)rix[row] * KPAD + ch * 8;
  const ushort* pRl = hnlo + (size_t)rix[row] * KPAD + ch * 8;
  const ushort* pCh = hnhi + (size_t)cix[row] * KPAD + ch * 8;
  const ushort* pCl = hnlo + (size_t)cix[row] * KPAD + ch * 8;
  uint4 rRh, rRl, rCh, rCl;
  auto ld = [&](int c) {
    int o = c * 32;
    rRh = *(const uint4*)(pRh + o);
    rRl = *(const uint4*)(pRl + o);
    rCh = *(const uint4*)(pCh + o);
    rCl = *(const uint4*)(pCl + o);
  };
  auto st = [&]() {
    *(uint4*)&lds[0][row][ch * 8] = rRh;
    *(uint4*)&lds[1][row][ch * 8] = rRl;
    *(uint4*)&lds[2][row][ch * 8] = rCh;
    *(uint4*)&lds[3][row][ch * 8] = rCl;
  };
  int w = tid >> 6, lane = tid & 63;
  int q = lane >> 4, l16 = lane & 15;
  int mh = w >> 1, nh = w & 1;
  f32x4 zf = {0.f, 0.f, 0.f, 0.f};
  f32x4 acc[2][2];
#pragma unroll
  for (int s = 0; s < 2; ++s)
#pragma unroll
    for (int t = 0; t < 2; ++t) acc[s][t] = zf;
  ld(0); st(); __syncthreads();
  for (int c = 0; c < 10; ++c) {
    if (c < 9) ld(c + 1);
    bf16x8 ah0 = *(const bf16x8*)&lds[0][mh * 32 + l16][q * 8];
    bf16x8 ah1 = *(const bf16x8*)&lds[0][mh * 32 + 16 + l16][q * 8];
    bf16x8 al0 = *(const bf16x8*)&lds[1][mh * 32 + l16][q * 8];
    bf16x8 al1 = *(const bf16x8*)&lds[1][mh * 32 + 16 + l16][q * 8];
#pragma unroll
    for (int t = 0; t < 2; ++t) {
      int brow = nh * 32 + t * 16 + l16;
      bf16x8 bh = *(const bf16x8*)&lds[2][brow][q * 8];
      bf16x8 bl = *(const bf16x8*)&lds[3][brow][q * 8];
      acc[0][t] = __builtin_amdgcn_mfma_f32_16x16x32_bf16(ah0, bh, acc[0][t], 0, 0, 0);
      acc[0][t] = __builtin_amdgcn_mfma_f32_16x16x32_bf16(ah0, bl, acc[0][t], 0, 0, 0);
      acc[0][t] = __builtin_amdgcn_mfma_f32_16x16x32_bf16(al0, bh, acc[0][t], 0, 0, 0);
      acc[1][t] = __builtin_amdgcn_mfma_f32_16x16x32_bf16(ah1, bh, acc[1][t], 0, 0, 0);
      acc[1][t] = __builtin_amdgcn_mfma_f32_16x16x32_bf16(ah1, bl, acc[1][t], 0, 0, 0);
      acc[1][t] = __builtin_amdgcn_mfma_f32_16x16x32_bf16(al1, bh, acc[1][t], 0, 0, 0);
    }
    __syncthreads();
    if (c < 9) st();
    __syncthreads();
  }
#pragma unroll
  for (int t = 0; t < 2; ++t) {
    int n = c0 + nh * 32 + t * 16 + l16;
#pragma unroll
    for (int s = 0; s < 2; ++s) {
#pragma unroll
      for (int r = 0; r < 4; ++r) {
        int m = r0 + mh * 32 + s * 16 + q * 4 + r;
        float kv = (m < rl && n < cl) ? expf((acc[s][t][r] - 1.f) / EPSR) : 0.f;
        Kg[(size_t)m * MMAX + n] = kv;
      }
    }
  }
}

// --------- K6: Sinkhorn, K held in VGPRs (kr row / kt col slices) ----------
__global__ __launch_bounds__(512) void k_sinkhorn(
    float* __restrict__ Kmat, const int* __restrict__ rlen,
    const int* __restrict__ clen) {
  __shared__ __align__(16) float vq[4][36];
  __shared__ __align__(16) float uq[4][36];
  int b = blockIdx.x;
  int tid = threadIdx.x;
  int n = tid >> 2, q = tid & 3;
  int rl = rlen[b], cl = clen[b];
  float* Kg = Kmat + (size_t)b * NMAX * MMAX;
  float kr[32], kt[32];
  const float4* Kg4 = (const float4*)(Kg + (size_t)n * MMAX + 32 * q);
#pragma unroll
  for (int t = 0; t < 8; ++t) *(float4*)&kr[4 * t] = Kg4[t];
#pragma unroll
  for (int j = 0; j < 32; ++j) kt[j] = Kg[(size_t)(32 * q + j) * MMAX + n];
  if (tid < 128) vq[tid >> 5][tid & 31] = (tid < cl) ? 1.f : 0.f;
  float av = (n < rl) ? 1.f / (float)rl : 0.f;
  float bv = (n < cl) ? 1.f / (float)cl : 0.f;
  float un = 0.f;
  __syncthreads();
  for (int it = 0; it < SITERS; ++it) {
    float s = 0.f;
#pragma unroll
    for (int t = 0; t < 8; ++t) {
      float4 vv = *(const float4*)&vq[q][4 * t];
      s += kr[4 * t + 0] * vv.x + kr[4 * t + 1] * vv.y +
           kr[4 * t + 2] * vv.z + kr[4 * t + 3] * vv.w;
    }
    s += __shfl_xor(s, 1, 64);
    s += __shfl_xor(s, 2, 64);
    un = (n < rl) ? av / s : 0.f;
    if (q == 0) uq[n >> 5][n & 31] = un;
    __syncthreads();
    float s2 = 0.f;
#pragma unroll
    for (int t = 0; t < 8; ++t) {
      float4 uu = *(const float4*)&uq[q][4 * t];
      s2 += kt[4 * t + 0] * uu.x + kt[4 * t + 1] * uu.y +
            kt[4 * t + 2] * uu.z + kt[4 * t + 3] * uu.w;
    }
    s2 += __shfl_xor(s2, 1, 64);
    s2 += __shfl_xor(s2, 2, 64);
    float vm = (n < cl) ? bv / s2 : 0.f;
    if (q == 0) vq[n >> 5][n & 31] = vm;
    __syncthreads();
  }
  float4* Pg4 = (float4*)(Kg + (size_t)n * MMAX + 32 * q);
#pragma unroll
  for (int t = 0; t < 8; ++t) {
    float4 vv = *(const float4*)&vq[q][4 * t];
    float4 p;
    p.x = un * kr[4 * t + 0] * vv.x;
    p.y = un * kr[4 * t + 1] * vv.y;
    p.z = un * kr[4 * t + 2] * vv.z;
    p.w = un * kr[4 * t + 3] * vv.w;
    Pg4[t] = p;
  }
}

// ---- K7: attend + compare + masked sum; burst-issue register staging ------
// R1 rewrite: G (gathered HcB attended-part rows) loaded ONCE per block into
// regs (<=32/thread, reused across mt — was re-fetched per mt); P + main rows
// for a whole mt burst-issued (<=48 outstanding loads/thread) so the ~900cy
// gather miss latency is paid once per mt, not once per 16-wide k-step.
// Inner loop is pure regs->LDS->FMA with one barrier per step.
__global__ __launch_bounds__(256) void k_att_cmp_both(
    const float* __restrict__ P, const float* __restrict__ HcB,
    const int* __restrict__ row_idx, const int* __restrict__ col_idx,
    const int* __restrict__ row_len, const int* __restrict__ col_len,
    const float* __restrict__ bc, float* __restrict__ cr,
    float* __restrict__ cc) {
  int b = blockIdx.y;
  int side = blockIdx.z;
  int c0 = blockIdx.x * 64;
  const int* idx_main = side == 0 ? row_idx : col_idx;
  const int* idx_other = side == 0 ? col_idx : row_idx;
  int lm = side == 0 ? row_len[b] : col_len[b];
  int lo = side == 0 ? col_len[b] : row_len[b];
  float* outacc = side == 0 ? cr : cc;
  __shared__ __align__(16) float smem[2][2][16][68];  // [buf][P|G]
  __shared__ int iox[NMAX];
  __shared__ int imx[NMAX];
  int tid = threadIdx.x, tx = tid & 15, ty = tid >> 4;
  int jj = tid & 63, kq = tid >> 6;
  if (tid < 128) iox[tid] = idx_other[b * NMAX + tid];
  else imx[tid - 128] = idx_main[b * NMAX + tid - 128];
  __syncthreads();
  const float* Pb = P + (size_t)b * NMAX * MMAX;
  bool cok = (c0 + jj) < HDIM;
  int nkc = (lo + 15) >> 4;
  int nmt = (lm + 63) >> 6;
  // bias regs (guarded scalar loads; bc has only HDIM entries)
  float bb[4];
#pragma unroll
  for (int j = 0; j < 4; ++j) {
    int col = c0 + tx * 4 + j;
    bb[j] = (col < HDIM) ? bc[col] : 0.f;
  }
  // ---- G burst: all kc slices once per block (persist across mt) ----
  float gReg[8][4];
#pragma unroll
  for (int kc = 0; kc < 8; ++kc) {
    if (kc < nkc) {
#pragma unroll
      for (int p = 0; p < 4; ++p) {
        int row = iox[kc * 16 + kq + p * 4];
        gReg[kc][p] = cok ? HcB[(size_t)row * 600 + 300 + c0 + jj] : 0.f;
      }
    }
  }
  float pReg[8][4];
  float4 m4[4];
  auto loadP = [&](int mt) {
    int m0 = mt * 64;
#pragma unroll
    for (int kc = 0; kc < 8; ++kc) {
      if (kc < nkc) {
        if (side == 0) {
#pragma unroll
          for (int p = 0; p < 4; ++p)
            pReg[kc][p] = Pb[(size_t)(m0 + ty + p * 16) * MMAX + kc * 16 + tx];
        } else {
#pragma unroll
          for (int p = 0; p < 4; ++p)
            pReg[kc][p] = Pb[(size_t)(kc * 16 + kq + p * 4) * MMAX + m0 + jj];
        }
      }
    }
  };
  auto loadMain = [&](int mt) {
#pragma unroll
    for (int i = 0; i < 4; ++i) {
      int mi = mt * 64 + ty * 4 + i;
      int hrow = imx[mi];
      m4[i] = *(const float4*)&HcB[(size_t)hrow * 600 + c0 + tx * 4];
    }
  };
  loadP(0);
  loadMain(0);
  float colsum[4] = {0.f, 0.f, 0.f, 0.f};
  for (int mt = 0; mt < nmt; ++mt) {
    float acc[4][4] = {};
#pragma unroll
    for (int kc = 0; kc < 8; ++kc) {
      if (kc < nkc) {
        int buf = kc & 1;
        if (side == 0) {
#pragma unroll
          for (int p = 0; p < 4; ++p)
            smem[buf][0][tx][ty + p * 16] = pReg[kc][p];
        } else {
#pragma unroll
          for (int p = 0; p < 4; ++p)
            smem[buf][0][kq + p * 4][jj] = pReg[kc][p];
        }
#pragma unroll
        for (int p = 0; p < 4; ++p) smem[buf][1][kq + p * 4][jj] = gReg[kc][p];
        __syncthreads();
#pragma unroll
        for (int kk = 0; kk < 16; ++kk) {
          float4 av = *(const float4*)&smem[buf][0][kk][ty * 4];
          float4 gv = *(const float4*)&smem[buf][1][kk][tx * 4];
          float a[4] = {av.x, av.y, av.z, av.w};
          float g[4] = {gv.x, gv.y, gv.z, gv.w};
#pragma unroll
          for (int i = 0; i < 4; ++i)
#pragma unroll
            for (int j = 0; j < 4; ++j) acc[i][j] += a[i] * g[j];
        }
      }
    }
    // prefetch next mt's P (pReg dead after stores above)
    if (mt + 1 < nmt) loadP(mt + 1);
    // epilogue for this mt (uses m4 of current mt)
#pragma unroll
    for (int i = 0; i < 4; ++i) {
      int mi = mt * 64 + ty * 4 + i;
      if (mi >= lm) continue;
#pragma unroll
      for (int j = 0; j < 4; ++j) {
        int col = c0 + tx * 4 + j;
        if (col >= HDIM) continue;
        float mv = (&m4[i].x)[j];
        float y = acc[i][j] + mv + bb[j];
        colsum[j] += y > 0.f ? y : 0.f;
      }
    }
    if (mt + 1 < nmt) loadMain(mt + 1);
    __syncthreads();  // wrap hazard: next mt's kc=0 store reuses buf0
  }
  float(*red)[68] = (float(*)[68]) & smem[0][0][0][0];
#pragma unroll
  for (int j = 0; j < 4; ++j) red[ty][tx * 4 + j] = colsum[j];
  __syncthreads();
  if (tid < 64) {
    float s = 0.f;
#pragma unroll
    for (int r = 0; r < 16; ++r) s += red[r][tid];
    int col = c0 + tid;
    if (col < HDIM) outacc[(size_t)b * HDIM + col] = s;
  }
}

// ---------------- K8: classifier head -> out [B,2] -------------------------
__global__ __launch_bounds__(320) void k_cls(
    const float* __restrict__ cr, const float* __restrict__ cc,
    const float* __restrict__ Wcls, const float* __restrict__ bcls,
    const float* __restrict__ Wout, const float* __restrict__ bout,
    float* __restrict__ out) {
  __shared__ __align__(16) float cz[2 * HDIM];
  __shared__ float zz[HDIM];
  int b = blockIdx.x, tid = threadIdx.x;
  if (tid < HDIM) {
    cz[tid] = cr[(size_t)b * HDIM + tid];
    cz[HDIM + tid] = cc[(size_t)b * HDIM + tid];
  }
  __syncthreads();
  if (tid < HDIM) {
    float acc = bcls[tid];
    for (int k4 = 0; k4 < 2 * HDIM; k4 += 4) {
      float4 c = *(const float4*)&cz[k4];
      acc += c.x * Wcls[(size_t)(k4 + 0) * HDIM + tid] +
             c.y * Wcls[(size_t)(k4 + 1) * HDIM + tid] +
             c.z * Wcls[(size_t)(k4 + 2) * HDIM + tid] +
             c.w * Wcls[(size_t)(k4 + 3) * HDIM + tid];
    }
    zz[tid] = acc > 0.f ? acc : 0.f;
  }
  __syncthreads();
  int o = tid >> 6, lane = tid & 63;
  if (o < 2) {
    float p = 0.f;
    for (int j = lane; j < HDIM; j += 64) p += zz[j] * Wout[(size_t)j * 2 + o];
#pragma unroll
    for (int off = 32; off > 0; off >>= 1) p += __shfl_down(p, off, 64);
    if (lane == 0) out[b * 2 + o] = p + bout[o];
  }
}

extern "C" void kernel_launch(void* const* d_in, const int* in_sizes, int n_in,
                              void* d_out, int out_size, void* d_ws, size_t ws_size,
                              hipStream_t stream) {
  (void)in_sizes; (void)n_in; (void)out_size; (void)ws_size;
  const int* data = (const int*)d_in[0];
  const int* row_idx = (const int*)d_in[1];
  const int* col_idx = (const int*)d_in[2];
  const int* row_len = (const int*)d_in[3];
  const int* col_len = (const int*)d_in[4];
  const float* emb = (const float*)d_in[5];
  const float* W1 = (const float*)d_in[6];
  const float* b1 = (const float*)d_in[7];
  const float* W2 = (const float*)d_in[8];
  const float* b2 = (const float*)d_in[9];
  const float* Wc = (const float*)d_in[10];
  const float* bc = (const float*)d_in[11];
  const float* Wcls = (const float*)d_in[12];
  const float* bcls = (const float*)d_in[13];
  const float* Wout = (const float*)d_in[14];
  const float* bout = (const float*)d_in[15];
  float* out = (float*)d_out;

  char* wp = (char*)d_ws;
  auto carve = [&](size_t bytes) {
    char* p = wp; wp += (bytes + 255) & ~(size_t)255; return p;
  };
  ushort* enchi = (ushort*)carve((size_t)NS * KPAD * 2);
  ushort* enclo = (ushort*)carve((size_t)NS * KPAD * 2);
  ushort* h1hi = (ushort*)carve((size_t)NS * KPAD * 2);
  ushort* h1lo = (ushort*)carve((size_t)NS * KPAD * 2);
  ushort* hehi = (ushort*)carve((size_t)NS * KPAD * 2);
  ushort* helo = (ushort*)carve((size_t)NS * KPAD * 2);
  ushort* hnhi = (ushort*)carve((size_t)NS * KPAD * 2);
  ushort* hnlo = (ushort*)carve((size_t)NS * KPAD * 2);
  ushort* W1hi = (ushort*)carve((size_t)NPADW * KPAD * 2);
  ushort* W1lo = (ushort*)carve((size_t)NPADW * KPAD * 2);
  ushort* W2hi = (ushort*)carve((size_t)NPADW * KPAD * 2);
  ushort* W2lo = (ushort*)carve((size_t)NPADW * KPAD * 2);
  ushort* Wchi = (ushort*)carve((size_t)640 * KPAD * 2);
  ushort* Wclo = (ushort*)carve((size_t)640 * KPAD * 2);
  float* HcB = (float*)carve((size_t)NS * 600 * 4);
  float* Km = (float*)carve((size_t)BB * NMAX * MMAX * 4);
  float* cr = (float*)carve((size_t)BB * HDIM * 4);
  float* cc = (float*)carve((size_t)BB * HDIM * 4);

  int gM = (NS + 63) / 64;  // 157
  int cvtTotal = 2 * NPADW * KPAD + 640 * KPAD;

  k_embed<<<NS, 256, 0, stream>>>(data, emb, enchi, enclo);
  k_cvt_all<<<(cvtTotal + 255) / 256, 256, 0, stream>>>(
      W1, W2, Wc, W1hi, W1lo, W2hi, W2lo, Wchi, Wclo);
  k_gemm_mfma<<<dim3(gM, 3), 256, 0, stream>>>(
      enchi, enclo, W1hi, W1lo, b1, NS, HDIM, 1, nullptr, h1hi, h1lo);
  k_gemm_mfma<<<dim3(gM, 3), 256, 0, stream>>>(
      h1hi, h1lo, W2hi, W2lo, b2, NS, HDIM, 1, nullptr, hehi, helo);
  k_norm_split<<<(NS + 3) / 4, 256, 0, stream>>>(hehi, helo, hnhi, hnlo);
  k_gemm_mfma<<<dim3(gM, 5), 256, 0, stream>>>(
      hehi, helo, Wchi, Wclo, nullptr, NS, 2 * HDIM, 0, HcB, nullptr, nullptr);
  k_cost_mfma<<<dim3(2, 2, BB), 256, 0, stream>>>(hnhi, hnlo, row_idx, col_idx,
                                                  row_len, col_len, Km);
  k_sinkhorn<<<BB, 512, 0, stream>>>(Km, row_len, col_len);
  k_att_cmp_both<<<dim3(5, BB, 2), 256, 0, stream>>>(
      Km, HcB, row_idx, col_idx, row_len, col_len, bc, cr, cc);
  k_cls<<<BB, 320, 0, stream>>>(cr, cc, Wcls, bcls, Wout, bout, out);
}

// Round 3
// 405.140 us; speedup vs baseline: 1.0414x; 1.0414x over previous
//
#include <hip/hip_runtime.h>
#include <math.h>

#define NS 10000
#define LSEQ 32
#define DDIM 300
#define HDIM 300
#define BB 256
#define NMAX 128
#define MMAX 128
#define EPSR 0.1f
#define SITERS 50
#define KPAD 320
#define NPADW 384

typedef __attribute__((ext_vector_type(8))) short bf16x8;
typedef __attribute__((ext_vector_type(4))) float f32x4;

__device__ __forceinline__ ushort f2bf(float x) {
  union { float f; unsigned u; } c; c.f = x;
  unsigned r = (c.u + 0x7fffu + ((c.u >> 16) & 1u)) >> 16;
  return (ushort)r;
}
__device__ __forceinline__ float bf2f(ushort h) {
  union { unsigned u; float f; } c; c.u = ((unsigned)h) << 16;
  return c.f;
}

// ------- K1: embedding + masked mean pool -> enc hi/lo [NS][KPAD] bf16 -----
__global__ __launch_bounds__(256) void k_embed(const int* __restrict__ data,
                                               const float* __restrict__ emb,
                                               ushort* __restrict__ enchi,
                                               ushort* __restrict__ enclo) {
  __shared__ int ids[LSEQ];
  __shared__ __align__(16) float4 part[3][76];
  int s = blockIdx.x;
  int tid = threadIdx.x;
  if (tid < LSEQ) ids[tid] = data[s * LSEQ + tid];
  __syncthreads();
  int cnt = 0;
#pragma unroll
  for (int t = 0; t < LSEQ; ++t) cnt += (ids[t] != 0) ? 1 : 0;
  int g = tid / 75, d = tid - g * 75;
  const float4* emb4 = (const float4*)emb;
  if (g < 3) {
    float4 acc = make_float4(0.f, 0.f, 0.f, 0.f);
    for (int t = g; t < LSEQ; t += 3) {
      int id = ids[t];
      if (id != 0) {
        float4 e = emb4[(size_t)id * 75 + d];
        acc.x += e.x; acc.y += e.y; acc.z += e.z; acc.w += e.w;
      }
    }
    part[g][d] = acc;
  }
  __syncthreads();
  if (g == 0) {
    float4 a = part[0][d], b = part[1][d], c = part[2][d];
    float inv = 1.f / (float)(cnt > 0 ? cnt : 1);
    float v[4] = {(a.x + b.x + c.x) * inv, (a.y + b.y + c.y) * inv,
                  (a.z + b.z + c.z) * inv, (a.w + b.w + c.w) * inv};
    ushort4 h, l;
    h.x = f2bf(v[0]); l.x = f2bf(v[0] - bf2f(h.x));
    h.y = f2bf(v[1]); l.y = f2bf(v[1] - bf2f(h.y));
    h.z = f2bf(v[2]); l.z = f2bf(v[2] - bf2f(h.z));
    h.w = f2bf(v[3]); l.w = f2bf(v[3] - bf2f(h.w));
    *(ushort4*)&enchi[(size_t)s * KPAD + d * 4] = h;
    *(ushort4*)&enclo[(size_t)s * KPAD + d * 4] = l;
  } else if (g == 1 && d < 5) {
    ushort4 z; z.x = z.y = z.z = z.w = 0;
    *(ushort4*)&enchi[(size_t)s * KPAD + 300 + d * 4] = z;
    *(ushort4*)&enclo[(size_t)s * KPAD + 300 + d * 4] = z;
  }
}

// ------- K2: all weight converts in one dispatch ---------------------------
__global__ __launch_bounds__(256) void k_cvt_all(
    const float* __restrict__ W1, const float* __restrict__ W2,
    const float* __restrict__ Wc, ushort* __restrict__ W1hi,
    ushort* __restrict__ W1lo, ushort* __restrict__ W2hi,
    ushort* __restrict__ W2lo, ushort* __restrict__ Wchi,
    ushort* __restrict__ Wclo) {
  int i = blockIdx.x * 256 + threadIdx.x;
  const int SA = NPADW * KPAD;
  const int SC = 640 * KPAD;
  float v = 0.f;
  ushort *ph, *pl;
  int idx;
  if (i < SA) {
    idx = i;
    int n = idx / KPAD, k = idx - n * KPAD;
    if (n < HDIM && k < DDIM) v = W1[(size_t)k * HDIM + n];
    ph = W1hi; pl = W1lo;
  } else if (i < 2 * SA) {
    idx = i - SA;
    int n = idx / KPAD, k = idx - n * KPAD;
    if (n < HDIM && k < HDIM) v = W2[(size_t)k * HDIM + n];
    ph = W2hi; pl = W2lo;
  } else if (i < 2 * SA + SC) {
    idx = i - 2 * SA;
    int n = idx / KPAD, k = idx - n * KPAD;
    if (k < HDIM && n < 2 * HDIM)
      v = (n < HDIM) ? Wc[(size_t)k * HDIM + n]
                     : Wc[(size_t)(HDIM + k) * HDIM + (n - HDIM)];
    ph = Wchi; pl = Wclo;
  } else {
    return;
  }
  ushort h = f2bf(v);
  ph[idx] = h;
  pl[idx] = f2bf(v - bf2f(h));
}

// ------- K3: MFMA GEMM, hi/lo 3-term, 64x128 tile, wave = 32x64 ------------
__global__ __launch_bounds__(256) void k_gemm_mfma(
    const ushort* __restrict__ Ahi, const ushort* __restrict__ Alo,
    const ushort* __restrict__ BhiT, const ushort* __restrict__ BloT,
    const float* __restrict__ bias, int M, int N, int relu,
    float* __restrict__ Cf, ushort* __restrict__ Chi,
    ushort* __restrict__ Clo) {
  __shared__ __align__(16) ushort ldsA[2][64][40];
  __shared__ __align__(16) ushort ldsB[2][128][40];
  int tid = threadIdx.x;
  int m0 = blockIdx.x * 64, n0 = blockIdx.y * 128;
  int rowA = tid >> 2, chA = (tid & 3) * 8;
  int rowB = tid >> 1, chB = (tid & 1) * 16;
  bool mok = (m0 + rowA) < M;
  const ushort* pAh = Ahi + (size_t)(m0 + rowA) * KPAD + chA;
  const ushort* pAl = Alo + (size_t)(m0 + rowA) * KPAD + chA;
  const ushort* pBh = BhiT + (size_t)(n0 + rowB) * KPAD + chB;
  const ushort* pBl = BloT + (size_t)(n0 + rowB) * KPAD + chB;
  uint4 rAh, rAl, rBh0, rBh1, rBl0, rBl1;
  uint4 z4; z4.x = z4.y = z4.z = z4.w = 0;
  auto ld = [&](int c) {
    int o = c * 32;
    rAh = mok ? *(const uint4*)(pAh + o) : z4;
    rAl = mok ? *(const uint4*)(pAl + o) : z4;
    rBh0 = *(const uint4*)(pBh + o);
    rBh1 = *(const uint4*)(pBh + o + 8);
    rBl0 = *(const uint4*)(pBl + o);
    rBl1 = *(const uint4*)(pBl + o + 8);
  };
  auto st = [&]() {
    *(uint4*)&ldsA[0][rowA][chA] = rAh;
    *(uint4*)&ldsA[1][rowA][chA] = rAl;
    *(uint4*)&ldsB[0][rowB][chB] = rBh0;
    *(uint4*)&ldsB[0][rowB][chB + 8] = rBh1;
    *(uint4*)&ldsB[1][rowB][chB] = rBl0;
    *(uint4*)&ldsB[1][rowB][chB + 8] = rBl1;
  };
  int w = tid >> 6, lane = tid & 63;
  int q = lane >> 4, l16 = lane & 15;
  int mh = w >> 1, nh = w & 1;
  f32x4 zf = {0.f, 0.f, 0.f, 0.f};
  f32x4 acc[2][4];
#pragma unroll
  for (int s = 0; s < 2; ++s)
#pragma unroll
    for (int t = 0; t < 4; ++t) acc[s][t] = zf;
  ld(0); st(); __syncthreads();
  for (int c = 0; c < 10; ++c) {
    if (c < 9) ld(c + 1);
    bf16x8 ah0 = *(const bf16x8*)&ldsA[0][mh * 32 + l16][q * 8];
    bf16x8 ah1 = *(const bf16x8*)&ldsA[0][mh * 32 + 16 + l16][q * 8];
    bf16x8 al0 = *(const bf16x8*)&ldsA[1][mh * 32 + l16][q * 8];
    bf16x8 al1 = *(const bf16x8*)&ldsA[1][mh * 32 + 16 + l16][q * 8];
#pragma unroll
    for (int t = 0; t < 4; ++t) {
      int brow = nh * 64 + t * 16 + l16;
      bf16x8 bh = *(const bf16x8*)&ldsB[0][brow][q * 8];
      bf16x8 bl = *(const bf16x8*)&ldsB[1][brow][q * 8];
      acc[0][t] = __builtin_amdgcn_mfma_f32_16x16x32_bf16(ah0, bh, acc[0][t], 0, 0, 0);
      acc[0][t] = __builtin_amdgcn_mfma_f32_16x16x32_bf16(ah0, bl, acc[0][t], 0, 0, 0);
      acc[0][t] = __builtin_amdgcn_mfma_f32_16x16x32_bf16(al0, bh, acc[0][t], 0, 0, 0);
      acc[1][t] = __builtin_amdgcn_mfma_f32_16x16x32_bf16(ah1, bh, acc[1][t], 0, 0, 0);
      acc[1][t] = __builtin_amdgcn_mfma_f32_16x16x32_bf16(ah1, bl, acc[1][t], 0, 0, 0);
      acc[1][t] = __builtin_amdgcn_mfma_f32_16x16x32_bf16(al1, bh, acc[1][t], 0, 0, 0);
    }
    __syncthreads();
    if (c < 9) st();
    __syncthreads();
  }
#pragma unroll
  for (int t = 0; t < 4; ++t) {
    int n = n0 + nh * 64 + t * 16 + l16;
    bool nin = n < N;
    float bz = (bias && nin) ? bias[n] : 0.f;
#pragma unroll
    for (int s = 0; s < 2; ++s) {
#pragma unroll
      for (int r = 0; r < 4; ++r) {
        int m = m0 + mh * 32 + s * 16 + q * 4 + r;
        if (m >= M) continue;
        float v = acc[s][t][r] + bz;
        if (relu) v = v > 0.f ? v : 0.f;
        if (Cf && nin) Cf[(size_t)m * N + n] = v;
        if (Chi && n < KPAD) {
          ushort h = 0, l = 0;
          if (nin) { h = f2bf(v); l = f2bf(v - bf2f(h)); }
          Chi[(size_t)m * KPAD + n] = h;
          Clo[(size_t)m * KPAD + n] = l;
        }
      }
    }
  }
}

// --- K4: normalize henc (hi/lo) -> hn hi/lo [NS][KPAD] (unit rows) ---------
__global__ __launch_bounds__(256) void k_norm_split(
    const ushort* __restrict__ hehi, const ushort* __restrict__ helo,
    ushort* __restrict__ hnhi, ushort* __restrict__ hnlo) {
  int s = blockIdx.x * 4 + (threadIdx.x >> 6);
  int lane = threadIdx.x & 63;
  if (s >= NS) return;
  const ushort* ph = hehi + (size_t)s * KPAD;
  const ushort* pl = helo + (size_t)s * KPAD;
  float x[5];
  float ss = 0.f;
#pragma unroll
  for (int q = 0; q < 5; ++q) {
    int d = lane + q * 64;
    x[q] = bf2f(ph[d]) + bf2f(pl[d]);
    ss += x[q] * x[q];
  }
#pragma unroll
  for (int off = 32; off > 0; off >>= 1) ss += __shfl_down(ss, off, 64);
  ss = __shfl(ss, 0, 64);
  float inv = 1.f / (sqrtf(ss) + 1e-8f);
  ushort* qh = hnhi + (size_t)s * KPAD;
  ushort* ql = hnlo + (size_t)s * KPAD;
#pragma unroll
  for (int q = 0; q < 5; ++q) {
    int d = lane + q * 64;
    float v = x[q] * inv;
    ushort h = f2bf(v);
    qh[d] = h;
    ql[d] = f2bf(v - bf2f(h));
  }
}

// --- K5: cost as gathered MFMA GEMM (hn·hn^T) + fused exp, wave = 32x32 ----
__global__ __launch_bounds__(256) void k_cost_mfma(
    const ushort* __restrict__ hnhi, const ushort* __restrict__ hnlo,
    const int* __restrict__ ridx, const int* __restrict__ cidx,
    const int* __restrict__ rlen, const int* __restrict__ clen,
    float* __restrict__ Kmat) {
  int b = blockIdx.z;
  int r0 = blockIdx.x * 64, c0 = blockIdx.y * 64;
  int rl = rlen[b], cl = clen[b];
  float* Kg = Kmat + (size_t)b * NMAX * MMAX;
  int tid = threadIdx.x;
  if (r0 >= rl || c0 >= cl) {
    for (int l = tid; l < 64 * 16; l += 256) {
      int i = l >> 4, j = (l & 15) << 2;
      *(float4*)&Kg[(size_t)(r0 + i) * MMAX + c0 + j] =
          make_float4(0.f, 0.f, 0.f, 0.f);
    }
    return;
  }
  __shared__ int rix[64], cix[64];
  __shared__ __align__(16) ushort lds[4][64][40];  // Rhi,Rlo,Chi,Clo
  if (tid < 64) rix[tid] = ridx[b * NMAX + r0 + tid];
  else if (tid < 128) cix[tid - 64] = cidx[b * MMAX + c0 + tid - 64];
  __syncthreads();
  int row = tid >> 2, ch = tid & 3;
  const ushort* pRh = hnhi + (size_t)rix[row] * KPAD + ch * 8;
  const ushort* pRl = hnlo + (size_t)rix[row] * KPAD + ch * 8;
  const ushort* pCh = hnhi + (size_t)cix[row] * KPAD + ch * 8;
  const ushort* pCl = hnlo + (size_t)cix[row] * KPAD + ch * 8;
  uint4 rRh, rRl, rCh, rCl;
  auto ld = [&](int c) {
    int o = c * 32;
    rRh = *(const uint4*)(pRh + o);
    rRl = *(const uint4*)(pRl + o);
    rCh = *(const uint4*)(pCh + o);
    rCl = *(const uint4*)(pCl + o);
  };
  auto st = [&]() {
    *(uint4*)&lds[0][row][ch * 8] = rRh;
    *(uint4*)&lds[1][row][ch * 8] = rRl;
    *(uint4*)&lds[2][row][ch * 8] = rCh;
    *(uint4*)&lds[3][row][ch * 8] = rCl;
  };
  int w = tid >> 6, lane = tid & 63;
  int q = lane >> 4, l16 = lane & 15;
  int mh = w >> 1, nh = w & 1;
  f32x4 zf = {0.f, 0.f, 0.f, 0.f};
  f32x4 acc[2][2];
#pragma unroll
  for (int s = 0; s < 2; ++s)
#pragma unroll
    for (int t = 0; t < 2; ++t) acc[s][t] = zf;
  ld(0); st(); __syncthreads();
  for (int c = 0; c < 10; ++c) {
    if (c < 9) ld(c + 1);
    bf16x8 ah0 = *(const bf16x8*)&lds[0][mh * 32 + l16][q * 8];
    bf16x8 ah1 = *(const bf16x8*)&lds[0][mh * 32 + 16 + l16][q * 8];
    bf16x8 al0 = *(const bf16x8*)&lds[1][mh * 32 + l16][q * 8];
    bf16x8 al1 = *(const bf16x8*)&lds[1][mh * 32 + 16 + l16][q * 8];
#pragma unroll
    for (int t = 0; t < 2; ++t) {
      int brow = nh * 32 + t * 16 + l16;
      bf16x8 bh = *(const bf16x8*)&lds[2][brow][q * 8];
      bf16x8 bl = *(const bf16x8*)&lds[3][brow][q * 8];
      acc[0][t] = __builtin_amdgcn_mfma_f32_16x16x32_bf16(ah0, bh, acc[0][t], 0, 0, 0);
      acc[0][t] = __builtin_amdgcn_mfma_f32_16x16x32_bf16(ah0, bl, acc[0][t], 0, 0, 0);
      acc[0][t] = __builtin_amdgcn_mfma_f32_16x16x32_bf16(al0, bh, acc[0][t], 0, 0, 0);
      acc[1][t] = __builtin_amdgcn_mfma_f32_16x16x32_bf16(ah1, bh, acc[1][t], 0, 0, 0);
      acc[1][t] = __builtin_amdgcn_mfma_f32_16x16x32_bf16(ah1, bl, acc[1][t], 0, 0, 0);
      acc[1][t] = __builtin_amdgcn_mfma_f32_16x16x32_bf16(al1, bh, acc[1][t], 0, 0, 0);
    }
    __syncthreads();
    if (c < 9) st();
    __syncthreads();
  }
#pragma unroll
  for (int t = 0; t < 2; ++t) {
    int n = c0 + nh * 32 + t * 16 + l16;
#pragma unroll
    for (int s = 0; s < 2; ++s) {
#pragma unroll
      for (int r = 0; r < 4; ++r) {
        int m = r0 + mh * 32 + s * 16 + q * 4 + r;
        float kv = (m < rl && n < cl) ? expf((acc[s][t][r] - 1.f) / EPSR) : 0.f;
        Kg[(size_t)m * MMAX + n] = kv;
      }
    }
  }
}

// --------- K6: Sinkhorn, K held in VGPRs; also zero-inits cr/cc ------------
__global__ __launch_bounds__(512) void k_sinkhorn(
    float* __restrict__ Kmat, const int* __restrict__ rlen,
    const int* __restrict__ clen, float* __restrict__ cr,
    float* __restrict__ cc) {
  __shared__ __align__(16) float vq[4][36];
  __shared__ __align__(16) float uq[4][36];
  int b = blockIdx.x;
  int tid = threadIdx.x;
  // zero-init cr/cc for K7's atomicAdd accumulation (same-stream ordering)
  if (tid < HDIM) {
    cr[(size_t)b * HDIM + tid] = 0.f;
    cc[(size_t)b * HDIM + tid] = 0.f;
  }
  int n = tid >> 2, q = tid & 3;
  int rl = rlen[b], cl = clen[b];
  float* Kg = Kmat + (size_t)b * NMAX * MMAX;
  float kr[32], kt[32];
  const float4* Kg4 = (const float4*)(Kg + (size_t)n * MMAX + 32 * q);
#pragma unroll
  for (int t = 0; t < 8; ++t) *(float4*)&kr[4 * t] = Kg4[t];
#pragma unroll
  for (int j = 0; j < 32; ++j) kt[j] = Kg[(size_t)(32 * q + j) * MMAX + n];
  if (tid < 128) vq[tid >> 5][tid & 31] = (tid < cl) ? 1.f : 0.f;
  float av = (n < rl) ? 1.f / (float)rl : 0.f;
  float bv = (n < cl) ? 1.f / (float)cl : 0.f;
  float un = 0.f;
  __syncthreads();
  for (int it = 0; it < SITERS; ++it) {
    float s = 0.f;
#pragma unroll
    for (int t = 0; t < 8; ++t) {
      float4 vv = *(const float4*)&vq[q][4 * t];
      s += kr[4 * t + 0] * vv.x + kr[4 * t + 1] * vv.y +
           kr[4 * t + 2] * vv.z + kr[4 * t + 3] * vv.w;
    }
    s += __shfl_xor(s, 1, 64);
    s += __shfl_xor(s, 2, 64);
    un = (n < rl) ? av / s : 0.f;
    if (q == 0) uq[n >> 5][n & 31] = un;
    __syncthreads();
    float s2 = 0.f;
#pragma unroll
    for (int t = 0; t < 8; ++t) {
      float4 uu = *(const float4*)&uq[q][4 * t];
      s2 += kt[4 * t + 0] * uu.x + kt[4 * t + 1] * uu.y +
            kt[4 * t + 2] * uu.z + kt[4 * t + 3] * uu.w;
    }
    s2 += __shfl_xor(s2, 1, 64);
    s2 += __shfl_xor(s2, 2, 64);
    float vm = (n < cl) ? bv / s2 : 0.f;
    if (q == 0) vq[n >> 5][n & 31] = vm;
    __syncthreads();
  }
  float4* Pg4 = (float4*)(Kg + (size_t)n * MMAX + 32 * q);
#pragma unroll
  for (int t = 0; t < 8; ++t) {
    float4 vv = *(const float4*)&vq[q][4 * t];
    float4 p;
    p.x = un * kr[4 * t + 0] * vv.x;
    p.y = un * kr[4 * t + 1] * vv.y;
    p.z = un * kr[4 * t + 2] * vv.z;
    p.w = un * kr[4 * t + 3] * vv.w;
    Pg4[t] = p;
  }
}

// ---- K7: attend + compare + masked sum; mt split across grid --------------
// R3: blockIdx.z = side*2 + mt. Each block handles ONE 64-row mt chunk
// (<=8 k-steps, was <=16) -> 2x blocks, shorter items, less tail, and the
// register footprint shrinks back to the R1-baseline 5-blocks/CU level.
// Partial col-sums combined with atomicAdd (cr/cc zeroed in k_sinkhorn).
__global__ __launch_bounds__(256) void k_att_cmp_both(
    const float* __restrict__ P, const float* __restrict__ HcB,
    const int* __restrict__ row_idx, const int* __restrict__ col_idx,
    const int* __restrict__ row_len, const int* __restrict__ col_len,
    const float* __restrict__ bc, float* __restrict__ cr,
    float* __restrict__ cc) {
  int b = blockIdx.y;
  int side = blockIdx.z >> 1;
  int mt = blockIdx.z & 1;
  int c0 = blockIdx.x * 64;
  const int* idx_main = side == 0 ? row_idx : col_idx;
  const int* idx_other = side == 0 ? col_idx : row_idx;
  int lm = side == 0 ? row_len[b] : col_len[b];
  int lo = side == 0 ? col_len[b] : row_len[b];
  int nmt = (lm + 63) >> 6;
  if (mt >= nmt) return;
  float* outacc = side == 0 ? cr : cc;
  __shared__ __align__(16) float smem[2][2][16][68];  // [buf][P|G]
  __shared__ int iox[NMAX];
  __shared__ int imx[64];
  int tid = threadIdx.x, tx = tid & 15, ty = tid >> 4;
  int jj = tid & 63, kq = tid >> 6;
  if (tid < 128) iox[tid] = idx_other[b * NMAX + tid];
  else if (tid < 192) imx[tid - 128] = idx_main[b * NMAX + mt * 64 + tid - 128];
  __syncthreads();
  const float* Pb = P + (size_t)b * NMAX * MMAX;
  bool cok = (c0 + jj) < HDIM;
  int nkc = (lo + 15) >> 4;
  int m0 = mt * 64;
  float pR[4], gR[4];
  auto loadPG = [&](int kc) {
    int k0 = kc * 16;
    if (side == 0) {
#pragma unroll
      for (int p = 0; p < 4; ++p)
        pR[p] = Pb[(size_t)(m0 + ty + p * 16) * MMAX + k0 + tx];
    } else {
#pragma unroll
      for (int p = 0; p < 4; ++p)
        pR[p] = Pb[(size_t)(k0 + kq + p * 4) * MMAX + m0 + jj];
    }
#pragma unroll
    for (int p = 0; p < 4; ++p) {
      int row = iox[k0 + kq + p * 4];
      gR[p] = cok ? HcB[(size_t)row * 600 + 300 + c0 + jj] : 0.f;
    }
  };
  auto storePG = [&](int buf) {
    if (side == 0) {
#pragma unroll
      for (int p = 0; p < 4; ++p) smem[buf][0][tx][ty + p * 16] = pR[p];
    } else {
#pragma unroll
      for (int p = 0; p < 4; ++p) smem[buf][0][kq + p * 4][jj] = pR[p];
    }
#pragma unroll
    for (int p = 0; p < 4; ++p) smem[buf][1][kq + p * 4][jj] = gR[p];
  };
  loadPG(0);
  storePG(0);
  __syncthreads();
  int cur = 0;
  float acc[4][4] = {};
  for (int kc = 0; kc < nkc; ++kc) {
    if (kc + 1 < nkc) loadPG(kc + 1);
#pragma unroll
    for (int kk = 0; kk < 16; ++kk) {
      float4 av = *(const float4*)&smem[cur][0][kk][ty * 4];
      float4 gv = *(const float4*)&smem[cur][1][kk][tx * 4];
      float a[4] = {av.x, av.y, av.z, av.w};
      float g[4] = {gv.x, gv.y, gv.z, gv.w};
#pragma unroll
      for (int i = 0; i < 4; ++i)
#pragma unroll
        for (int j = 0; j < 4; ++j) acc[i][j] += a[i] * g[j];
    }
    if (kc + 1 < nkc) storePG(cur ^ 1);
    __syncthreads();
    cur ^= 1;
  }
  float colsum[4] = {0.f, 0.f, 0.f, 0.f};
#pragma unroll
  for (int i = 0; i < 4; ++i) {
    int li = ty * 4 + i;
    int mi = m0 + li;
    if (mi >= lm) continue;
    int hrow = imx[li];
#pragma unroll
    for (int j = 0; j < 4; ++j) {
      int col = c0 + tx * 4 + j;
      if (col >= HDIM) continue;
      float y = acc[i][j] + HcB[(size_t)hrow * 600 + col] + bc[col];
      colsum[j] += y > 0.f ? y : 0.f;
    }
  }
  __syncthreads();
  float(*red)[68] = (float(*)[68]) & smem[0][0][0][0];
#pragma unroll
  for (int j = 0; j < 4; ++j) red[ty][tx * 4 + j] = colsum[j];
  __syncthreads();
  if (tid < 64) {
    float s = 0.f;
#pragma unroll
    for (int r = 0; r < 16; ++r) s += red[r][tid];
    int col = c0 + tid;
    if (col < HDIM) atomicAdd(&outacc[(size_t)b * HDIM + col], s);
  }
}

// ---------------- K8: classifier head -> out [B,2] -------------------------
__global__ __launch_bounds__(320) void k_cls(
    const float* __restrict__ cr, const float* __restrict__ cc,
    const float* __restrict__ Wcls, const float* __restrict__ bcls,
    const float* __restrict__ Wout, const float* __restrict__ bout,
    float* __restrict__ out) {
  __shared__ __align__(16) float cz[2 * HDIM];
  __shared__ float zz[HDIM];
  int b = blockIdx.x, tid = threadIdx.x;
  if (tid < HDIM) {
    cz[tid] = cr[(size_t)b * HDIM + tid];
    cz[HDIM + tid] = cc[(size_t)b * HDIM + tid];
  }
  __syncthreads();
  if (tid < HDIM) {
    float acc = bcls[tid];
    for (int k4 = 0; k4 < 2 * HDIM; k4 += 4) {
      float4 c = *(const float4*)&cz[k4];
      acc += c.x * Wcls[(size_t)(k4 + 0) * HDIM + tid] +
             c.y * Wcls[(size_t)(k4 + 1) * HDIM + tid] +
             c.z * Wcls[(size_t)(k4 + 2) * HDIM + tid] +
             c.w * Wcls[(size_t)(k4 + 3) * HDIM + tid];
    }
    zz[tid] = acc > 0.f ? acc : 0.f;
  }
  __syncthreads();
  int o = tid >> 6, lane = tid & 63;
  if (o < 2) {
    float p = 0.f;
    for (int j = lane; j < HDIM; j += 64) p += zz[j] * Wout[(size_t)j * 2 + o];
#pragma unroll
    for (int off = 32; off > 0; off >>= 1) p += __shfl_down(p, off, 64);
    if (lane == 0) out[b * 2 + o] = p + bout[o];
  }
}

extern "C" void kernel_launch(void* const* d_in, const int* in_sizes, int n_in,
                              void* d_out, int out_size, void* d_ws, size_t ws_size,
                              hipStream_t stream) {
  (void)in_sizes; (void)n_in; (void)out_size; (void)ws_size;
  const int* data = (const int*)d_in[0];
  const int* row_idx = (const int*)d_in[1];
  const int* col_idx = (const int*)d_in[2];
  const int* row_len = (const int*)d_in[3];
  const int* col_len = (const int*)d_in[4];
  const float* emb = (const float*)d_in[5];
  const float* W1 = (const float*)d_in[6];
  const float* b1 = (const float*)d_in[7];
  const float* W2 = (const float*)d_in[8];
  const float* b2 = (const float*)d_in[9];
  const float* Wc = (const float*)d_in[10];
  const float* bc = (const float*)d_in[11];
  const float* Wcls = (const float*)d_in[12];
  const float* bcls = (const float*)d_in[13];
  const float* Wout = (const float*)d_in[14];
  const float* bout = (const float*)d_in[15];
  float* out = (float*)d_out;

  char* wp = (char*)d_ws;
  auto carve = [&](size_t bytes) {
    char* p = wp; wp += (bytes + 255) & ~(size_t)255; return p;
  };
  ushort* enchi = (ushort*)carve((size_t)NS * KPAD * 2);
  ushort* enclo = (ushort*)carve((size_t)NS * KPAD * 2);
  ushort* h1hi = (ushort*)carve((size_t)NS * KPAD * 2);
  ushort* h1lo = (ushort*)carve((size_t)NS * KPAD * 2);
  ushort* hehi = (ushort*)carve((size_t)NS * KPAD * 2);
  ushort* helo = (ushort*)carve((size_t)NS * KPAD * 2);
  ushort* hnhi = (ushort*)carve((size_t)NS * KPAD * 2);
  ushort* hnlo = (ushort*)carve((size_t)NS * KPAD * 2);
  ushort* W1hi = (ushort*)carve((size_t)NPADW * KPAD * 2);
  ushort* W1lo = (ushort*)carve((size_t)NPADW * KPAD * 2);
  ushort* W2hi = (ushort*)carve((size_t)NPADW * KPAD * 2);
  ushort* W2lo = (ushort*)carve((size_t)NPADW * KPAD * 2);
  ushort* Wchi = (ushort*)carve((size_t)640 * KPAD * 2);
  ushort* Wclo = (ushort*)carve((size_t)640 * KPAD * 2);
  float* HcB = (float*)carve((size_t)NS * 600 * 4);
  float* Km = (float*)carve((size_t)BB * NMAX * MMAX * 4);
  float* cr = (float*)carve((size_t)BB * HDIM * 4);
  float* cc = (float*)carve((size_t)BB * HDIM * 4);

  int gM = (NS + 63) / 64;  // 157
  int cvtTotal = 2 * NPADW * KPAD + 640 * KPAD;

  k_embed<<<NS, 256, 0, stream>>>(data, emb, enchi, enclo);
  k_cvt_all<<<(cvtTotal + 255) / 256, 256, 0, stream>>>(
      W1, W2, Wc, W1hi, W1lo, W2hi, W2lo, Wchi, Wclo);
  k_gemm_mfma<<<dim3(gM, 3), 256, 0, stream>>>(
      enchi, enclo, W1hi, W1lo, b1, NS, HDIM, 1, nullptr, h1hi, h1lo);
  k_gemm_mfma<<<dim3(gM, 3), 256, 0, stream>>>(
      h1hi, h1lo, W2hi, W2lo, b2, NS, HDIM, 1, nullptr, hehi, helo);
  k_norm_split<<<(NS + 3) / 4, 256, 0, stream>>>(hehi, helo, hnhi, hnlo);
  k_gemm_mfma<<<dim3(gM, 5), 256, 0, stream>>>(
      hehi, helo, Wchi, Wclo, nullptr, NS, 2 * HDIM, 0, HcB, nullptr, nullptr);
  k_cost_mfma<<<dim3(2, 2, BB), 256, 0, stream>>>(hnhi, hnlo, row_idx, col_idx,
                                                  row_len, col_len, Km);
  k_sinkhorn<<<BB, 512, 0, stream>>>(Km, row_len, col_len, cr, cc);
  k_att_cmp_both<<<dim3(5, BB, 4), 256, 0, stream>>>(
      Km, HcB, row_idx, col_idx, row_len, col_len, bc, cr, cc);
  k_cls<<<BB, 320, 0, stream>>>(cr, cc, Wcls, bcls, Wout, bout, out);
}

// Round 4
// 401.209 us; speedup vs baseline: 1.0516x; 1.0098x over previous
//
#include <hip/hip_runtime.h>
#include <math.h>

#define NS 10000
#define LSEQ 32
#define DDIM 300
#define HDIM 300
#define BB 256
#define NMAX 128
#define MMAX 128
#define EPSR 0.1f
#define SITERS 50
#define KPAD 320
#define NPADW 384

typedef __attribute__((ext_vector_type(8))) short bf16x8;
typedef __attribute__((ext_vector_type(4))) float f32x4;

__device__ __forceinline__ ushort f2bf(float x) {
  union { float f; unsigned u; } c; c.f = x;
  unsigned r = (c.u + 0x7fffu + ((c.u >> 16) & 1u)) >> 16;
  return (ushort)r;
}
__device__ __forceinline__ float bf2f(ushort h) {
  union { unsigned u; float f; } c; c.u = ((unsigned)h) << 16;
  return c.f;
}

// ------- K1: embedding + masked mean pool -> enc hi/lo [NS][KPAD] bf16 -----
__global__ __launch_bounds__(256) void k_embed(const int* __restrict__ data,
                                               const float* __restrict__ emb,
                                               ushort* __restrict__ enchi,
                                               ushort* __restrict__ enclo) {
  __shared__ int ids[LSEQ];
  __shared__ __align__(16) float4 part[3][76];
  int s = blockIdx.x;
  int tid = threadIdx.x;
  if (tid < LSEQ) ids[tid] = data[s * LSEQ + tid];
  __syncthreads();
  int cnt = 0;
#pragma unroll
  for (int t = 0; t < LSEQ; ++t) cnt += (ids[t] != 0) ? 1 : 0;
  int g = tid / 75, d = tid - g * 75;
  const float4* emb4 = (const float4*)emb;
  if (g < 3) {
    float4 acc = make_float4(0.f, 0.f, 0.f, 0.f);
    for (int t = g; t < LSEQ; t += 3) {
      int id = ids[t];
      if (id != 0) {
        float4 e = emb4[(size_t)id * 75 + d];
        acc.x += e.x; acc.y += e.y; acc.z += e.z; acc.w += e.w;
      }
    }
    part[g][d] = acc;
  }
  __syncthreads();
  if (g == 0) {
    float4 a = part[0][d], b = part[1][d], c = part[2][d];
    float inv = 1.f / (float)(cnt > 0 ? cnt : 1);
    float v[4] = {(a.x + b.x + c.x) * inv, (a.y + b.y + c.y) * inv,
                  (a.z + b.z + c.z) * inv, (a.w + b.w + c.w) * inv};
    ushort4 h, l;
    h.x = f2bf(v[0]); l.x = f2bf(v[0] - bf2f(h.x));
    h.y = f2bf(v[1]); l.y = f2bf(v[1] - bf2f(h.y));
    h.z = f2bf(v[2]); l.z = f2bf(v[2] - bf2f(h.z));
    h.w = f2bf(v[3]); l.w = f2bf(v[3] - bf2f(h.w));
    *(ushort4*)&enchi[(size_t)s * KPAD + d * 4] = h;
    *(ushort4*)&enclo[(size_t)s * KPAD + d * 4] = l;
  } else if (g == 1 && d < 5) {
    ushort4 z; z.x = z.y = z.z = z.w = 0;
    *(ushort4*)&enchi[(size_t)s * KPAD + 300 + d * 4] = z;
    *(ushort4*)&enclo[(size_t)s * KPAD + 300 + d * 4] = z;
  }
}

// ------- K2: all weight converts in one dispatch ---------------------------
__global__ __launch_bounds__(256) void k_cvt_all(
    const float* __restrict__ W1, const float* __restrict__ W2,
    const float* __restrict__ Wc, ushort* __restrict__ W1hi,
    ushort* __restrict__ W1lo, ushort* __restrict__ W2hi,
    ushort* __restrict__ W2lo, ushort* __restrict__ Wchi,
    ushort* __restrict__ Wclo) {
  int i = blockIdx.x * 256 + threadIdx.x;
  const int SA = NPADW * KPAD;
  const int SC = 640 * KPAD;
  float v = 0.f;
  ushort *ph, *pl;
  int idx;
  if (i < SA) {
    idx = i;
    int n = idx / KPAD, k = idx - n * KPAD;
    if (n < HDIM && k < DDIM) v = W1[(size_t)k * HDIM + n];
    ph = W1hi; pl = W1lo;
  } else if (i < 2 * SA) {
    idx = i - SA;
    int n = idx / KPAD, k = idx - n * KPAD;
    if (n < HDIM && k < HDIM) v = W2[(size_t)k * HDIM + n];
    ph = W2hi; pl = W2lo;
  } else if (i < 2 * SA + SC) {
    idx = i - 2 * SA;
    int n = idx / KPAD, k = idx - n * KPAD;
    if (k < HDIM && n < 2 * HDIM)
      v = (n < HDIM) ? Wc[(size_t)k * HDIM + n]
                     : Wc[(size_t)(HDIM + k) * HDIM + (n - HDIM)];
    ph = Wchi; pl = Wclo;
  } else {
    return;
  }
  ushort h = f2bf(v);
  ph[idx] = h;
  pl[idx] = f2bf(v - bf2f(h));
}

// ------- K3: MFMA GEMM, hi/lo 3-term, 64x128 tile, wave = 32x64 ------------
__global__ __launch_bounds__(256) void k_gemm_mfma(
    const ushort* __restrict__ Ahi, const ushort* __restrict__ Alo,
    const ushort* __restrict__ BhiT, const ushort* __restrict__ BloT,
    const float* __restrict__ bias, int M, int N, int relu,
    float* __restrict__ Cf, ushort* __restrict__ Chi,
    ushort* __restrict__ Clo) {
  __shared__ __align__(16) ushort ldsA[2][64][40];
  __shared__ __align__(16) ushort ldsB[2][128][40];
  int tid = threadIdx.x;
  int m0 = blockIdx.x * 64, n0 = blockIdx.y * 128;
  int rowA = tid >> 2, chA = (tid & 3) * 8;
  int rowB = tid >> 1, chB = (tid & 1) * 16;
  bool mok = (m0 + rowA) < M;
  const ushort* pAh = Ahi + (size_t)(m0 + rowA) * KPAD + chA;
  const ushort* pAl = Alo + (size_t)(m0 + rowA) * KPAD + chA;
  const ushort* pBh = BhiT + (size_t)(n0 + rowB) * KPAD + chB;
  const ushort* pBl = BloT + (size_t)(n0 + rowB) * KPAD + chB;
  uint4 rAh, rAl, rBh0, rBh1, rBl0, rBl1;
  uint4 z4; z4.x = z4.y = z4.z = z4.w = 0;
  auto ld = [&](int c) {
    int o = c * 32;
    rAh = mok ? *(const uint4*)(pAh + o) : z4;
    rAl = mok ? *(const uint4*)(pAl + o) : z4;
    rBh0 = *(const uint4*)(pBh + o);
    rBh1 = *(const uint4*)(pBh + o + 8);
    rBl0 = *(const uint4*)(pBl + o);
    rBl1 = *(const uint4*)(pBl + o + 8);
  };
  auto st = [&]() {
    *(uint4*)&ldsA[0][rowA][chA] = rAh;
    *(uint4*)&ldsA[1][rowA][chA] = rAl;
    *(uint4*)&ldsB[0][rowB][chB] = rBh0;
    *(uint4*)&ldsB[0][rowB][chB + 8] = rBh1;
    *(uint4*)&ldsB[1][rowB][chB] = rBl0;
    *(uint4*)&ldsB[1][rowB][chB + 8] = rBl1;
  };
  int w = tid >> 6, lane = tid & 63;
  int q = lane >> 4, l16 = lane & 15;
  int mh = w >> 1, nh = w & 1;
  f32x4 zf = {0.f, 0.f, 0.f, 0.f};
  f32x4 acc[2][4];
#pragma unroll
  for (int s = 0; s < 2; ++s)
#pragma unroll
    for (int t = 0; t < 4; ++t) acc[s][t] = zf;
  ld(0); st(); __syncthreads();
  for (int c = 0; c < 10; ++c) {
    if (c < 9) ld(c + 1);
    bf16x8 ah0 = *(const bf16x8*)&ldsA[0][mh * 32 + l16][q * 8];
    bf16x8 ah1 = *(const bf16x8*)&ldsA[0][mh * 32 + 16 + l16][q * 8];
    bf16x8 al0 = *(const bf16x8*)&ldsA[1][mh * 32 + l16][q * 8];
    bf16x8 al1 = *(const bf16x8*)&ldsA[1][mh * 32 + 16 + l16][q * 8];
#pragma unroll
    for (int t = 0; t < 4; ++t) {
      int brow = nh * 64 + t * 16 + l16;
      bf16x8 bh = *(const bf16x8*)&ldsB[0][brow][q * 8];
      bf16x8 bl = *(const bf16x8*)&ldsB[1][brow][q * 8];
      acc[0][t] = __builtin_amdgcn_mfma_f32_16x16x32_bf16(ah0, bh, acc[0][t], 0, 0, 0);
      acc[0][t] = __builtin_amdgcn_mfma_f32_16x16x32_bf16(ah0, bl, acc[0][t], 0, 0, 0);
      acc[0][t] = __builtin_amdgcn_mfma_f32_16x16x32_bf16(al0, bh, acc[0][t], 0, 0, 0);
      acc[1][t] = __builtin_amdgcn_mfma_f32_16x16x32_bf16(ah1, bh, acc[1][t], 0, 0, 0);
      acc[1][t] = __builtin_amdgcn_mfma_f32_16x16x32_bf16(ah1, bl, acc[1][t], 0, 0, 0);
      acc[1][t] = __builtin_amdgcn_mfma_f32_16x16x32_bf16(al1, bh, acc[1][t], 0, 0, 0);
    }
    __syncthreads();
    if (c < 9) st();
    __syncthreads();
  }
#pragma unroll
  for (int t = 0; t < 4; ++t) {
    int n = n0 + nh * 64 + t * 16 + l16;
    bool nin = n < N;
    float bz = (bias && nin) ? bias[n] : 0.f;
#pragma unroll
    for (int s = 0; s < 2; ++s) {
#pragma unroll
      for (int r = 0; r < 4; ++r) {
        int m = m0 + mh * 32 + s * 16 + q * 4 + r;
        if (m >= M) continue;
        float v = acc[s][t][r] + bz;
        if (relu) v = v > 0.f ? v : 0.f;
        if (Cf && nin) Cf[(size_t)m * N + n] = v;
        if (Chi && n < KPAD) {
          ushort h = 0, l = 0;
          if (nin) { h = f2bf(v); l = f2bf(v - bf2f(h)); }
          Chi[(size_t)m * KPAD + n] = h;
          Clo[(size_t)m * KPAD + n] = l;
        }
      }
    }
  }
}

// --- K4: normalize henc (hi/lo) -> hn hi/lo [NS][KPAD] (unit rows) ---------
__global__ __launch_bounds__(256) void k_norm_split(
    const ushort* __restrict__ hehi, const ushort* __restrict__ helo,
    ushort* __restrict__ hnhi, ushort* __restrict__ hnlo) {
  int s = blockIdx.x * 4 + (threadIdx.x >> 6);
  int lane = threadIdx.x & 63;
  if (s >= NS) return;
  const ushort* ph = hehi + (size_t)s * KPAD;
  const ushort* pl = helo + (size_t)s * KPAD;
  float x[5];
  float ss = 0.f;
#pragma unroll
  for (int q = 0; q < 5; ++q) {
    int d = lane + q * 64;
    x[q] = bf2f(ph[d]) + bf2f(pl[d]);
    ss += x[q] * x[q];
  }
#pragma unroll
  for (int off = 32; off > 0; off >>= 1) ss += __shfl_down(ss, off, 64);
  ss = __shfl(ss, 0, 64);
  float inv = 1.f / (sqrtf(ss) + 1e-8f);
  ushort* qh = hnhi + (size_t)s * KPAD;
  ushort* ql = hnlo + (size_t)s * KPAD;
#pragma unroll
  for (int q = 0; q < 5; ++q) {
    int d = lane + q * 64;
    float v = x[q] * inv;
    ushort h = f2bf(v);
    qh[d] = h;
    ql[d] = f2bf(v - bf2f(h));
  }
}

// --- K5: cost as gathered MFMA GEMM (hn·hn^T) + fused exp, wave = 32x32 ----
__global__ __launch_bounds__(256) void k_cost_mfma(
    const ushort* __restrict__ hnhi, const ushort* __restrict__ hnlo,
    const int* __restrict__ ridx, const int* __restrict__ cidx,
    const int* __restrict__ rlen, const int* __restrict__ clen,
    float* __restrict__ Kmat) {
  int b = blockIdx.z;
  int r0 = blockIdx.x * 64, c0 = blockIdx.y * 64;
  int rl = rlen[b], cl = clen[b];
  float* Kg = Kmat + (size_t)b * NMAX * MMAX;
  int tid = threadIdx.x;
  if (r0 >= rl || c0 >= cl) {
    for (int l = tid; l < 64 * 16; l += 256) {
      int i = l >> 4, j = (l & 15) << 2;
      *(float4*)&Kg[(size_t)(r0 + i) * MMAX + c0 + j] =
          make_float4(0.f, 0.f, 0.f, 0.f);
    }
    return;
  }
  __shared__ int rix[64], cix[64];
  __shared__ __align__(16) ushort lds[4][64][40];  // Rhi,Rlo,Chi,Clo
  if (tid < 64) rix[tid] = ridx[b * NMAX + r0 + tid];
  else if (tid < 128) cix[tid - 64] = cidx[b * MMAX + c0 + tid - 64];
  __syncthreads();
  int row = tid >> 2, ch = tid & 3;
  const ushort* pRh = hnhi + (size_t)rix[row] * KPAD + ch * 8;
  const ushort* pRl = hnlo + (size_t)rix[row] * KPAD + ch * 8;
  const ushort* pCh = hnhi + (size_t)cix[row] * KPAD + ch * 8;
  const ushort* pCl = hnlo + (size_t)cix[row] * KPAD + ch * 8;
  uint4 rRh, rRl, rCh, rCl;
  auto ld = [&](int c) {
    int o = c * 32;
    rRh = *(const uint4*)(pRh + o);
    rRl = *(const uint4*)(pRl + o);
    rCh = *(const uint4*)(pCh + o);
    rCl = *(const uint4*)(pCl + o);
  };
  auto st = [&]() {
    *(uint4*)&lds[0][row][ch * 8] = rRh;
    *(uint4*)&lds[1][row][ch * 8] = rRl;
    *(uint4*)&lds[2][row][ch * 8] = rCh;
    *(uint4*)&lds[3][row][ch * 8] = rCl;
  };
  int w = tid >> 6, lane = tid & 63;
  int q = lane >> 4, l16 = lane & 15;
  int mh = w >> 1, nh = w & 1;
  f32x4 zf = {0.f, 0.f, 0.f, 0.f};
  f32x4 acc[2][2];
#pragma unroll
  for (int s = 0; s < 2; ++s)
#pragma unroll
    for (int t = 0; t < 2; ++t) acc[s][t] = zf;
  ld(0); st(); __syncthreads();
  for (int c = 0; c < 10; ++c) {
    if (c < 9) ld(c + 1);
    bf16x8 ah0 = *(const bf16x8*)&lds[0][mh * 32 + l16][q * 8];
    bf16x8 ah1 = *(const bf16x8*)&lds[0][mh * 32 + 16 + l16][q * 8];
    bf16x8 al0 = *(const bf16x8*)&lds[1][mh * 32 + l16][q * 8];
    bf16x8 al1 = *(const bf16x8*)&lds[1][mh * 32 + 16 + l16][q * 8];
#pragma unroll
    for (int t = 0; t < 2; ++t) {
      int brow = nh * 32 + t * 16 + l16;
      bf16x8 bh = *(const bf16x8*)&lds[2][brow][q * 8];
      bf16x8 bl = *(const bf16x8*)&lds[3][brow][q * 8];
      acc[0][t] = __builtin_amdgcn_mfma_f32_16x16x32_bf16(ah0, bh, acc[0][t], 0, 0, 0);
      acc[0][t] = __builtin_amdgcn_mfma_f32_16x16x32_bf16(ah0, bl, acc[0][t], 0, 0, 0);
      acc[0][t] = __builtin_amdgcn_mfma_f32_16x16x32_bf16(al0, bh, acc[0][t], 0, 0, 0);
      acc[1][t] = __builtin_amdgcn_mfma_f32_16x16x32_bf16(ah1, bh, acc[1][t], 0, 0, 0);
      acc[1][t] = __builtin_amdgcn_mfma_f32_16x16x32_bf16(ah1, bl, acc[1][t], 0, 0, 0);
      acc[1][t] = __builtin_amdgcn_mfma_f32_16x16x32_bf16(al1, bh, acc[1][t], 0, 0, 0);
    }
    __syncthreads();
    if (c < 9) st();
    __syncthreads();
  }
#pragma unroll
  for (int t = 0; t < 2; ++t) {
    int n = c0 + nh * 32 + t * 16 + l16;
#pragma unroll
    for (int s = 0; s < 2; ++s) {
#pragma unroll
      for (int r = 0; r < 4; ++r) {
        int m = r0 + mh * 32 + s * 16 + q * 4 + r;
        float kv = (m < rl && n < cl) ? expf((acc[s][t][r] - 1.f) / EPSR) : 0.f;
        Kg[(size_t)m * MMAX + n] = kv;
      }
    }
  }
}

// --------- K6: Sinkhorn, K held in VGPRs; also zero-inits cr/cc ------------
__global__ __launch_bounds__(512) void k_sinkhorn(
    float* __restrict__ Kmat, const int* __restrict__ rlen,
    const int* __restrict__ clen, float* __restrict__ cr,
    float* __restrict__ cc) {
  __shared__ __align__(16) float vq[4][36];
  __shared__ __align__(16) float uq[4][36];
  int b = blockIdx.x;
  int tid = threadIdx.x;
  if (tid < HDIM) {
    cr[(size_t)b * HDIM + tid] = 0.f;
    cc[(size_t)b * HDIM + tid] = 0.f;
  }
  int n = tid >> 2, q = tid & 3;
  int rl = rlen[b], cl = clen[b];
  float* Kg = Kmat + (size_t)b * NMAX * MMAX;
  float kr[32], kt[32];
  const float4* Kg4 = (const float4*)(Kg + (size_t)n * MMAX + 32 * q);
#pragma unroll
  for (int t = 0; t < 8; ++t) *(float4*)&kr[4 * t] = Kg4[t];
#pragma unroll
  for (int j = 0; j < 32; ++j) kt[j] = Kg[(size_t)(32 * q + j) * MMAX + n];
  if (tid < 128) vq[tid >> 5][tid & 31] = (tid < cl) ? 1.f : 0.f;
  float av = (n < rl) ? 1.f / (float)rl : 0.f;
  float bv = (n < cl) ? 1.f / (float)cl : 0.f;
  float un = 0.f;
  __syncthreads();
  for (int it = 0; it < SITERS; ++it) {
    float s = 0.f;
#pragma unroll
    for (int t = 0; t < 8; ++t) {
      float4 vv = *(const float4*)&vq[q][4 * t];
      s += kr[4 * t + 0] * vv.x + kr[4 * t + 1] * vv.y +
           kr[4 * t + 2] * vv.z + kr[4 * t + 3] * vv.w;
    }
    s += __shfl_xor(s, 1, 64);
    s += __shfl_xor(s, 2, 64);
    un = (n < rl) ? av / s : 0.f;
    if (q == 0) uq[n >> 5][n & 31] = un;
    __syncthreads();
    float s2 = 0.f;
#pragma unroll
    for (int t = 0; t < 8; ++t) {
      float4 uu = *(const float4*)&uq[q][4 * t];
      s2 += kt[4 * t + 0] * uu.x + kt[4 * t + 1] * uu.y +
            kt[4 * t + 2] * uu.z + kt[4 * t + 3] * uu.w;
    }
    s2 += __shfl_xor(s2, 1, 64);
    s2 += __shfl_xor(s2, 2, 64);
    float vm = (n < cl) ? bv / s2 : 0.f;
    if (q == 0) vq[n >> 5][n & 31] = vm;
    __syncthreads();
  }
  float4* Pg4 = (float4*)(Kg + (size_t)n * MMAX + 32 * q);
#pragma unroll
  for (int t = 0; t < 8; ++t) {
    float4 vv = *(const float4*)&vq[q][4 * t];
    float4 p;
    p.x = un * kr[4 * t + 0] * vv.x;
    p.y = un * kr[4 * t + 1] * vv.y;
    p.z = un * kr[4 * t + 2] * vv.z;
    p.w = un * kr[4 * t + 3] * vv.w;
    Pg4[t] = p;
  }
}

// ---- K7: attend + compare + masked sum; G-stationary in LDS ---------------
// R4: the only GATHERED stream in the hot loop (G = HcB attended-part rows)
// is loaded ONCE per block into LDS (up to 128x64 fp32, 32 concurrent
// loads/thread -> gather latency paid once, ~1us). mt loop back inside the
// block (no G re-gather per mt, no atomics). Per k-step the only global
// traffic is the CONTIGUOUS, L3-resident P stream (4 loads, depth-1
// prefetch) -> steps become FMA-bound instead of gather-latency-bound.
__global__ __launch_bounds__(256) void k_att_cmp_both(
    const float* __restrict__ P, const float* __restrict__ HcB,
    const int* __restrict__ row_idx, const int* __restrict__ col_idx,
    const int* __restrict__ row_len, const int* __restrict__ col_len,
    const float* __restrict__ bc, float* __restrict__ cr,
    float* __restrict__ cc) {
  int b = blockIdx.y;
  int side = blockIdx.z;
  int c0 = blockIdx.x * 64;
  const int* idx_main = side == 0 ? row_idx : col_idx;
  const int* idx_other = side == 0 ? col_idx : row_idx;
  int lm = side == 0 ? row_len[b] : col_len[b];
  int lo = side == 0 ? col_len[b] : row_len[b];
  float* outacc = side == 0 ? cr : cc;

  __shared__ __align__(16) float gld[128][66];   // G: [k][col] fp32
  __shared__ __align__(16) float pbuf[2][16][66];// P^T slice, double-buffered
  __shared__ int iox[NMAX];
  __shared__ int imx[NMAX];

  int tid = threadIdx.x, tx = tid & 15, ty = tid >> 4;
  int jj = tid & 63, kq = tid >> 6;
  if (tid < 128) iox[tid] = idx_other[b * NMAX + tid];
  else imx[tid - 128] = idx_main[b * NMAX + tid - 128];
  __syncthreads();

  int nkc = (lo + 15) >> 4;
  int nmt = (lm + 63) >> 6;
  bool cok = (c0 + jj) < HDIM;
  const float* Pb = P + (size_t)b * NMAX * MMAX;

  // bias regs
  float bb[4];
#pragma unroll
  for (int j = 0; j < 4; ++j) {
    int col = c0 + tx * 4 + j;
    bb[j] = (col < HDIM) ? bc[col] : 0.f;
  }

  // ---- G burst: gather nkc*16 rows x 64 cols, all loads in flight, once ---
  {
    float gt[8][4];
#pragma unroll
    for (int kc = 0; kc < 8; ++kc) {
      if (kc < nkc) {
#pragma unroll
        for (int p = 0; p < 4; ++p) {
          int row = iox[kc * 16 + kq + p * 4];
          gt[kc][p] = cok ? HcB[(size_t)row * 600 + 300 + c0 + jj] : 0.f;
        }
      }
    }
#pragma unroll
    for (int kc = 0; kc < 8; ++kc) {
      if (kc < nkc) {
#pragma unroll
        for (int p = 0; p < 4; ++p) gld[kc * 16 + kq + p * 4][jj] = gt[kc][p];
      }
    }
  }
  __syncthreads();

  float pR[4];
  auto loadP = [&](int mt, int kc) {
    int m0 = mt * 64, k0 = kc * 16;
    if (side == 0) {
#pragma unroll
      for (int p = 0; p < 4; ++p)
        pR[p] = Pb[(size_t)(m0 + ty + p * 16) * MMAX + k0 + tx];
    } else {
#pragma unroll
      for (int p = 0; p < 4; ++p)
        pR[p] = Pb[(size_t)(k0 + kq + p * 4) * MMAX + m0 + jj];
    }
  };
  auto storeP = [&](int buf) {
    if (side == 0) {
#pragma unroll
      for (int p = 0; p < 4; ++p) pbuf[buf][tx][ty + p * 16] = pR[p];
    } else {
#pragma unroll
      for (int p = 0; p < 4; ++p) pbuf[buf][kq + p * 4][jj] = pR[p];
    }
  };

  float colsum[4] = {0.f, 0.f, 0.f, 0.f};
  for (int mt = 0; mt < nmt; ++mt) {
    int m0 = mt * 64;
    // main-row prefetch: issued now, consumed at epilogue (overlaps kc loop)
    float4 m4[4];
#pragma unroll
    for (int i = 0; i < 4; ++i) {
      int hrow = imx[m0 + ty * 4 + i];
      m4[i] = *(const float4*)&HcB[(size_t)hrow * 600 + c0 + tx * 4];
    }
    loadP(mt, 0);
    storeP(0);
    __syncthreads();
    float acc[4][4] = {};
    int cur = 0;
    for (int kc = 0; kc < nkc; ++kc) {
      if (kc + 1 < nkc) loadP(mt, kc + 1);
      int k0 = kc * 16;
#pragma unroll
      for (int kk = 0; kk < 16; ++kk) {
        float4 av = *(const float4*)&pbuf[cur][kk][ty * 4];
        float4 gv = *(const float4*)&gld[k0 + kk][tx * 4];
        float a[4] = {av.x, av.y, av.z, av.w};
        float g[4] = {gv.x, gv.y, gv.z, gv.w};
#pragma unroll
        for (int i = 0; i < 4; ++i)
#pragma unroll
          for (int j = 0; j < 4; ++j) acc[i][j] += a[i] * g[j];
      }
      if (kc + 1 < nkc) storeP(cur ^ 1);
      __syncthreads();
      cur ^= 1;
    }
    // epilogue: compare + relu + col-sum for this mt
#pragma unroll
    for (int i = 0; i < 4; ++i) {
      int mi = m0 + ty * 4 + i;
      if (mi >= lm) continue;
#pragma unroll
      for (int j = 0; j < 4; ++j) {
        int col = c0 + tx * 4 + j;
        if (col >= HDIM) continue;
        float y = acc[i][j] + (&m4[i].x)[j] + bb[j];
        colsum[j] += y > 0.f ? y : 0.f;
      }
    }
  }
  // cross-ty reduction (reuse pbuf area; all pbuf reads done at last barrier)
  float(*red)[66] = (float(*)[66]) & pbuf[0][0][0];
#pragma unroll
  for (int j = 0; j < 4; ++j) red[ty][tx * 4 + j] = colsum[j];
  __syncthreads();
  if (tid < 64) {
    float s = 0.f;
#pragma unroll
    for (int r = 0; r < 16; ++r) s += red[r][tid];
    int col = c0 + tid;
    if (col < HDIM) outacc[(size_t)b * HDIM + col] = s;
  }
}

// ---------------- K8: classifier head -> out [B,2] -------------------------
__global__ __launch_bounds__(320) void k_cls(
    const float* __restrict__ cr, const float* __restrict__ cc,
    const float* __restrict__ Wcls, const float* __restrict__ bcls,
    const float* __restrict__ Wout, const float* __restrict__ bout,
    float* __restrict__ out) {
  __shared__ __align__(16) float cz[2 * HDIM];
  __shared__ float zz[HDIM];
  int b = blockIdx.x, tid = threadIdx.x;
  if (tid < HDIM) {
    cz[tid] = cr[(size_t)b * HDIM + tid];
    cz[HDIM + tid] = cc[(size_t)b * HDIM + tid];
  }
  __syncthreads();
  if (tid < HDIM) {
    float acc = bcls[tid];
    for (int k4 = 0; k4 < 2 * HDIM; k4 += 4) {
      float4 c = *(const float4*)&cz[k4];
      acc += c.x * Wcls[(size_t)(k4 + 0) * HDIM + tid] +
             c.y * Wcls[(size_t)(k4 + 1) * HDIM + tid] +
             c.z * Wcls[(size_t)(k4 + 2) * HDIM + tid] +
             c.w * Wcls[(size_t)(k4 + 3) * HDIM + tid];
    }
    zz[tid] = acc > 0.f ? acc : 0.f;
  }
  __syncthreads();
  int o = tid >> 6, lane = tid & 63;
  if (o < 2) {
    float p = 0.f;
    for (int j = lane; j < HDIM; j += 64) p += zz[j] * Wout[(size_t)j * 2 + o];
#pragma unroll
    for (int off = 32; off > 0; off >>= 1) p += __shfl_down(p, off, 64);
    if (lane == 0) out[b * 2 + o] = p + bout[o];
  }
}

extern "C" void kernel_launch(void* const* d_in, const int* in_sizes, int n_in,
                              void* d_out, int out_size, void* d_ws, size_t ws_size,
                              hipStream_t stream) {
  (void)in_sizes; (void)n_in; (void)out_size; (void)ws_size;
  const int* data = (const int*)d_in[0];
  const int* row_idx = (const int*)d_in[1];
  const int* col_idx = (const int*)d_in[2];
  const int* row_len = (const int*)d_in[3];
  const int* col_len = (const int*)d_in[4];
  const float* emb = (const float*)d_in[5];
  const float* W1 = (const float*)d_in[6];
  const float* b1 = (const float*)d_in[7];
  const float* W2 = (const float*)d_in[8];
  const float* b2 = (const float*)d_in[9];
  const float* Wc = (const float*)d_in[10];
  const float* bc = (const float*)d_in[11];
  const float* Wcls = (const float*)d_in[12];
  const float* bcls = (const float*)d_in[13];
  const float* Wout = (const float*)d_in[14];
  const float* bout = (const float*)d_in[15];
  float* out = (float*)d_out;

  char* wp = (char*)d_ws;
  auto carve = [&](size_t bytes) {
    char* p = wp; wp += (bytes + 255) & ~(size_t)255; return p;
  };
  ushort* enchi = (ushort*)carve((size_t)NS * KPAD * 2);
  ushort* enclo = (ushort*)carve((size_t)NS * KPAD * 2);
  ushort* h1hi = (ushort*)carve((size_t)NS * KPAD * 2);
  ushort* h1lo = (ushort*)carve((size_t)NS * KPAD * 2);
  ushort* hehi = (ushort*)carve((size_t)NS * KPAD * 2);
  ushort* helo = (ushort*)carve((size_t)NS * KPAD * 2);
  ushort* hnhi = (ushort*)carve((size_t)NS * KPAD * 2);
  ushort* hnlo = (ushort*)carve((size_t)NS * KPAD * 2);
  ushort* W1hi = (ushort*)carve((size_t)NPADW * KPAD * 2);
  ushort* W1lo = (ushort*)carve((size_t)NPADW * KPAD * 2);
  ushort* W2hi = (ushort*)carve((size_t)NPADW * KPAD * 2);
  ushort* W2lo = (ushort*)carve((size_t)NPADW * KPAD * 2);
  ushort* Wchi = (ushort*)carve((size_t)640 * KPAD * 2);
  ushort* Wclo = (ushort*)carve((size_t)640 * KPAD * 2);
  float* HcB = (float*)carve((size_t)NS * 600 * 4);
  float* Km = (float*)carve((size_t)BB * NMAX * MMAX * 4);
  float* cr = (float*)carve((size_t)BB * HDIM * 4);
  float* cc = (float*)carve((size_t)BB * HDIM * 4);

  int gM = (NS + 63) / 64;  // 157
  int cvtTotal = 2 * NPADW * KPAD + 640 * KPAD;

  k_embed<<<NS, 256, 0, stream>>>(data, emb, enchi, enclo);
  k_cvt_all<<<(cvtTotal + 255) / 256, 256, 0, stream>>>(
      W1, W2, Wc, W1hi, W1lo, W2hi, W2lo, Wchi, Wclo);
  k_gemm_mfma<<<dim3(gM, 3), 256, 0, stream>>>(
      enchi, enclo, W1hi, W1lo, b1, NS, HDIM, 1, nullptr, h1hi, h1lo);
  k_gemm_mfma<<<dim3(gM, 3), 256, 0, stream>>>(
      h1hi, h1lo, W2hi, W2lo, b2, NS, HDIM, 1, nullptr, hehi, helo);
  k_norm_split<<<(NS + 3) / 4, 256, 0, stream>>>(hehi, helo, hnhi, hnlo);
  k_gemm_mfma<<<dim3(gM, 5), 256, 0, stream>>>(
      hehi, helo, Wchi, Wclo, nullptr, NS, 2 * HDIM, 0, HcB, nullptr, nullptr);
  k_cost_mfma<<<dim3(2, 2, BB), 256, 0, stream>>>(hnhi, hnlo, row_idx, col_idx,
                                                  row_len, col_len, Km);
  k_sinkhorn<<<BB, 512, 0, stream>>>(Km, row_len, col_len, cr, cc);
  k_att_cmp_both<<<dim3(5, BB, 2), 256, 0, stream>>>(
      Km, HcB, row_idx, col_idx, row_len, col_len, bc, cr, cc);
  k_cls<<<BB, 320, 0, stream>>>(cr, cc, Wcls, bcls, Wout, bout, out);
}

// Round 5
// 392.529 us; speedup vs baseline: 1.0749x; 1.0221x over previous
//
#include <hip/hip_runtime.h>
#include <math.h>

#define NS 10000
#define LSEQ 32
#define DDIM 300
#define HDIM 300
#define BB 256
#define NMAX 128
#define MMAX 128
#define EPSR 0.1f
#define SITERS 50
#define KPAD 320
#define NPADW 384

typedef __attribute__((ext_vector_type(8))) short bf16x8;
typedef __attribute__((ext_vector_type(4))) float f32x4;

__device__ __forceinline__ ushort f2bf(float x) {
  union { float f; unsigned u; } c; c.f = x;
  unsigned r = (c.u + 0x7fffu + ((c.u >> 16) & 1u)) >> 16;
  return (ushort)r;
}
__device__ __forceinline__ float bf2f(ushort h) {
  union { unsigned u; float f; } c; c.u = ((unsigned)h) << 16;
  return c.f;
}

// ------- K1: embedding + masked mean pool -> enc hi/lo [NS][KPAD] bf16 -----
__global__ __launch_bounds__(256) void k_embed(const int* __restrict__ data,
                                               const float* __restrict__ emb,
                                               ushort* __restrict__ enchi,
                                               ushort* __restrict__ enclo) {
  __shared__ int ids[LSEQ];
  __shared__ __align__(16) float4 part[3][76];
  int s = blockIdx.x;
  int tid = threadIdx.x;
  if (tid < LSEQ) ids[tid] = data[s * LSEQ + tid];
  __syncthreads();
  int cnt = 0;
#pragma unroll
  for (int t = 0; t < LSEQ; ++t) cnt += (ids[t] != 0) ? 1 : 0;
  int g = tid / 75, d = tid - g * 75;
  const float4* emb4 = (const float4*)emb;
  if (g < 3) {
    float4 acc = make_float4(0.f, 0.f, 0.f, 0.f);
    for (int t = g; t < LSEQ; t += 3) {
      int id = ids[t];
      if (id != 0) {
        float4 e = emb4[(size_t)id * 75 + d];
        acc.x += e.x; acc.y += e.y; acc.z += e.z; acc.w += e.w;
      }
    }
    part[g][d] = acc;
  }
  __syncthreads();
  if (g == 0) {
    float4 a = part[0][d], b = part[1][d], c = part[2][d];
    float inv = 1.f / (float)(cnt > 0 ? cnt : 1);
    float v[4] = {(a.x + b.x + c.x) * inv, (a.y + b.y + c.y) * inv,
                  (a.z + b.z + c.z) * inv, (a.w + b.w + c.w) * inv};
    ushort4 h, l;
    h.x = f2bf(v[0]); l.x = f2bf(v[0] - bf2f(h.x));
    h.y = f2bf(v[1]); l.y = f2bf(v[1] - bf2f(h.y));
    h.z = f2bf(v[2]); l.z = f2bf(v[2] - bf2f(h.z));
    h.w = f2bf(v[3]); l.w = f2bf(v[3] - bf2f(h.w));
    *(ushort4*)&enchi[(size_t)s * KPAD + d * 4] = h;
    *(ushort4*)&enclo[(size_t)s * KPAD + d * 4] = l;
  } else if (g == 1 && d < 5) {
    ushort4 z; z.x = z.y = z.z = z.w = 0;
    *(ushort4*)&enchi[(size_t)s * KPAD + 300 + d * 4] = z;
    *(ushort4*)&enclo[(size_t)s * KPAD + 300 + d * 4] = z;
  }
}

// ------- K2: all weight converts in one dispatch ---------------------------
__global__ __launch_bounds__(256) void k_cvt_all(
    const float* __restrict__ W1, const float* __restrict__ W2,
    const float* __restrict__ Wc, ushort* __restrict__ W1hi,
    ushort* __restrict__ W1lo, ushort* __restrict__ W2hi,
    ushort* __restrict__ W2lo, ushort* __restrict__ Wchi,
    ushort* __restrict__ Wclo) {
  int i = blockIdx.x * 256 + threadIdx.x;
  const int SA = NPADW * KPAD;
  const int SC = 640 * KPAD;
  float v = 0.f;
  ushort *ph, *pl;
  int idx;
  if (i < SA) {
    idx = i;
    int n = idx / KPAD, k = idx - n * KPAD;
    if (n < HDIM && k < DDIM) v = W1[(size_t)k * HDIM + n];
    ph = W1hi; pl = W1lo;
  } else if (i < 2 * SA) {
    idx = i - SA;
    int n = idx / KPAD, k = idx - n * KPAD;
    if (n < HDIM && k < HDIM) v = W2[(size_t)k * HDIM + n];
    ph = W2hi; pl = W2lo;
  } else if (i < 2 * SA + SC) {
    idx = i - 2 * SA;
    int n = idx / KPAD, k = idx - n * KPAD;
    if (k < HDIM && n < 2 * HDIM)
      v = (n < HDIM) ? Wc[(size_t)k * HDIM + n]
                     : Wc[(size_t)(HDIM + k) * HDIM + (n - HDIM)];
    ph = Wchi; pl = Wclo;
  } else {
    return;
  }
  ushort h = f2bf(v);
  ph[idx] = h;
  pl[idx] = f2bf(v - bf2f(h));
}

// ------- K3: MFMA GEMM, hi/lo 3-term, 64x128 tile, wave = 32x64 ------------
__global__ __launch_bounds__(256) void k_gemm_mfma(
    const ushort* __restrict__ Ahi, const ushort* __restrict__ Alo,
    const ushort* __restrict__ BhiT, const ushort* __restrict__ BloT,
    const float* __restrict__ bias, int M, int N, int relu,
    float* __restrict__ Cf, ushort* __restrict__ Chi,
    ushort* __restrict__ Clo) {
  __shared__ __align__(16) ushort ldsA[2][64][40];
  __shared__ __align__(16) ushort ldsB[2][128][40];
  int tid = threadIdx.x;
  int m0 = blockIdx.x * 64, n0 = blockIdx.y * 128;
  int rowA = tid >> 2, chA = (tid & 3) * 8;
  int rowB = tid >> 1, chB = (tid & 1) * 16;
  bool mok = (m0 + rowA) < M;
  const ushort* pAh = Ahi + (size_t)(m0 + rowA) * KPAD + chA;
  const ushort* pAl = Alo + (size_t)(m0 + rowA) * KPAD + chA;
  const ushort* pBh = BhiT + (size_t)(n0 + rowB) * KPAD + chB;
  const ushort* pBl = BloT + (size_t)(n0 + rowB) * KPAD + chB;
  uint4 rAh, rAl, rBh0, rBh1, rBl0, rBl1;
  uint4 z4; z4.x = z4.y = z4.z = z4.w = 0;
  auto ld = [&](int c) {
    int o = c * 32;
    rAh = mok ? *(const uint4*)(pAh + o) : z4;
    rAl = mok ? *(const uint4*)(pAl + o) : z4;
    rBh0 = *(const uint4*)(pBh + o);
    rBh1 = *(const uint4*)(pBh + o + 8);
    rBl0 = *(const uint4*)(pBl + o);
    rBl1 = *(const uint4*)(pBl + o + 8);
  };
  auto st = [&]() {
    *(uint4*)&ldsA[0][rowA][chA] = rAh;
    *(uint4*)&ldsA[1][rowA][chA] = rAl;
    *(uint4*)&ldsB[0][rowB][chB] = rBh0;
    *(uint4*)&ldsB[0][rowB][chB + 8] = rBh1;
    *(uint4*)&ldsB[1][rowB][chB] = rBl0;
    *(uint4*)&ldsB[1][rowB][chB + 8] = rBl1;
  };
  int w = tid >> 6, lane = tid & 63;
  int q = lane >> 4, l16 = lane & 15;
  int mh = w >> 1, nh = w & 1;
  f32x4 zf = {0.f, 0.f, 0.f, 0.f};
  f32x4 acc[2][4];
#pragma unroll
  for (int s = 0; s < 2; ++s)
#pragma unroll
    for (int t = 0; t < 4; ++t) acc[s][t] = zf;
  ld(0); st(); __syncthreads();
  for (int c = 0; c < 10; ++c) {
    if (c < 9) ld(c + 1);
    bf16x8 ah0 = *(const bf16x8*)&ldsA[0][mh * 32 + l16][q * 8];
    bf16x8 ah1 = *(const bf16x8*)&ldsA[0][mh * 32 + 16 + l16][q * 8];
    bf16x8 al0 = *(const bf16x8*)&ldsA[1][mh * 32 + l16][q * 8];
    bf16x8 al1 = *(const bf16x8*)&ldsA[1][mh * 32 + 16 + l16][q * 8];
#pragma unroll
    for (int t = 0; t < 4; ++t) {
      int brow = nh * 64 + t * 16 + l16;
      bf16x8 bh = *(const bf16x8*)&ldsB[0][brow][q * 8];
      bf16x8 bl = *(const bf16x8*)&ldsB[1][brow][q * 8];
      acc[0][t] = __builtin_amdgcn_mfma_f32_16x16x32_bf16(ah0, bh, acc[0][t], 0, 0, 0);
      acc[0][t] = __builtin_amdgcn_mfma_f32_16x16x32_bf16(ah0, bl, acc[0][t], 0, 0, 0);
      acc[0][t] = __builtin_amdgcn_mfma_f32_16x16x32_bf16(al0, bh, acc[0][t], 0, 0, 0);
      acc[1][t] = __builtin_amdgcn_mfma_f32_16x16x32_bf16(ah1, bh, acc[1][t], 0, 0, 0);
      acc[1][t] = __builtin_amdgcn_mfma_f32_16x16x32_bf16(ah1, bl, acc[1][t], 0, 0, 0);
      acc[1][t] = __builtin_amdgcn_mfma_f32_16x16x32_bf16(al1, bh, acc[1][t], 0, 0, 0);
    }
    __syncthreads();
    if (c < 9) st();
    __syncthreads();
  }
#pragma unroll
  for (int t = 0; t < 4; ++t) {
    int n = n0 + nh * 64 + t * 16 + l16;
    bool nin = n < N;
    float bz = (bias && nin) ? bias[n] : 0.f;
#pragma unroll
    for (int s = 0; s < 2; ++s) {
#pragma unroll
      for (int r = 0; r < 4; ++r) {
        int m = m0 + mh * 32 + s * 16 + q * 4 + r;
        if (m >= M) continue;
        float v = acc[s][t][r] + bz;
        if (relu) v = v > 0.f ? v : 0.f;
        if (Cf && nin) Cf[(size_t)m * N + n] = v;
        if (Chi && n < KPAD) {
          ushort h = 0, l = 0;
          if (nin) { h = f2bf(v); l = f2bf(v - bf2f(h)); }
          Chi[(size_t)m * KPAD + n] = h;
          Clo[(size_t)m * KPAD + n] = l;
        }
      }
    }
  }
}

// --- K4: normalize henc (hi/lo) -> hn hi/lo [NS][KPAD] (unit rows) ---------
__global__ __launch_bounds__(256) void k_norm_split(
    const ushort* __restrict__ hehi, const ushort* __restrict__ helo,
    ushort* __restrict__ hnhi, ushort* __restrict__ hnlo) {
  int s = blockIdx.x * 4 + (threadIdx.x >> 6);
  int lane = threadIdx.x & 63;
  if (s >= NS) return;
  const ushort* ph = hehi + (size_t)s * KPAD;
  const ushort* pl = helo + (size_t)s * KPAD;
  float x[5];
  float ss = 0.f;
#pragma unroll
  for (int q = 0; q < 5; ++q) {
    int d = lane + q * 64;
    x[q] = bf2f(ph[d]) + bf2f(pl[d]);
    ss += x[q] * x[q];
  }
#pragma unroll
  for (int off = 32; off > 0; off >>= 1) ss += __shfl_down(ss, off, 64);
  ss = __shfl(ss, 0, 64);
  float inv = 1.f / (sqrtf(ss) + 1e-8f);
  ushort* qh = hnhi + (size_t)s * KPAD;
  ushort* ql = hnlo + (size_t)s * KPAD;
#pragma unroll
  for (int q = 0; q < 5; ++q) {
    int d = lane + q * 64;
    float v = x[q] * inv;
    ushort h = f2bf(v);
    qh[d] = h;
    ql[d] = f2bf(v - bf2f(h));
  }
}

// --- K5: cost as gathered MFMA GEMM (hn·hn^T) + fused exp, wave = 32x32 ----
__global__ __launch_bounds__(256) void k_cost_mfma(
    const ushort* __restrict__ hnhi, const ushort* __restrict__ hnlo,
    const int* __restrict__ ridx, const int* __restrict__ cidx,
    const int* __restrict__ rlen, const int* __restrict__ clen,
    float* __restrict__ Kmat) {
  int b = blockIdx.z;
  int r0 = blockIdx.x * 64, c0 = blockIdx.y * 64;
  int rl = rlen[b], cl = clen[b];
  float* Kg = Kmat + (size_t)b * NMAX * MMAX;
  int tid = threadIdx.x;
  if (r0 >= rl || c0 >= cl) {
    for (int l = tid; l < 64 * 16; l += 256) {
      int i = l >> 4, j = (l & 15) << 2;
      *(float4*)&Kg[(size_t)(r0 + i) * MMAX + c0 + j] =
          make_float4(0.f, 0.f, 0.f, 0.f);
    }
    return;
  }
  __shared__ int rix[64], cix[64];
  __shared__ __align__(16) ushort lds[4][64][40];  // Rhi,Rlo,Chi,Clo
  if (tid < 64) rix[tid] = ridx[b * NMAX + r0 + tid];
  else if (tid < 128) cix[tid - 64] = cidx[b * MMAX + c0 + tid - 64];
  __syncthreads();
  int row = tid >> 2, ch = tid & 3;
  const ushort* pRh = hnhi + (size_t)rix[row] * KPAD + ch * 8;
  const ushort* pRl = hnlo + (size_t)rix[row] * KPAD + ch * 8;
  const ushort* pCh = hnhi + (size_t)cix[row] * KPAD + ch * 8;
  const ushort* pCl = hnlo + (size_t)cix[row] * KPAD + ch * 8;
  uint4 rRh, rRl, rCh, rCl;
  auto ld = [&](int c) {
    int o = c * 32;
    rRh = *(const uint4*)(pRh + o);
    rRl = *(const uint4*)(pRl + o);
    rCh = *(const uint4*)(pCh + o);
    rCl = *(const uint4*)(pCl + o);
  };
  auto st = [&]() {
    *(uint4*)&lds[0][row][ch * 8] = rRh;
    *(uint4*)&lds[1][row][ch * 8] = rRl;
    *(uint4*)&lds[2][row][ch * 8] = rCh;
    *(uint4*)&lds[3][row][ch * 8] = rCl;
  };
  int w = tid >> 6, lane = tid & 63;
  int q = lane >> 4, l16 = lane & 15;
  int mh = w >> 1, nh = w & 1;
  f32x4 zf = {0.f, 0.f, 0.f, 0.f};
  f32x4 acc[2][2];
#pragma unroll
  for (int s = 0; s < 2; ++s)
#pragma unroll
    for (int t = 0; t < 2; ++t) acc[s][t] = zf;
  ld(0); st(); __syncthreads();
  for (int c = 0; c < 10; ++c) {
    if (c < 9) ld(c + 1);
    bf16x8 ah0 = *(const bf16x8*)&lds[0][mh * 32 + l16][q * 8];
    bf16x8 ah1 = *(const bf16x8*)&lds[0][mh * 32 + 16 + l16][q * 8];
    bf16x8 al0 = *(const bf16x8*)&lds[1][mh * 32 + l16][q * 8];
    bf16x8 al1 = *(const bf16x8*)&lds[1][mh * 32 + 16 + l16][q * 8];
#pragma unroll
    for (int t = 0; t < 2; ++t) {
      int brow = nh * 32 + t * 16 + l16;
      bf16x8 bh = *(const bf16x8*)&lds[2][brow][q * 8];
      bf16x8 bl = *(const bf16x8*)&lds[3][brow][q * 8];
      acc[0][t] = __builtin_amdgcn_mfma_f32_16x16x32_bf16(ah0, bh, acc[0][t], 0, 0, 0);
      acc[0][t] = __builtin_amdgcn_mfma_f32_16x16x32_bf16(ah0, bl, acc[0][t], 0, 0, 0);
      acc[0][t] = __builtin_amdgcn_mfma_f32_16x16x32_bf16(al0, bh, acc[0][t], 0, 0, 0);
      acc[1][t] = __builtin_amdgcn_mfma_f32_16x16x32_bf16(ah1, bh, acc[1][t], 0, 0, 0);
      acc[1][t] = __builtin_amdgcn_mfma_f32_16x16x32_bf16(ah1, bl, acc[1][t], 0, 0, 0);
      acc[1][t] = __builtin_amdgcn_mfma_f32_16x16x32_bf16(al1, bh, acc[1][t], 0, 0, 0);
    }
    __syncthreads();
    if (c < 9) st();
    __syncthreads();
  }
#pragma unroll
  for (int t = 0; t < 2; ++t) {
    int n = c0 + nh * 32 + t * 16 + l16;
#pragma unroll
    for (int s = 0; s < 2; ++s) {
#pragma unroll
      for (int r = 0; r < 4; ++r) {
        int m = r0 + mh * 32 + s * 16 + q * 4 + r;
        float kv = (m < rl && n < cl) ? expf((acc[s][t][r] - 1.f) / EPSR) : 0.f;
        Kg[(size_t)m * MMAX + n] = kv;
      }
    }
  }
}

// --------- K6: Sinkhorn; emits P and P^T directly as hi/lo bf16 ------------
// Thread (n,q) holds K row-slice kr[j]=K[n][32q+j] and col-slice
// kt[j]=K[32q+j][n]. After the iterations (u in uq/un, v in vq):
//   P [n][32q+j] = u[n]      * kr[j] * v[32q+j]   (A-operand, side 0)
//   PT[n][32q+j] = u[32q+j]  * kt[j] * v[n]       (A-operand, side 1)
// Both written as hi/lo bf16 split, coalesced 64B/thread. fp32 P writeback
// removed (k_att_mfma consumes only the bf16 forms).
__global__ __launch_bounds__(512) void k_sinkhorn(
    float* __restrict__ Kmat, const int* __restrict__ rlen,
    const int* __restrict__ clen, ushort* __restrict__ Phi,
    ushort* __restrict__ Plo, ushort* __restrict__ PThi,
    ushort* __restrict__ PTlo) {
  __shared__ __align__(16) float vq[4][36];
  __shared__ __align__(16) float uq[4][36];
  int b = blockIdx.x;
  int tid = threadIdx.x;
  int n = tid >> 2, q = tid & 3;
  int rl = rlen[b], cl = clen[b];
  float* Kg = Kmat + (size_t)b * NMAX * MMAX;
  float kr[32], kt[32];
  const float4* Kg4 = (const float4*)(Kg + (size_t)n * MMAX + 32 * q);
#pragma unroll
  for (int t = 0; t < 8; ++t) *(float4*)&kr[4 * t] = Kg4[t];
#pragma unroll
  for (int j = 0; j < 32; ++j) kt[j] = Kg[(size_t)(32 * q + j) * MMAX + n];
  if (tid < 128) vq[tid >> 5][tid & 31] = (tid < cl) ? 1.f : 0.f;
  float av = (n < rl) ? 1.f / (float)rl : 0.f;
  float bv = (n < cl) ? 1.f / (float)cl : 0.f;
  float un = 0.f;
  __syncthreads();
  for (int it = 0; it < SITERS; ++it) {
    float s = 0.f;
#pragma unroll
    for (int t = 0; t < 8; ++t) {
      float4 vv = *(const float4*)&vq[q][4 * t];
      s += kr[4 * t + 0] * vv.x + kr[4 * t + 1] * vv.y +
           kr[4 * t + 2] * vv.z + kr[4 * t + 3] * vv.w;
    }
    s += __shfl_xor(s, 1, 64);
    s += __shfl_xor(s, 2, 64);
    un = (n < rl) ? av / s : 0.f;
    if (q == 0) uq[n >> 5][n & 31] = un;
    __syncthreads();
    float s2 = 0.f;
#pragma unroll
    for (int t = 0; t < 8; ++t) {
      float4 uu = *(const float4*)&uq[q][4 * t];
      s2 += kt[4 * t + 0] * uu.x + kt[4 * t + 1] * uu.y +
            kt[4 * t + 2] * uu.z + kt[4 * t + 3] * uu.w;
    }
    s2 += __shfl_xor(s2, 1, 64);
    s2 += __shfl_xor(s2, 2, 64);
    float vm = (n < cl) ? bv / s2 : 0.f;
    if (q == 0) vq[n >> 5][n & 31] = vm;
    __syncthreads();
  }
  float vn = vq[n >> 5][n & 31];
  size_t rowoff = (size_t)b * (NMAX * MMAX) + (size_t)n * MMAX + 32 * q;
  // P hi/lo
  {
    uint hw[16], lw[16];
#pragma unroll
    for (int t = 0; t < 16; ++t) {
      float p0 = un * kr[2 * t] * vq[q][2 * t];
      float p1 = un * kr[2 * t + 1] * vq[q][2 * t + 1];
      ushort h0 = f2bf(p0), h1 = f2bf(p1);
      hw[t] = (uint)h0 | ((uint)h1 << 16);
      lw[t] = (uint)f2bf(p0 - bf2f(h0)) | ((uint)f2bf(p1 - bf2f(h1)) << 16);
    }
#pragma unroll
    for (int t4 = 0; t4 < 4; ++t4) {
      uint4 vh = make_uint4(hw[4 * t4], hw[4 * t4 + 1], hw[4 * t4 + 2], hw[4 * t4 + 3]);
      uint4 vl = make_uint4(lw[4 * t4], lw[4 * t4 + 1], lw[4 * t4 + 2], lw[4 * t4 + 3]);
      *(uint4*)(Phi + rowoff + 8 * t4) = vh;
      *(uint4*)(Plo + rowoff + 8 * t4) = vl;
    }
  }
  // P^T hi/lo
  {
    uint hw[16], lw[16];
#pragma unroll
    for (int t = 0; t < 16; ++t) {
      float p0 = uq[q][2 * t] * kt[2 * t] * vn;
      float p1 = uq[q][2 * t + 1] * kt[2 * t + 1] * vn;
      ushort h0 = f2bf(p0), h1 = f2bf(p1);
      hw[t] = (uint)h0 | ((uint)h1 << 16);
      lw[t] = (uint)f2bf(p0 - bf2f(h0)) | ((uint)f2bf(p1 - bf2f(h1)) << 16);
    }
#pragma unroll
    for (int t4 = 0; t4 < 4; ++t4) {
      uint4 vh = make_uint4(hw[4 * t4], hw[4 * t4 + 1], hw[4 * t4 + 2], hw[4 * t4 + 3]);
      uint4 vl = make_uint4(lw[4 * t4], lw[4 * t4 + 1], lw[4 * t4 + 2], lw[4 * t4 + 3]);
      *(uint4*)(PThi + rowoff + 8 * t4) = vh;
      *(uint4*)(PTlo + rowoff + 8 * t4) = vl;
    }
  }
}

// ---- K7: attend + compare + masked sum as MFMA GEMM (hi/lo 3-term) --------
// R5: OUT[i,d] = sum_k A[i,k]*G[k,d], A = P (side0) / P^T (side1) in hi/lo
// bf16 from global (K-contiguous rows -> direct fragment loads); G rows
// gathered ONCE into LDS [k][d] (coalesced, conflict-free); b-fragments
// assembled via 8x ds_read_u16 (2-way/broadcast). Epilogue fuses main-row
// add + bias + relu + column-sum; direct store (d-tiles disjoint).
// P is exactly zero beyond (rl,cl) so K/i padding contributes nothing.
__global__ __launch_bounds__(256) void k_att_mfma(
    const ushort* __restrict__ Phi, const ushort* __restrict__ Plo,
    const ushort* __restrict__ PThi, const ushort* __restrict__ PTlo,
    const float* __restrict__ HcB, const int* __restrict__ row_idx,
    const int* __restrict__ col_idx, const int* __restrict__ row_len,
    const int* __restrict__ col_len, const float* __restrict__ bc,
    float* __restrict__ cr, float* __restrict__ cc) {
  int b = blockIdx.y;
  int side = blockIdx.z;
  int c0 = blockIdx.x * 64;
  const int* idx_main = side == 0 ? row_idx : col_idx;
  const int* idx_other = side == 0 ? col_idx : row_idx;
  int lm = side == 0 ? row_len[b] : col_len[b];
  int lo = side == 0 ? col_len[b] : row_len[b];
  const ushort* Ah = (side == 0 ? Phi : PThi) + (size_t)b * (NMAX * MMAX);
  const ushort* Al = (side == 0 ? Plo : PTlo) + (size_t)b * (NMAX * MMAX);
  float* outacc = side == 0 ? cr : cc;

  __shared__ __align__(16) ushort gldh[128][68];
  __shared__ __align__(16) ushort gldl[128][68];
  __shared__ float red[4][64];
  __shared__ int iox[NMAX];
  __shared__ int imx[NMAX];

  int tid = threadIdx.x;
  int w = tid >> 6, lane = tid & 63;
  int q = lane >> 4, l16 = lane & 15;
  if (tid < 128) iox[tid] = idx_other[b * NMAX + tid];
  else imx[tid - 128] = idx_main[b * NMAX + tid - 128];
  __syncthreads();

  int nkc = (lo + 31) >> 5;  // K chunks of 32
  int kmax = nkc * 32;
  int ndt = (300 - c0 + 15) >> 4;
  if (ndt > 4) ndt = 4;
  bool dok = (c0 + lane) < 300;

  // ---- stage G [k][d]: wave w loads rows w*32..w*32+31, 64 lanes = d ----
  {
    float gv[32];
#pragma unroll
    for (int t = 0; t < 32; ++t) {
      int k = w * 32 + t;
      gv[t] = (k < lo && dok) ? HcB[(size_t)iox[k] * 600 + 300 + c0 + lane]
                              : 0.f;
    }
#pragma unroll
    for (int t = 0; t < 32; ++t) {
      int k = w * 32 + t;
      if (k < kmax) {
        ushort h = f2bf(gv[t]);
        gldh[k][lane] = h;
        gldl[k][lane] = f2bf(gv[t] - bf2f(h));
      }
    }
  }
  __syncthreads();

  // ---- A fragments: wave covers i rows [w*16, w*16+16) and [64+w*16, ..) --
  int i0a = w * 16;
  int i0b = 64 + w * 16;
  bool act0 = i0a < lm;
  bool act1 = i0b < lm;
  bf16x8 fa0h[4], fa0l[4], fa1h[4], fa1l[4];
#pragma unroll
  for (int c = 0; c < 4; ++c) {
    if (c < nkc) {
      size_t oa = (size_t)(i0a + l16) * MMAX + 32 * c + 8 * q;
      size_t ob = (size_t)(i0b + l16) * MMAX + 32 * c + 8 * q;
      if (act0) {
        fa0h[c] = *(const bf16x8*)&Ah[oa];
        fa0l[c] = *(const bf16x8*)&Al[oa];
      }
      if (act1) {
        fa1h[c] = *(const bf16x8*)&Ah[ob];
        fa1l[c] = *(const bf16x8*)&Al[ob];
      }
    }
  }

  f32x4 zf = {0.f, 0.f, 0.f, 0.f};
  f32x4 acc0[4], acc1[4];
#pragma unroll
  for (int dt = 0; dt < 4; ++dt) { acc0[dt] = zf; acc1[dt] = zf; }

#pragma unroll
  for (int c = 0; c < 4; ++c) {
    if (c < nkc) {
      int kb = 32 * c + 8 * q;
#pragma unroll
      for (int dt = 0; dt < 4; ++dt) {
        if (dt < ndt) {
          int d = dt * 16 + l16;
          bf16x8 bh, bl;
#pragma unroll
          for (int e = 0; e < 8; ++e) {
            bh[e] = (short)gldh[kb + e][d];
            bl[e] = (short)gldl[kb + e][d];
          }
          if (act0) {
            acc0[dt] = __builtin_amdgcn_mfma_f32_16x16x32_bf16(fa0h[c], bh, acc0[dt], 0, 0, 0);
            acc0[dt] = __builtin_amdgcn_mfma_f32_16x16x32_bf16(fa0h[c], bl, acc0[dt], 0, 0, 0);
            acc0[dt] = __builtin_amdgcn_mfma_f32_16x16x32_bf16(fa0l[c], bh, acc0[dt], 0, 0, 0);
          }
          if (act1) {
            acc1[dt] = __builtin_amdgcn_mfma_f32_16x16x32_bf16(fa1h[c], bh, acc1[dt], 0, 0, 0);
            acc1[dt] = __builtin_amdgcn_mfma_f32_16x16x32_bf16(fa1h[c], bl, acc1[dt], 0, 0, 0);
            acc1[dt] = __builtin_amdgcn_mfma_f32_16x16x32_bf16(fa1l[c], bh, acc1[dt], 0, 0, 0);
          }
        }
      }
    }
  }

  // ---- epilogue: + main + bias, relu, column partial sums -----------------
  float psum[4] = {0.f, 0.f, 0.f, 0.f};
  float bcv[4];
#pragma unroll
  for (int dt = 0; dt < 4; ++dt) {
    int col = c0 + dt * 16 + l16;
    bcv[dt] = (col < 300) ? bc[col] : 0.f;
  }
#pragma unroll
  for (int s = 0; s < 2; ++s) {
    bool act = (s == 0) ? act0 : act1;
    if (!act) continue;
    int ibase = ((s == 0) ? i0a : i0b) + q * 4;
#pragma unroll
    for (int r = 0; r < 4; ++r) {
      int i = ibase + r;
      if (i >= lm) continue;
      const float* Mrow = &HcB[(size_t)imx[i] * 600];
#pragma unroll
      for (int dt = 0; dt < 4; ++dt) {
        int col = c0 + dt * 16 + l16;
        if (dt < ndt && col < 300) {
          float av = (s == 0) ? acc0[dt][r] : acc1[dt][r];
          float y = av + Mrow[col] + bcv[dt];
          psum[dt] += y > 0.f ? y : 0.f;
        }
      }
    }
  }
#pragma unroll
  for (int dt = 0; dt < 4; ++dt) {
    psum[dt] += __shfl_xor(psum[dt], 16, 64);
    psum[dt] += __shfl_xor(psum[dt], 32, 64);
  }
  if (lane < 16) {
#pragma unroll
    for (int dt = 0; dt < 4; ++dt) red[w][dt * 16 + lane] = psum[dt];
  }
  __syncthreads();
  if (tid < 64) {
    float s = red[0][tid] + red[1][tid] + red[2][tid] + red[3][tid];
    int col = c0 + tid;
    if (col < 300) outacc[(size_t)b * HDIM + col] = s;
  }
}

// ---------------- K8: classifier head -> out [B,2] -------------------------
__global__ __launch_bounds__(320) void k_cls(
    const float* __restrict__ cr, const float* __restrict__ cc,
    const float* __restrict__ Wcls, const float* __restrict__ bcls,
    const float* __restrict__ Wout, const float* __restrict__ bout,
    float* __restrict__ out) {
  __shared__ __align__(16) float cz[2 * HDIM];
  __shared__ float zz[HDIM];
  int b = blockIdx.x, tid = threadIdx.x;
  if (tid < HDIM) {
    cz[tid] = cr[(size_t)b * HDIM + tid];
    cz[HDIM + tid] = cc[(size_t)b * HDIM + tid];
  }
  __syncthreads();
  if (tid < HDIM) {
    float acc = bcls[tid];
    for (int k4 = 0; k4 < 2 * HDIM; k4 += 4) {
      float4 c = *(const float4*)&cz[k4];
      acc += c.x * Wcls[(size_t)(k4 + 0) * HDIM + tid] +
             c.y * Wcls[(size_t)(k4 + 1) * HDIM + tid] +
             c.z * Wcls[(size_t)(k4 + 2) * HDIM + tid] +
             c.w * Wcls[(size_t)(k4 + 3) * HDIM + tid];
    }
    zz[tid] = acc > 0.f ? acc : 0.f;
  }
  __syncthreads();
  int o = tid >> 6, lane = tid & 63;
  if (o < 2) {
    float p = 0.f;
    for (int j = lane; j < HDIM; j += 64) p += zz[j] * Wout[(size_t)j * 2 + o];
#pragma unroll
    for (int off = 32; off > 0; off >>= 1) p += __shfl_down(p, off, 64);
    if (lane == 0) out[b * 2 + o] = p + bout[o];
  }
}

extern "C" void kernel_launch(void* const* d_in, const int* in_sizes, int n_in,
                              void* d_out, int out_size, void* d_ws, size_t ws_size,
                              hipStream_t stream) {
  (void)in_sizes; (void)n_in; (void)out_size; (void)ws_size;
  const int* data = (const int*)d_in[0];
  const int* row_idx = (const int*)d_in[1];
  const int* col_idx = (const int*)d_in[2];
  const int* row_len = (const int*)d_in[3];
  const int* col_len = (const int*)d_in[4];
  const float* emb = (const float*)d_in[5];
  const float* W1 = (const float*)d_in[6];
  const float* b1 = (const float*)d_in[7];
  const float* W2 = (const float*)d_in[8];
  const float* b2 = (const float*)d_in[9];
  const float* Wc = (const float*)d_in[10];
  const float* bc = (const float*)d_in[11];
  const float* Wcls = (const float*)d_in[12];
  const float* bcls = (const float*)d_in[13];
  const float* Wout = (const float*)d_in[14];
  const float* bout = (const float*)d_in[15];
  float* out = (float*)d_out;

  char* wp = (char*)d_ws;
  auto carve = [&](size_t bytes) {
    char* p = wp; wp += (bytes + 255) & ~(size_t)255; return p;
  };
  ushort* enchi = (ushort*)carve((size_t)NS * KPAD * 2);
  ushort* enclo = (ushort*)carve((size_t)NS * KPAD * 2);
  ushort* h1hi = (ushort*)carve((size_t)NS * KPAD * 2);
  ushort* h1lo = (ushort*)carve((size_t)NS * KPAD * 2);
  ushort* hehi = (ushort*)carve((size_t)NS * KPAD * 2);
  ushort* helo = (ushort*)carve((size_t)NS * KPAD * 2);
  ushort* hnhi = (ushort*)carve((size_t)NS * KPAD * 2);
  ushort* hnlo = (ushort*)carve((size_t)NS * KPAD * 2);
  ushort* W1hi = (ushort*)carve((size_t)NPADW * KPAD * 2);
  ushort* W1lo = (ushort*)carve((size_t)NPADW * KPAD * 2);
  ushort* W2hi = (ushort*)carve((size_t)NPADW * KPAD * 2);
  ushort* W2lo = (ushort*)carve((size_t)NPADW * KPAD * 2);
  ushort* Wchi = (ushort*)carve((size_t)640 * KPAD * 2);
  ushort* Wclo = (ushort*)carve((size_t)640 * KPAD * 2);
  float* HcB = (float*)carve((size_t)NS * 600 * 4);
  float* Km = (float*)carve((size_t)BB * NMAX * MMAX * 4);
  float* cr = (float*)carve((size_t)BB * HDIM * 4);
  float* cc = (float*)carve((size_t)BB * HDIM * 4);

  // bf16 hi/lo P and P^T alias buffers that are DEAD by k_sinkhorn time:
  // enc (dead after gemm#1), h1 (dead after gemm#2), he (dead after Wc gemm),
  // hn (dead after k_cost). Each pair spans 12.8MB >= needed 8.39MB.
  ushort* Phi = enchi;
  ushort* Plo = h1hi;
  ushort* PThi = hehi;
  ushort* PTlo = hnhi;

  int gM = (NS + 63) / 64;  // 157
  int cvtTotal = 2 * NPADW * KPAD + 640 * KPAD;

  k_embed<<<NS, 256, 0, stream>>>(data, emb, enchi, enclo);
  k_cvt_all<<<(cvtTotal + 255) / 256, 256, 0, stream>>>(
      W1, W2, Wc, W1hi, W1lo, W2hi, W2lo, Wchi, Wclo);
  k_gemm_mfma<<<dim3(gM, 3), 256, 0, stream>>>(
      enchi, enclo, W1hi, W1lo, b1, NS, HDIM, 1, nullptr, h1hi, h1lo);
  k_gemm_mfma<<<dim3(gM, 3), 256, 0, stream>>>(
      h1hi, h1lo, W2hi, W2lo, b2, NS, HDIM, 1, nullptr, hehi, helo);
  k_norm_split<<<(NS + 3) / 4, 256, 0, stream>>>(hehi, helo, hnhi, hnlo);
  k_gemm_mfma<<<dim3(gM, 5), 256, 0, stream>>>(
      hehi, helo, Wchi, Wclo, nullptr, NS, 2 * HDIM, 0, HcB, nullptr, nullptr);
  k_cost_mfma<<<dim3(2, 2, BB), 256, 0, stream>>>(hnhi, hnlo, row_idx, col_idx,
                                                  row_len, col_len, Km);
  k_sinkhorn<<<BB, 512, 0, stream>>>(Km, row_len, col_len, Phi, Plo, PThi, PTlo);
  k_att_mfma<<<dim3(5, BB, 2), 256, 0, stream>>>(
      Phi, Plo, PThi, PTlo, HcB, row_idx, col_idx, row_len, col_len, bc, cr, cc);
  k_cls<<<BB, 320, 0, stream>>>(cr, cc, Wcls, bcls, Wout, bout, out);
}

// Round 6
// 386.258 us; speedup vs baseline: 1.0923x; 1.0162x over previous
//
#include <hip/hip_runtime.h>
#include <math.h>

#define NS 10000
#define LSEQ 32
#define DDIM 300
#define HDIM 300
#define BB 256
#define NMAX 128
#define MMAX 128
#define EPSR 0.1f
#define SITERS 50
#define KPAD 320
#define NPADW 384

typedef __attribute__((ext_vector_type(8))) short bf16x8;
typedef __attribute__((ext_vector_type(4))) float f32x4;

__device__ __forceinline__ ushort f2bf(float x) {
  union { float f; unsigned u; } c; c.f = x;
  unsigned r = (c.u + 0x7fffu + ((c.u >> 16) & 1u)) >> 16;
  return (ushort)r;
}
__device__ __forceinline__ float bf2f(ushort h) {
  union { unsigned u; float f; } c; c.u = ((unsigned)h) << 16;
  return c.f;
}

// ------- K1: embedding + masked mean pool -> enc hi/lo [NS][KPAD] bf16 -----
__global__ __launch_bounds__(256) void k_embed(const int* __restrict__ data,
                                               const float* __restrict__ emb,
                                               ushort* __restrict__ enchi,
                                               ushort* __restrict__ enclo) {
  __shared__ int ids[LSEQ];
  __shared__ __align__(16) float4 part[3][76];
  int s = blockIdx.x;
  int tid = threadIdx.x;
  if (tid < LSEQ) ids[tid] = data[s * LSEQ + tid];
  __syncthreads();
  int cnt = 0;
#pragma unroll
  for (int t = 0; t < LSEQ; ++t) cnt += (ids[t] != 0) ? 1 : 0;
  int g = tid / 75, d = tid - g * 75;
  const float4* emb4 = (const float4*)emb;
  if (g < 3) {
    float4 acc = make_float4(0.f, 0.f, 0.f, 0.f);
    for (int t = g; t < LSEQ; t += 3) {
      int id = ids[t];
      if (id != 0) {
        float4 e = emb4[(size_t)id * 75 + d];
        acc.x += e.x; acc.y += e.y; acc.z += e.z; acc.w += e.w;
      }
    }
    part[g][d] = acc;
  }
  __syncthreads();
  if (g == 0) {
    float4 a = part[0][d], b = part[1][d], c = part[2][d];
    float inv = 1.f / (float)(cnt > 0 ? cnt : 1);
    float v[4] = {(a.x + b.x + c.x) * inv, (a.y + b.y + c.y) * inv,
                  (a.z + b.z + c.z) * inv, (a.w + b.w + c.w) * inv};
    ushort4 h, l;
    h.x = f2bf(v[0]); l.x = f2bf(v[0] - bf2f(h.x));
    h.y = f2bf(v[1]); l.y = f2bf(v[1] - bf2f(h.y));
    h.z = f2bf(v[2]); l.z = f2bf(v[2] - bf2f(h.z));
    h.w = f2bf(v[3]); l.w = f2bf(v[3] - bf2f(h.w));
    *(ushort4*)&enchi[(size_t)s * KPAD + d * 4] = h;
    *(ushort4*)&enclo[(size_t)s * KPAD + d * 4] = l;
  } else if (g == 1 && d < 5) {
    ushort4 z; z.x = z.y = z.z = z.w = 0;
    *(ushort4*)&enchi[(size_t)s * KPAD + 300 + d * 4] = z;
    *(ushort4*)&enclo[(size_t)s * KPAD + 300 + d * 4] = z;
  }
}

// ------- K2: all weight converts in one dispatch ---------------------------
__global__ __launch_bounds__(256) void k_cvt_all(
    const float* __restrict__ W1, const float* __restrict__ W2,
    const float* __restrict__ Wc, ushort* __restrict__ W1hi,
    ushort* __restrict__ W1lo, ushort* __restrict__ W2hi,
    ushort* __restrict__ W2lo, ushort* __restrict__ Wchi,
    ushort* __restrict__ Wclo) {
  int i = blockIdx.x * 256 + threadIdx.x;
  const int SA = NPADW * KPAD;
  const int SC = 640 * KPAD;
  float v = 0.f;
  ushort *ph, *pl;
  int idx;
  if (i < SA) {
    idx = i;
    int n = idx / KPAD, k = idx - n * KPAD;
    if (n < HDIM && k < DDIM) v = W1[(size_t)k * HDIM + n];
    ph = W1hi; pl = W1lo;
  } else if (i < 2 * SA) {
    idx = i - SA;
    int n = idx / KPAD, k = idx - n * KPAD;
    if (n < HDIM && k < HDIM) v = W2[(size_t)k * HDIM + n];
    ph = W2hi; pl = W2lo;
  } else if (i < 2 * SA + SC) {
    idx = i - 2 * SA;
    int n = idx / KPAD, k = idx - n * KPAD;
    if (k < HDIM && n < 2 * HDIM)
      v = (n < HDIM) ? Wc[(size_t)k * HDIM + n]
                     : Wc[(size_t)(HDIM + k) * HDIM + (n - HDIM)];
    ph = Wchi; pl = Wclo;
  } else {
    return;
  }
  ushort h = f2bf(v);
  ph[idx] = h;
  pl[idx] = f2bf(v - bf2f(h));
}

// ------- K3: MFMA GEMM, hi/lo 3-term, 64x128 tile, wave = 32x64 ------------
__global__ __launch_bounds__(256) void k_gemm_mfma(
    const ushort* __restrict__ Ahi, const ushort* __restrict__ Alo,
    const ushort* __restrict__ BhiT, const ushort* __restrict__ BloT,
    const float* __restrict__ bias, int M, int N, int relu,
    float* __restrict__ Cf, ushort* __restrict__ Chi,
    ushort* __restrict__ Clo) {
  __shared__ __align__(16) ushort ldsA[2][64][40];
  __shared__ __align__(16) ushort ldsB[2][128][40];
  int tid = threadIdx.x;
  int m0 = blockIdx.x * 64, n0 = blockIdx.y * 128;
  int rowA = tid >> 2, chA = (tid & 3) * 8;
  int rowB = tid >> 1, chB = (tid & 1) * 16;
  bool mok = (m0 + rowA) < M;
  const ushort* pAh = Ahi + (size_t)(m0 + rowA) * KPAD + chA;
  const ushort* pAl = Alo + (size_t)(m0 + rowA) * KPAD + chA;
  const ushort* pBh = BhiT + (size_t)(n0 + rowB) * KPAD + chB;
  const ushort* pBl = BloT + (size_t)(n0 + rowB) * KPAD + chB;
  uint4 rAh, rAl, rBh0, rBh1, rBl0, rBl1;
  uint4 z4; z4.x = z4.y = z4.z = z4.w = 0;
  auto ld = [&](int c) {
    int o = c * 32;
    rAh = mok ? *(const uint4*)(pAh + o) : z4;
    rAl = mok ? *(const uint4*)(pAl + o) : z4;
    rBh0 = *(const uint4*)(pBh + o);
    rBh1 = *(const uint4*)(pBh + o + 8);
    rBl0 = *(const uint4*)(pBl + o);
    rBl1 = *(const uint4*)(pBl + o + 8);
  };
  auto st = [&]() {
    *(uint4*)&ldsA[0][rowA][chA] = rAh;
    *(uint4*)&ldsA[1][rowA][chA] = rAl;
    *(uint4*)&ldsB[0][rowB][chB] = rBh0;
    *(uint4*)&ldsB[0][rowB][chB + 8] = rBh1;
    *(uint4*)&ldsB[1][rowB][chB] = rBl0;
    *(uint4*)&ldsB[1][rowB][chB + 8] = rBl1;
  };
  int w = tid >> 6, lane = tid & 63;
  int q = lane >> 4, l16 = lane & 15;
  int mh = w >> 1, nh = w & 1;
  f32x4 zf = {0.f, 0.f, 0.f, 0.f};
  f32x4 acc[2][4];
#pragma unroll
  for (int s = 0; s < 2; ++s)
#pragma unroll
    for (int t = 0; t < 4; ++t) acc[s][t] = zf;
  ld(0); st(); __syncthreads();
  for (int c = 0; c < 10; ++c) {
    if (c < 9) ld(c + 1);
    bf16x8 ah0 = *(const bf16x8*)&ldsA[0][mh * 32 + l16][q * 8];
    bf16x8 ah1 = *(const bf16x8*)&ldsA[0][mh * 32 + 16 + l16][q * 8];
    bf16x8 al0 = *(const bf16x8*)&ldsA[1][mh * 32 + l16][q * 8];
    bf16x8 al1 = *(const bf16x8*)&ldsA[1][mh * 32 + 16 + l16][q * 8];
#pragma unroll
    for (int t = 0; t < 4; ++t) {
      int brow = nh * 64 + t * 16 + l16;
      bf16x8 bh = *(const bf16x8*)&ldsB[0][brow][q * 8];
      bf16x8 bl = *(const bf16x8*)&ldsB[1][brow][q * 8];
      acc[0][t] = __builtin_amdgcn_mfma_f32_16x16x32_bf16(ah0, bh, acc[0][t], 0, 0, 0);
      acc[0][t] = __builtin_amdgcn_mfma_f32_16x16x32_bf16(ah0, bl, acc[0][t], 0, 0, 0);
      acc[0][t] = __builtin_amdgcn_mfma_f32_16x16x32_bf16(al0, bh, acc[0][t], 0, 0, 0);
      acc[1][t] = __builtin_amdgcn_mfma_f32_16x16x32_bf16(ah1, bh, acc[1][t], 0, 0, 0);
      acc[1][t] = __builtin_amdgcn_mfma_f32_16x16x32_bf16(ah1, bl, acc[1][t], 0, 0, 0);
      acc[1][t] = __builtin_amdgcn_mfma_f32_16x16x32_bf16(al1, bh, acc[1][t], 0, 0, 0);
    }
    __syncthreads();
    if (c < 9) st();
    __syncthreads();
  }
#pragma unroll
  for (int t = 0; t < 4; ++t) {
    int n = n0 + nh * 64 + t * 16 + l16;
    bool nin = n < N;
    float bz = (bias && nin) ? bias[n] : 0.f;
#pragma unroll
    for (int s = 0; s < 2; ++s) {
#pragma unroll
      for (int r = 0; r < 4; ++r) {
        int m = m0 + mh * 32 + s * 16 + q * 4 + r;
        if (m >= M) continue;
        float v = acc[s][t][r] + bz;
        if (relu) v = v > 0.f ? v : 0.f;
        if (Cf && nin) Cf[(size_t)m * N + n] = v;
        if (Chi && n < KPAD) {
          ushort h = 0, l = 0;
          if (nin) { h = f2bf(v); l = f2bf(v - bf2f(h)); }
          Chi[(size_t)m * KPAD + n] = h;
          Clo[(size_t)m * KPAD + n] = l;
        }
      }
    }
  }
}

// --- K4: normalize henc (hi/lo) -> hn hi/lo [NS][KPAD] (unit rows) ---------
__global__ __launch_bounds__(256) void k_norm_split(
    const ushort* __restrict__ hehi, const ushort* __restrict__ helo,
    ushort* __restrict__ hnhi, ushort* __restrict__ hnlo) {
  int s = blockIdx.x * 4 + (threadIdx.x >> 6);
  int lane = threadIdx.x & 63;
  if (s >= NS) return;
  const ushort* ph = hehi + (size_t)s * KPAD;
  const ushort* pl = helo + (size_t)s * KPAD;
  float x[5];
  float ss = 0.f;
#pragma unroll
  for (int q = 0; q < 5; ++q) {
    int d = lane + q * 64;
    x[q] = bf2f(ph[d]) + bf2f(pl[d]);
    ss += x[q] * x[q];
  }
#pragma unroll
  for (int off = 32; off > 0; off >>= 1) ss += __shfl_down(ss, off, 64);
  ss = __shfl(ss, 0, 64);
  float inv = 1.f / (sqrtf(ss) + 1e-8f);
  ushort* qh = hnhi + (size_t)s * KPAD;
  ushort* ql = hnlo + (size_t)s * KPAD;
#pragma unroll
  for (int q = 0; q < 5; ++q) {
    int d = lane + q * 64;
    float v = x[q] * inv;
    ushort h = f2bf(v);
    qh[d] = h;
    ql[d] = f2bf(v - bf2f(h));
  }
}

// --- K5: cost as gathered MFMA GEMM (hn·hn^T) + fused exp, wave = 32x32 ----
__global__ __launch_bounds__(256) void k_cost_mfma(
    const ushort* __restrict__ hnhi, const ushort* __restrict__ hnlo,
    const int* __restrict__ ridx, const int* __restrict__ cidx,
    const int* __restrict__ rlen, const int* __restrict__ clen,
    float* __restrict__ Kmat) {
  int b = blockIdx.z;
  int r0 = blockIdx.x * 64, c0 = blockIdx.y * 64;
  int rl = rlen[b], cl = clen[b];
  float* Kg = Kmat + (size_t)b * NMAX * MMAX;
  int tid = threadIdx.x;
  if (r0 >= rl || c0 >= cl) {
    for (int l = tid; l < 64 * 16; l += 256) {
      int i = l >> 4, j = (l & 15) << 2;
      *(float4*)&Kg[(size_t)(r0 + i) * MMAX + c0 + j] =
          make_float4(0.f, 0.f, 0.f, 0.f);
    }
    return;
  }
  __shared__ int rix[64], cix[64];
  __shared__ __align__(16) ushort lds[4][64][40];  // Rhi,Rlo,Chi,Clo
  if (tid < 64) rix[tid] = ridx[b * NMAX + r0 + tid];
  else if (tid < 128) cix[tid - 64] = cidx[b * MMAX + c0 + tid - 64];
  __syncthreads();
  int row = tid >> 2, ch = tid & 3;
  const ushort* pRh = hnhi + (size_t)rix[row] * KPAD + ch * 8;
  const ushort* pRl = hnlo + (size_t)rix[row] * KPAD + ch * 8;
  const ushort* pCh = hnhi + (size_t)cix[row] * KPAD + ch * 8;
  const ushort* pCl = hnlo + (size_t)cix[row] * KPAD + ch * 8;
  uint4 rRh, rRl, rCh, rCl;
  auto ld = [&](int c) {
    int o = c * 32;
    rRh = *(const uint4*)(pRh + o);
    rRl = *(const uint4*)(pRl + o);
    rCh = *(const uint4*)(pCh + o);
    rCl = *(const uint4*)(pCl + o);
  };
  auto st = [&]() {
    *(uint4*)&lds[0][row][ch * 8] = rRh;
    *(uint4*)&lds[1][row][ch * 8] = rRl;
    *(uint4*)&lds[2][row][ch * 8] = rCh;
    *(uint4*)&lds[3][row][ch * 8] = rCl;
  };
  int w = tid >> 6, lane = tid & 63;
  int q = lane >> 4, l16 = lane & 15;
  int mh = w >> 1, nh = w & 1;
  f32x4 zf = {0.f, 0.f, 0.f, 0.f};
  f32x4 acc[2][2];
#pragma unroll
  for (int s = 0; s < 2; ++s)
#pragma unroll
    for (int t = 0; t < 2; ++t) acc[s][t] = zf;
  ld(0); st(); __syncthreads();
  for (int c = 0; c < 10; ++c) {
    if (c < 9) ld(c + 1);
    bf16x8 ah0 = *(const bf16x8*)&lds[0][mh * 32 + l16][q * 8];
    bf16x8 ah1 = *(const bf16x8*)&lds[0][mh * 32 + 16 + l16][q * 8];
    bf16x8 al0 = *(const bf16x8*)&lds[1][mh * 32 + l16][q * 8];
    bf16x8 al1 = *(const bf16x8*)&lds[1][mh * 32 + 16 + l16][q * 8];
#pragma unroll
    for (int t = 0; t < 2; ++t) {
      int brow = nh * 32 + t * 16 + l16;
      bf16x8 bh = *(const bf16x8*)&lds[2][brow][q * 8];
      bf16x8 bl = *(const bf16x8*)&lds[3][brow][q * 8];
      acc[0][t] = __builtin_amdgcn_mfma_f32_16x16x32_bf16(ah0, bh, acc[0][t], 0, 0, 0);
      acc[0][t] = __builtin_amdgcn_mfma_f32_16x16x32_bf16(ah0, bl, acc[0][t], 0, 0, 0);
      acc[0][t] = __builtin_amdgcn_mfma_f32_16x16x32_bf16(al0, bh, acc[0][t], 0, 0, 0);
      acc[1][t] = __builtin_amdgcn_mfma_f32_16x16x32_bf16(ah1, bh, acc[1][t], 0, 0, 0);
      acc[1][t] = __builtin_amdgcn_mfma_f32_16x16x32_bf16(ah1, bl, acc[1][t], 0, 0, 0);
      acc[1][t] = __builtin_amdgcn_mfma_f32_16x16x32_bf16(al1, bh, acc[1][t], 0, 0, 0);
    }
    __syncthreads();
    if (c < 9) st();
    __syncthreads();
  }
#pragma unroll
  for (int t = 0; t < 2; ++t) {
    int n = c0 + nh * 32 + t * 16 + l16;
#pragma unroll
    for (int s = 0; s < 2; ++s) {
#pragma unroll
      for (int r = 0; r < 4; ++r) {
        int m = r0 + mh * 32 + s * 16 + q * 4 + r;
        float kv = (m < rl && n < cl) ? expf((acc[s][t][r] - 1.f) / EPSR) : 0.f;
        Kg[(size_t)m * MMAX + n] = kv;
      }
    }
  }
}

// --------- K6: Sinkhorn; emits P and P^T directly as hi/lo bf16 ------------
__global__ __launch_bounds__(512) void k_sinkhorn(
    float* __restrict__ Kmat, const int* __restrict__ rlen,
    const int* __restrict__ clen, ushort* __restrict__ Phi,
    ushort* __restrict__ Plo, ushort* __restrict__ PThi,
    ushort* __restrict__ PTlo) {
  __shared__ __align__(16) float vq[4][36];
  __shared__ __align__(16) float uq[4][36];
  int b = blockIdx.x;
  int tid = threadIdx.x;
  int n = tid >> 2, q = tid & 3;
  int rl = rlen[b], cl = clen[b];
  float* Kg = Kmat + (size_t)b * NMAX * MMAX;
  float kr[32], kt[32];
  const float4* Kg4 = (const float4*)(Kg + (size_t)n * MMAX + 32 * q);
#pragma unroll
  for (int t = 0; t < 8; ++t) *(float4*)&kr[4 * t] = Kg4[t];
#pragma unroll
  for (int j = 0; j < 32; ++j) kt[j] = Kg[(size_t)(32 * q + j) * MMAX + n];
  if (tid < 128) vq[tid >> 5][tid & 31] = (tid < cl) ? 1.f : 0.f;
  float av = (n < rl) ? 1.f / (float)rl : 0.f;
  float bv = (n < cl) ? 1.f / (float)cl : 0.f;
  float un = 0.f;
  __syncthreads();
  for (int it = 0; it < SITERS; ++it) {
    float s = 0.f;
#pragma unroll
    for (int t = 0; t < 8; ++t) {
      float4 vv = *(const float4*)&vq[q][4 * t];
      s += kr[4 * t + 0] * vv.x + kr[4 * t + 1] * vv.y +
           kr[4 * t + 2] * vv.z + kr[4 * t + 3] * vv.w;
    }
    s += __shfl_xor(s, 1, 64);
    s += __shfl_xor(s, 2, 64);
    un = (n < rl) ? av / s : 0.f;
    if (q == 0) uq[n >> 5][n & 31] = un;
    __syncthreads();
    float s2 = 0.f;
#pragma unroll
    for (int t = 0; t < 8; ++t) {
      float4 uu = *(const float4*)&uq[q][4 * t];
      s2 += kt[4 * t + 0] * uu.x + kt[4 * t + 1] * uu.y +
            kt[4 * t + 2] * uu.z + kt[4 * t + 3] * uu.w;
    }
    s2 += __shfl_xor(s2, 1, 64);
    s2 += __shfl_xor(s2, 2, 64);
    float vm = (n < cl) ? bv / s2 : 0.f;
    if (q == 0) vq[n >> 5][n & 31] = vm;
    __syncthreads();
  }
  float vn = vq[n >> 5][n & 31];
  size_t rowoff = (size_t)b * (NMAX * MMAX) + (size_t)n * MMAX + 32 * q;
  // P hi/lo
  {
    uint hw[16], lw[16];
#pragma unroll
    for (int t = 0; t < 16; ++t) {
      float p0 = un * kr[2 * t] * vq[q][2 * t];
      float p1 = un * kr[2 * t + 1] * vq[q][2 * t + 1];
      ushort h0 = f2bf(p0), h1 = f2bf(p1);
      hw[t] = (uint)h0 | ((uint)h1 << 16);
      lw[t] = (uint)f2bf(p0 - bf2f(h0)) | ((uint)f2bf(p1 - bf2f(h1)) << 16);
    }
#pragma unroll
    for (int t4 = 0; t4 < 4; ++t4) {
      uint4 vh = make_uint4(hw[4 * t4], hw[4 * t4 + 1], hw[4 * t4 + 2], hw[4 * t4 + 3]);
      uint4 vl = make_uint4(lw[4 * t4], lw[4 * t4 + 1], lw[4 * t4 + 2], lw[4 * t4 + 3]);
      *(uint4*)(Phi + rowoff + 8 * t4) = vh;
      *(uint4*)(Plo + rowoff + 8 * t4) = vl;
    }
  }
  // P^T hi/lo
  {
    uint hw[16], lw[16];
#pragma unroll
    for (int t = 0; t < 16; ++t) {
      float p0 = uq[q][2 * t] * kt[2 * t] * vn;
      float p1 = uq[q][2 * t + 1] * kt[2 * t + 1] * vn;
      ushort h0 = f2bf(p0), h1 = f2bf(p1);
      hw[t] = (uint)h0 | ((uint)h1 << 16);
      lw[t] = (uint)f2bf(p0 - bf2f(h0)) | ((uint)f2bf(p1 - bf2f(h1)) << 16);
    }
#pragma unroll
    for (int t4 = 0; t4 < 4; ++t4) {
      uint4 vh = make_uint4(hw[4 * t4], hw[4 * t4 + 1], hw[4 * t4 + 2], hw[4 * t4 + 3]);
      uint4 vl = make_uint4(lw[4 * t4], lw[4 * t4 + 1], lw[4 * t4 + 2], lw[4 * t4 + 3]);
      *(uint4*)(PThi + rowoff + 8 * t4) = vh;
      *(uint4*)(PTlo + rowoff + 8 * t4) = vl;
    }
  }
}

// ---- K7: attend + compare + masked sum as MFMA GEMM (hi/lo 3-term) --------
// R6: G stored TRANSPOSED in LDS as [d][k] with XOR-swizzled 16B blocks
// (phys8 = kb8 ^ (row&15)) so each B-fragment is ONE ds_read_b128 instead of
// 8 scalar ds_read_u16 + packs (R5's hidden cost: 256 u16 reads/thread).
// Swizzle makes both staged writes and fragment reads 2-way (free) per
// 16-lane phase group. Staging: lane owns row d=lane, gathers its 32 k's
// (wave w covers k in [32w,32w+32)), packs in regs, 8 swizzled b128 writes.
__global__ __launch_bounds__(256) void k_att_mfma(
    const ushort* __restrict__ Phi, const ushort* __restrict__ Plo,
    const ushort* __restrict__ PThi, const ushort* __restrict__ PTlo,
    const float* __restrict__ HcB, const int* __restrict__ row_idx,
    const int* __restrict__ col_idx, const int* __restrict__ row_len,
    const int* __restrict__ col_len, const float* __restrict__ bc,
    float* __restrict__ cr, float* __restrict__ cc) {
  int b = blockIdx.y;
  int side = blockIdx.z;
  int c0 = blockIdx.x * 64;
  const int* idx_main = side == 0 ? row_idx : col_idx;
  const int* idx_other = side == 0 ? col_idx : row_idx;
  int lm = side == 0 ? row_len[b] : col_len[b];
  int lo = side == 0 ? col_len[b] : row_len[b];
  const ushort* Ah = (side == 0 ? Phi : PThi) + (size_t)b * (NMAX * MMAX);
  const ushort* Al = (side == 0 ? Plo : PTlo) + (size_t)b * (NMAX * MMAX);
  float* outacc = side == 0 ? cr : cc;

  __shared__ __align__(16) ushort gldh[64][128];  // [d][k], blocks swizzled
  __shared__ __align__(16) ushort gldl[64][128];
  __shared__ float red[4][64];
  __shared__ int iox[NMAX];
  __shared__ int imx[NMAX];

  int tid = threadIdx.x;
  int w = tid >> 6, lane = tid & 63;
  int q = lane >> 4, l16 = lane & 15;
  if (tid < 128) iox[tid] = idx_other[b * NMAX + tid];
  else imx[tid - 128] = idx_main[b * NMAX + tid - 128];
  __syncthreads();

  int nkc = (lo + 31) >> 5;  // K chunks of 32
  int ndt = (300 - c0 + 15) >> 4;
  if (ndt > 4) ndt = 4;
  bool dok = (c0 + lane) < 300;

  // ---- stage G transposed [d][k]: lane = row d, wave w covers 32 k's ----
  {
    float gv[32];
#pragma unroll
    for (int t = 0; t < 32; ++t) {
      int k = w * 32 + t;
      gv[t] = (k < lo && dok) ? HcB[(size_t)iox[k] * 600 + 300 + c0 + lane]
                              : 0.f;
    }
    if (w < nkc) {
#pragma unroll
      for (int blk = 0; blk < 4; ++blk) {
        int kb8 = 4 * w + blk;
        int phys = kb8 ^ (lane & 15);
        ushort hb[8], lb[8];
#pragma unroll
        for (int e = 0; e < 8; ++e) {
          float v = gv[blk * 8 + e];
          ushort h = f2bf(v);
          hb[e] = h;
          lb[e] = f2bf(v - bf2f(h));
        }
        *(uint4*)&gldh[lane][phys * 8] = *(uint4*)hb;
        *(uint4*)&gldl[lane][phys * 8] = *(uint4*)lb;
      }
    }
  }
  __syncthreads();

  // ---- A fragments: wave covers i rows [w*16, w*16+16) and [64+w*16, ..) --
  int i0a = w * 16;
  int i0b = 64 + w * 16;
  bool act0 = i0a < lm;
  bool act1 = i0b < lm;
  bf16x8 fa0h[4], fa0l[4], fa1h[4], fa1l[4];
#pragma unroll
  for (int c = 0; c < 4; ++c) {
    if (c < nkc) {
      size_t oa = (size_t)(i0a + l16) * MMAX + 32 * c + 8 * q;
      size_t ob = (size_t)(i0b + l16) * MMAX + 32 * c + 8 * q;
      if (act0) {
        fa0h[c] = *(const bf16x8*)&Ah[oa];
        fa0l[c] = *(const bf16x8*)&Al[oa];
      }
      if (act1) {
        fa1h[c] = *(const bf16x8*)&Ah[ob];
        fa1l[c] = *(const bf16x8*)&Al[ob];
      }
    }
  }

  f32x4 zf = {0.f, 0.f, 0.f, 0.f};
  f32x4 acc0[4], acc1[4];
#pragma unroll
  for (int dt = 0; dt < 4; ++dt) { acc0[dt] = zf; acc1[dt] = zf; }

#pragma unroll
  for (int c = 0; c < 4; ++c) {
    if (c < nkc) {
      int phys = (4 * c + q) ^ l16;  // swizzled 16B block index
#pragma unroll
      for (int dt = 0; dt < 4; ++dt) {
        if (dt < ndt) {
          int d = dt * 16 + l16;
          bf16x8 bh = *(const bf16x8*)&gldh[d][phys * 8];
          bf16x8 bl = *(const bf16x8*)&gldl[d][phys * 8];
          if (act0) {
            acc0[dt] = __builtin_amdgcn_mfma_f32_16x16x32_bf16(fa0h[c], bh, acc0[dt], 0, 0, 0);
            acc0[dt] = __builtin_amdgcn_mfma_f32_16x16x32_bf16(fa0h[c], bl, acc0[dt], 0, 0, 0);
            acc0[dt] = __builtin_amdgcn_mfma_f32_16x16x32_bf16(fa0l[c], bh, acc0[dt], 0, 0, 0);
          }
          if (act1) {
            acc1[dt] = __builtin_amdgcn_mfma_f32_16x16x32_bf16(fa1h[c], bh, acc1[dt], 0, 0, 0);
            acc1[dt] = __builtin_amdgcn_mfma_f32_16x16x32_bf16(fa1h[c], bl, acc1[dt], 0, 0, 0);
            acc1[dt] = __builtin_amdgcn_mfma_f32_16x16x32_bf16(fa1l[c], bh, acc1[dt], 0, 0, 0);
          }
        }
      }
    }
  }

  // ---- epilogue: + main + bias, relu, column partial sums -----------------
  float psum[4] = {0.f, 0.f, 0.f, 0.f};
  float bcv[4];
#pragma unroll
  for (int dt = 0; dt < 4; ++dt) {
    int col = c0 + dt * 16 + l16;
    bcv[dt] = (col < 300) ? bc[col] : 0.f;
  }
#pragma unroll
  for (int s = 0; s < 2; ++s) {
    bool act = (s == 0) ? act0 : act1;
    if (!act) continue;
    int ibase = ((s == 0) ? i0a : i0b) + q * 4;
#pragma unroll
    for (int r = 0; r < 4; ++r) {
      int i = ibase + r;
      if (i >= lm) continue;
      const float* Mrow = &HcB[(size_t)imx[i] * 600];
#pragma unroll
      for (int dt = 0; dt < 4; ++dt) {
        int col = c0 + dt * 16 + l16;
        if (dt < ndt && col < 300) {
          float av = (s == 0) ? acc0[dt][r] : acc1[dt][r];
          float y = av + Mrow[col] + bcv[dt];
          psum[dt] += y > 0.f ? y : 0.f;
        }
      }
    }
  }
#pragma unroll
  for (int dt = 0; dt < 4; ++dt) {
    psum[dt] += __shfl_xor(psum[dt], 16, 64);
    psum[dt] += __shfl_xor(psum[dt], 32, 64);
  }
  if (lane < 16) {
#pragma unroll
    for (int dt = 0; dt < 4; ++dt) red[w][dt * 16 + lane] = psum[dt];
  }
  __syncthreads();
  if (tid < 64) {
    float s = red[0][tid] + red[1][tid] + red[2][tid] + red[3][tid];
    int col = c0 + tid;
    if (col < 300) outacc[(size_t)b * HDIM + col] = s;
  }
}

// ---------------- K8: classifier head -> out [B,2] -------------------------
__global__ __launch_bounds__(320) void k_cls(
    const float* __restrict__ cr, const float* __restrict__ cc,
    const float* __restrict__ Wcls, const float* __restrict__ bcls,
    const float* __restrict__ Wout, const float* __restrict__ bout,
    float* __restrict__ out) {
  __shared__ __align__(16) float cz[2 * HDIM];
  __shared__ float zz[HDIM];
  int b = blockIdx.x, tid = threadIdx.x;
  if (tid < HDIM) {
    cz[tid] = cr[(size_t)b * HDIM + tid];
    cz[HDIM + tid] = cc[(size_t)b * HDIM + tid];
  }
  __syncthreads();
  if (tid < HDIM) {
    float acc = bcls[tid];
    for (int k4 = 0; k4 < 2 * HDIM; k4 += 4) {
      float4 c = *(const float4*)&cz[k4];
      acc += c.x * Wcls[(size_t)(k4 + 0) * HDIM + tid] +
             c.y * Wcls[(size_t)(k4 + 1) * HDIM + tid] +
             c.z * Wcls[(size_t)(k4 + 2) * HDIM + tid] +
             c.w * Wcls[(size_t)(k4 + 3) * HDIM + tid];
    }
    zz[tid] = acc > 0.f ? acc : 0.f;
  }
  __syncthreads();
  int o = tid >> 6, lane = tid & 63;
  if (o < 2) {
    float p = 0.f;
    for (int j = lane; j < HDIM; j += 64) p += zz[j] * Wout[(size_t)j * 2 + o];
#pragma unroll
    for (int off = 32; off > 0; off >>= 1) p += __shfl_down(p, off, 64);
    if (lane == 0) out[b * 2 + o] = p + bout[o];
  }
}

extern "C" void kernel_launch(void* const* d_in, const int* in_sizes, int n_in,
                              void* d_out, int out_size, void* d_ws, size_t ws_size,
                              hipStream_t stream) {
  (void)in_sizes; (void)n_in; (void)out_size; (void)ws_size;
  const int* data = (const int*)d_in[0];
  const int* row_idx = (const int*)d_in[1];
  const int* col_idx = (const int*)d_in[2];
  const int* row_len = (const int*)d_in[3];
  const int* col_len = (const int*)d_in[4];
  const float* emb = (const float*)d_in[5];
  const float* W1 = (const float*)d_in[6];
  const float* b1 = (const float*)d_in[7];
  const float* W2 = (const float*)d_in[8];
  const float* b2 = (const float*)d_in[9];
  const float* Wc = (const float*)d_in[10];
  const float* bc = (const float*)d_in[11];
  const float* Wcls = (const float*)d_in[12];
  const float* bcls = (const float*)d_in[13];
  const float* Wout = (const float*)d_in[14];
  const float* bout = (const float*)d_in[15];
  float* out = (float*)d_out;

  char* wp = (char*)d_ws;
  auto carve = [&](size_t bytes) {
    char* p = wp; wp += (bytes + 255) & ~(size_t)255; return p;
  };
  ushort* enchi = (ushort*)carve((size_t)NS * KPAD * 2);
  ushort* enclo = (ushort*)carve((size_t)NS * KPAD * 2);
  ushort* h1hi = (ushort*)carve((size_t)NS * KPAD * 2);
  ushort* h1lo = (ushort*)carve((size_t)NS * KPAD * 2);
  ushort* hehi = (ushort*)carve((size_t)NS * KPAD * 2);
  ushort* helo = (ushort*)carve((size_t)NS * KPAD * 2);
  ushort* hnhi = (ushort*)carve((size_t)NS * KPAD * 2);
  ushort* hnlo = (ushort*)carve((size_t)NS * KPAD * 2);
  ushort* W1hi = (ushort*)carve((size_t)NPADW * KPAD * 2);
  ushort* W1lo = (ushort*)carve((size_t)NPADW * KPAD * 2);
  ushort* W2hi = (ushort*)carve((size_t)NPADW * KPAD * 2);
  ushort* W2lo = (ushort*)carve((size_t)NPADW * KPAD * 2);
  ushort* Wchi = (ushort*)carve((size_t)640 * KPAD * 2);
  ushort* Wclo = (ushort*)carve((size_t)640 * KPAD * 2);
  float* HcB = (float*)carve((size_t)NS * 600 * 4);
  float* Km = (float*)carve((size_t)BB * NMAX * MMAX * 4);
  float* cr = (float*)carve((size_t)BB * HDIM * 4);
  float* cc = (float*)carve((size_t)BB * HDIM * 4);

  // bf16 hi/lo P and P^T alias buffers that are DEAD by k_sinkhorn time.
  ushort* Phi = enchi;
  ushort* Plo = h1hi;
  ushort* PThi = hehi;
  ushort* PTlo = hnhi;

  int gM = (NS + 63) / 64;  // 157
  int cvtTotal = 2 * NPADW * KPAD + 640 * KPAD;

  k_embed<<<NS, 256, 0, stream>>>(data, emb, enchi, enclo);
  k_cvt_all<<<(cvtTotal + 255) / 256, 256, 0, stream>>>(
      W1, W2, Wc, W1hi, W1lo, W2hi, W2lo, Wchi, Wclo);
  k_gemm_mfma<<<dim3(gM, 3), 256, 0, stream>>>(
      enchi, enclo, W1hi, W1lo, b1, NS, HDIM, 1, nullptr, h1hi, h1lo);
  k_gemm_mfma<<<dim3(gM, 3), 256, 0, stream>>>(
      h1hi, h1lo, W2hi, W2lo, b2, NS, HDIM, 1, nullptr, hehi, helo);
  k_norm_split<<<(NS + 3) / 4, 256, 0, stream>>>(hehi, helo, hnhi, hnlo);
  k_gemm_mfma<<<dim3(gM, 5), 256, 0, stream>>>(
      hehi, helo, Wchi, Wclo, nullptr, NS, 2 * HDIM, 0, HcB, nullptr, nullptr);
  k_cost_mfma<<<dim3(2, 2, BB), 256, 0, stream>>>(hnhi, hnlo, row_idx, col_idx,
                                                  row_len, col_len, Km);
  k_sinkhorn<<<BB, 512, 0, stream>>>(Km, row_len, col_len, Phi, Plo, PThi, PTlo);
  k_att_mfma<<<dim3(5, BB, 2), 256, 0, stream>>>(
      Phi, Plo, PThi, PTlo, HcB, row_idx, col_idx, row_len, col_len, bc, cr, cc);
  k_cls<<<BB, 320, 0, stream>>>(cr, cc, Wcls, bcls, Wout, bout, out);
}

// Round 7
// 384.766 us; speedup vs baseline: 1.0965x; 1.0039x over previous
//
#include <hip/hip_runtime.h>
#include <math.h>

#define NS 10000
#define LSEQ 32
#define DDIM 300
#define HDIM 300
#define BB 256
#define NMAX 128
#define MMAX 128
#define EPSR 0.1f
#define SITERS 50
#define KPAD 320
#define NPADW 384

typedef __attribute__((ext_vector_type(8))) short bf16x8;
typedef __attribute__((ext_vector_type(4))) float f32x4;

__device__ __forceinline__ ushort f2bf(float x) {
  union { float f; unsigned u; } c; c.f = x;
  unsigned r = (c.u + 0x7fffu + ((c.u >> 16) & 1u)) >> 16;
  return (ushort)r;
}
__device__ __forceinline__ float bf2f(ushort h) {
  union { unsigned u; float f; } c; c.u = ((unsigned)h) << 16;
  return c.f;
}

// ------- K1: embedding + masked mean pool -> enc hi/lo [NS][KPAD] bf16 -----
__global__ __launch_bounds__(256) void k_embed(const int* __restrict__ data,
                                               const float* __restrict__ emb,
                                               ushort* __restrict__ enchi,
                                               ushort* __restrict__ enclo) {
  __shared__ int ids[LSEQ];
  __shared__ __align__(16) float4 part[3][76];
  int s = blockIdx.x;
  int tid = threadIdx.x;
  if (tid < LSEQ) ids[tid] = data[s * LSEQ + tid];
  __syncthreads();
  int cnt = 0;
#pragma unroll
  for (int t = 0; t < LSEQ; ++t) cnt += (ids[t] != 0) ? 1 : 0;
  int g = tid / 75, d = tid - g * 75;
  const float4* emb4 = (const float4*)emb;
  if (g < 3) {
    float4 acc = make_float4(0.f, 0.f, 0.f, 0.f);
    for (int t = g; t < LSEQ; t += 3) {
      int id = ids[t];
      if (id != 0) {
        float4 e = emb4[(size_t)id * 75 + d];
        acc.x += e.x; acc.y += e.y; acc.z += e.z; acc.w += e.w;
      }
    }
    part[g][d] = acc;
  }
  __syncthreads();
  if (g == 0) {
    float4 a = part[0][d], b = part[1][d], c = part[2][d];
    float inv = 1.f / (float)(cnt > 0 ? cnt : 1);
    float v[4] = {(a.x + b.x + c.x) * inv, (a.y + b.y + c.y) * inv,
                  (a.z + b.z + c.z) * inv, (a.w + b.w + c.w) * inv};
    ushort4 h, l;
    h.x = f2bf(v[0]); l.x = f2bf(v[0] - bf2f(h.x));
    h.y = f2bf(v[1]); l.y = f2bf(v[1] - bf2f(h.y));
    h.z = f2bf(v[2]); l.z = f2bf(v[2] - bf2f(h.z));
    h.w = f2bf(v[3]); l.w = f2bf(v[3] - bf2f(h.w));
    *(ushort4*)&enchi[(size_t)s * KPAD + d * 4] = h;
    *(ushort4*)&enclo[(size_t)s * KPAD + d * 4] = l;
  } else if (g == 1 && d < 5) {
    ushort4 z; z.x = z.y = z.z = z.w = 0;
    *(ushort4*)&enchi[(size_t)s * KPAD + 300 + d * 4] = z;
    *(ushort4*)&enclo[(size_t)s * KPAD + 300 + d * 4] = z;
  }
}

// ------- K2: all weight converts in one dispatch ---------------------------
__global__ __launch_bounds__(256) void k_cvt_all(
    const float* __restrict__ W1, const float* __restrict__ W2,
    const float* __restrict__ Wc, ushort* __restrict__ W1hi,
    ushort* __restrict__ W1lo, ushort* __restrict__ W2hi,
    ushort* __restrict__ W2lo, ushort* __restrict__ Wchi,
    ushort* __restrict__ Wclo) {
  int i = blockIdx.x * 256 + threadIdx.x;
  const int SA = NPADW * KPAD;
  const int SC = 640 * KPAD;
  float v = 0.f;
  ushort *ph, *pl;
  int idx;
  if (i < SA) {
    idx = i;
    int n = idx / KPAD, k = idx - n * KPAD;
    if (n < HDIM && k < DDIM) v = W1[(size_t)k * HDIM + n];
    ph = W1hi; pl = W1lo;
  } else if (i < 2 * SA) {
    idx = i - SA;
    int n = idx / KPAD, k = idx - n * KPAD;
    if (n < HDIM && k < HDIM) v = W2[(size_t)k * HDIM + n];
    ph = W2hi; pl = W2lo;
  } else if (i < 2 * SA + SC) {
    idx = i - 2 * SA;
    int n = idx / KPAD, k = idx - n * KPAD;
    if (k < HDIM && n < 2 * HDIM)
      v = (n < HDIM) ? Wc[(size_t)k * HDIM + n]
                     : Wc[(size_t)(HDIM + k) * HDIM + (n - HDIM)];
    ph = Wchi; pl = Wclo;
  } else {
    return;
  }
  ushort h = f2bf(v);
  ph[idx] = h;
  pl[idx] = f2bf(v - bf2f(h));
}

// ------- K3: MFMA GEMM, hi/lo 3-term, 64x128 tile, wave = 32x64 ------------
__global__ __launch_bounds__(256) void k_gemm_mfma(
    const ushort* __restrict__ Ahi, const ushort* __restrict__ Alo,
    const ushort* __restrict__ BhiT, const ushort* __restrict__ BloT,
    const float* __restrict__ bias, int M, int N, int relu,
    float* __restrict__ Cf, ushort* __restrict__ Chi,
    ushort* __restrict__ Clo) {
  __shared__ __align__(16) ushort ldsA[2][64][40];
  __shared__ __align__(16) ushort ldsB[2][128][40];
  int tid = threadIdx.x;
  int m0 = blockIdx.x * 64, n0 = blockIdx.y * 128;
  int rowA = tid >> 2, chA = (tid & 3) * 8;
  int rowB = tid >> 1, chB = (tid & 1) * 16;
  bool mok = (m0 + rowA) < M;
  const ushort* pAh = Ahi + (size_t)(m0 + rowA) * KPAD + chA;
  const ushort* pAl = Alo + (size_t)(m0 + rowA) * KPAD + chA;
  const ushort* pBh = BhiT + (size_t)(n0 + rowB) * KPAD + chB;
  const ushort* pBl = BloT + (size_t)(n0 + rowB) * KPAD + chB;
  uint4 rAh, rAl, rBh0, rBh1, rBl0, rBl1;
  uint4 z4; z4.x = z4.y = z4.z = z4.w = 0;
  auto ld = [&](int c) {
    int o = c * 32;
    rAh = mok ? *(const uint4*)(pAh + o) : z4;
    rAl = mok ? *(const uint4*)(pAl + o) : z4;
    rBh0 = *(const uint4*)(pBh + o);
    rBh1 = *(const uint4*)(pBh + o + 8);
    rBl0 = *(const uint4*)(pBl + o);
    rBl1 = *(const uint4*)(pBl + o + 8);
  };
  auto st = [&]() {
    *(uint4*)&ldsA[0][rowA][chA] = rAh;
    *(uint4*)&ldsA[1][rowA][chA] = rAl;
    *(uint4*)&ldsB[0][rowB][chB] = rBh0;
    *(uint4*)&ldsB[0][rowB][chB + 8] = rBh1;
    *(uint4*)&ldsB[1][rowB][chB] = rBl0;
    *(uint4*)&ldsB[1][rowB][chB + 8] = rBl1;
  };
  int w = tid >> 6, lane = tid & 63;
  int q = lane >> 4, l16 = lane & 15;
  int mh = w >> 1, nh = w & 1;
  f32x4 zf = {0.f, 0.f, 0.f, 0.f};
  f32x4 acc[2][4];
#pragma unroll
  for (int s = 0; s < 2; ++s)
#pragma unroll
    for (int t = 0; t < 4; ++t) acc[s][t] = zf;
  ld(0); st(); __syncthreads();
  for (int c = 0; c < 10; ++c) {
    if (c < 9) ld(c + 1);
    bf16x8 ah0 = *(const bf16x8*)&ldsA[0][mh * 32 + l16][q * 8];
    bf16x8 ah1 = *(const bf16x8*)&ldsA[0][mh * 32 + 16 + l16][q * 8];
    bf16x8 al0 = *(const bf16x8*)&ldsA[1][mh * 32 + l16][q * 8];
    bf16x8 al1 = *(const bf16x8*)&ldsA[1][mh * 32 + 16 + l16][q * 8];
#pragma unroll
    for (int t = 0; t < 4; ++t) {
      int brow = nh * 64 + t * 16 + l16;
      bf16x8 bh = *(const bf16x8*)&ldsB[0][brow][q * 8];
      bf16x8 bl = *(const bf16x8*)&ldsB[1][brow][q * 8];
      acc[0][t] = __builtin_amdgcn_mfma_f32_16x16x32_bf16(ah0, bh, acc[0][t], 0, 0, 0);
      acc[0][t] = __builtin_amdgcn_mfma_f32_16x16x32_bf16(ah0, bl, acc[0][t], 0, 0, 0);
      acc[0][t] = __builtin_amdgcn_mfma_f32_16x16x32_bf16(al0, bh, acc[0][t], 0, 0, 0);
      acc[1][t] = __builtin_amdgcn_mfma_f32_16x16x32_bf16(ah1, bh, acc[1][t], 0, 0, 0);
      acc[1][t] = __builtin_amdgcn_mfma_f32_16x16x32_bf16(ah1, bl, acc[1][t], 0, 0, 0);
      acc[1][t] = __builtin_amdgcn_mfma_f32_16x16x32_bf16(al1, bh, acc[1][t], 0, 0, 0);
    }
    __syncthreads();
    if (c < 9) st();
    __syncthreads();
  }
#pragma unroll
  for (int t = 0; t < 4; ++t) {
    int n = n0 + nh * 64 + t * 16 + l16;
    bool nin = n < N;
    float bz = (bias && nin) ? bias[n] : 0.f;
#pragma unroll
    for (int s = 0; s < 2; ++s) {
#pragma unroll
      for (int r = 0; r < 4; ++r) {
        int m = m0 + mh * 32 + s * 16 + q * 4 + r;
        if (m >= M) continue;
        float v = acc[s][t][r] + bz;
        if (relu) v = v > 0.f ? v : 0.f;
        if (Cf && nin) Cf[(size_t)m * N + n] = v;
        if (Chi && n < KPAD) {
          ushort h = 0, l = 0;
          if (nin) { h = f2bf(v); l = f2bf(v - bf2f(h)); }
          Chi[(size_t)m * KPAD + n] = h;
          Clo[(size_t)m * KPAD + n] = l;
        }
      }
    }
  }
}

// --- K4: normalize henc (hi/lo) -> hn hi/lo [NS][KPAD] (unit rows) ---------
__global__ __launch_bounds__(256) void k_norm_split(
    const ushort* __restrict__ hehi, const ushort* __restrict__ helo,
    ushort* __restrict__ hnhi, ushort* __restrict__ hnlo) {
  int s = blockIdx.x * 4 + (threadIdx.x >> 6);
  int lane = threadIdx.x & 63;
  if (s >= NS) return;
  const ushort* ph = hehi + (size_t)s * KPAD;
  const ushort* pl = helo + (size_t)s * KPAD;
  float x[5];
  float ss = 0.f;
#pragma unroll
  for (int q = 0; q < 5; ++q) {
    int d = lane + q * 64;
    x[q] = bf2f(ph[d]) + bf2f(pl[d]);
    ss += x[q] * x[q];
  }
#pragma unroll
  for (int off = 32; off > 0; off >>= 1) ss += __shfl_down(ss, off, 64);
  ss = __shfl(ss, 0, 64);
  float inv = 1.f / (sqrtf(ss) + 1e-8f);
  ushort* qh = hnhi + (size_t)s * KPAD;
  ushort* ql = hnlo + (size_t)s * KPAD;
#pragma unroll
  for (int q = 0; q < 5; ++q) {
    int d = lane + q * 64;
    float v = x[q] * inv;
    ushort h = f2bf(v);
    qh[d] = h;
    ql[d] = f2bf(v - bf2f(h));
  }
}

// --- K5: cost as gathered MFMA GEMM (hn·hn^T) + fused exp, wave = 32x32 ----
__global__ __launch_bounds__(256) void k_cost_mfma(
    const ushort* __restrict__ hnhi, const ushort* __restrict__ hnlo,
    const int* __restrict__ ridx, const int* __restrict__ cidx,
    const int* __restrict__ rlen, const int* __restrict__ clen,
    float* __restrict__ Kmat) {
  int b = blockIdx.z;
  int r0 = blockIdx.x * 64, c0 = blockIdx.y * 64;
  int rl = rlen[b], cl = clen[b];
  float* Kg = Kmat + (size_t)b * NMAX * MMAX;
  int tid = threadIdx.x;
  if (r0 >= rl || c0 >= cl) {
    for (int l = tid; l < 64 * 16; l += 256) {
      int i = l >> 4, j = (l & 15) << 2;
      *(float4*)&Kg[(size_t)(r0 + i) * MMAX + c0 + j] =
          make_float4(0.f, 0.f, 0.f, 0.f);
    }
    return;
  }
  __shared__ int rix[64], cix[64];
  __shared__ __align__(16) ushort lds[4][64][40];  // Rhi,Rlo,Chi,Clo
  if (tid < 64) rix[tid] = ridx[b * NMAX + r0 + tid];
  else if (tid < 128) cix[tid - 64] = cidx[b * MMAX + c0 + tid - 64];
  __syncthreads();
  int row = tid >> 2, ch = tid & 3;
  const ushort* pRh = hnhi + (size_t)rix[row] * KPAD + ch * 8;
  const ushort* pRl = hnlo + (size_t)rix[row] * KPAD + ch * 8;
  const ushort* pCh = hnhi + (size_t)cix[row] * KPAD + ch * 8;
  const ushort* pCl = hnlo + (size_t)cix[row] * KPAD + ch * 8;
  uint4 rRh, rRl, rCh, rCl;
  auto ld = [&](int c) {
    int o = c * 32;
    rRh = *(const uint4*)(pRh + o);
    rRl = *(const uint4*)(pRl + o);
    rCh = *(const uint4*)(pCh + o);
    rCl = *(const uint4*)(pCl + o);
  };
  auto st = [&]() {
    *(uint4*)&lds[0][row][ch * 8] = rRh;
    *(uint4*)&lds[1][row][ch * 8] = rRl;
    *(uint4*)&lds[2][row][ch * 8] = rCh;
    *(uint4*)&lds[3][row][ch * 8] = rCl;
  };
  int w = tid >> 6, lane = tid & 63;
  int q = lane >> 4, l16 = lane & 15;
  int mh = w >> 1, nh = w & 1;
  f32x4 zf = {0.f, 0.f, 0.f, 0.f};
  f32x4 acc[2][2];
#pragma unroll
  for (int s = 0; s < 2; ++s)
#pragma unroll
    for (int t = 0; t < 2; ++t) acc[s][t] = zf;
  ld(0); st(); __syncthreads();
  for (int c = 0; c < 10; ++c) {
    if (c < 9) ld(c + 1);
    bf16x8 ah0 = *(const bf16x8*)&lds[0][mh * 32 + l16][q * 8];
    bf16x8 ah1 = *(const bf16x8*)&lds[0][mh * 32 + 16 + l16][q * 8];
    bf16x8 al0 = *(const bf16x8*)&lds[1][mh * 32 + l16][q * 8];
    bf16x8 al1 = *(const bf16x8*)&lds[1][mh * 32 + 16 + l16][q * 8];
#pragma unroll
    for (int t = 0; t < 2; ++t) {
      int brow = nh * 32 + t * 16 + l16;
      bf16x8 bh = *(const bf16x8*)&lds[2][brow][q * 8];
      bf16x8 bl = *(const bf16x8*)&lds[3][brow][q * 8];
      acc[0][t] = __builtin_amdgcn_mfma_f32_16x16x32_bf16(ah0, bh, acc[0][t], 0, 0, 0);
      acc[0][t] = __builtin_amdgcn_mfma_f32_16x16x32_bf16(ah0, bl, acc[0][t], 0, 0, 0);
      acc[0][t] = __builtin_amdgcn_mfma_f32_16x16x32_bf16(al0, bh, acc[0][t], 0, 0, 0);
      acc[1][t] = __builtin_amdgcn_mfma_f32_16x16x32_bf16(ah1, bh, acc[1][t], 0, 0, 0);
      acc[1][t] = __builtin_amdgcn_mfma_f32_16x16x32_bf16(ah1, bl, acc[1][t], 0, 0, 0);
      acc[1][t] = __builtin_amdgcn_mfma_f32_16x16x32_bf16(al1, bh, acc[1][t], 0, 0, 0);
    }
    __syncthreads();
    if (c < 9) st();
    __syncthreads();
  }
#pragma unroll
  for (int t = 0; t < 2; ++t) {
    int n = c0 + nh * 32 + t * 16 + l16;
#pragma unroll
    for (int s = 0; s < 2; ++s) {
#pragma unroll
      for (int r = 0; r < 4; ++r) {
        int m = r0 + mh * 32 + s * 16 + q * 4 + r;
        float kv = (m < rl && n < cl) ? expf((acc[s][t][r] - 1.f) / EPSR) : 0.f;
        Kg[(size_t)m * MMAX + n] = kv;
      }
    }
  }
}

// --------- K6: Sinkhorn; emits P and P^T directly as hi/lo bf16 ------------
__global__ __launch_bounds__(512) void k_sinkhorn(
    float* __restrict__ Kmat, const int* __restrict__ rlen,
    const int* __restrict__ clen, ushort* __restrict__ Phi,
    ushort* __restrict__ Plo, ushort* __restrict__ PThi,
    ushort* __restrict__ PTlo) {
  __shared__ __align__(16) float vq[4][36];
  __shared__ __align__(16) float uq[4][36];
  int b = blockIdx.x;
  int tid = threadIdx.x;
  int n = tid >> 2, q = tid & 3;
  int rl = rlen[b], cl = clen[b];
  float* Kg = Kmat + (size_t)b * NMAX * MMAX;
  float kr[32], kt[32];
  const float4* Kg4 = (const float4*)(Kg + (size_t)n * MMAX + 32 * q);
#pragma unroll
  for (int t = 0; t < 8; ++t) *(float4*)&kr[4 * t] = Kg4[t];
#pragma unroll
  for (int j = 0; j < 32; ++j) kt[j] = Kg[(size_t)(32 * q + j) * MMAX + n];
  if (tid < 128) vq[tid >> 5][tid & 31] = (tid < cl) ? 1.f : 0.f;
  float av = (n < rl) ? 1.f / (float)rl : 0.f;
  float bv = (n < cl) ? 1.f / (float)cl : 0.f;
  float un = 0.f;
  __syncthreads();
  for (int it = 0; it < SITERS; ++it) {
    float s = 0.f;
#pragma unroll
    for (int t = 0; t < 8; ++t) {
      float4 vv = *(const float4*)&vq[q][4 * t];
      s += kr[4 * t + 0] * vv.x + kr[4 * t + 1] * vv.y +
           kr[4 * t + 2] * vv.z + kr[4 * t + 3] * vv.w;
    }
    s += __shfl_xor(s, 1, 64);
    s += __shfl_xor(s, 2, 64);
    un = (n < rl) ? av / s : 0.f;
    if (q == 0) uq[n >> 5][n & 31] = un;
    __syncthreads();
    float s2 = 0.f;
#pragma unroll
    for (int t = 0; t < 8; ++t) {
      float4 uu = *(const float4*)&uq[q][4 * t];
      s2 += kt[4 * t + 0] * uu.x + kt[4 * t + 1] * uu.y +
            kt[4 * t + 2] * uu.z + kt[4 * t + 3] * uu.w;
    }
    s2 += __shfl_xor(s2, 1, 64);
    s2 += __shfl_xor(s2, 2, 64);
    float vm = (n < cl) ? bv / s2 : 0.f;
    if (q == 0) vq[n >> 5][n & 31] = vm;
    __syncthreads();
  }
  float vn = vq[n >> 5][n & 31];
  size_t rowoff = (size_t)b * (NMAX * MMAX) + (size_t)n * MMAX + 32 * q;
  // P hi/lo
  {
    uint hw[16], lw[16];
#pragma unroll
    for (int t = 0; t < 16; ++t) {
      float p0 = un * kr[2 * t] * vq[q][2 * t];
      float p1 = un * kr[2 * t + 1] * vq[q][2 * t + 1];
      ushort h0 = f2bf(p0), h1 = f2bf(p1);
      hw[t] = (uint)h0 | ((uint)h1 << 16);
      lw[t] = (uint)f2bf(p0 - bf2f(h0)) | ((uint)f2bf(p1 - bf2f(h1)) << 16);
    }
#pragma unroll
    for (int t4 = 0; t4 < 4; ++t4) {
      uint4 vh = make_uint4(hw[4 * t4], hw[4 * t4 + 1], hw[4 * t4 + 2], hw[4 * t4 + 3]);
      uint4 vl = make_uint4(lw[4 * t4], lw[4 * t4 + 1], lw[4 * t4 + 2], lw[4 * t4 + 3]);
      *(uint4*)(Phi + rowoff + 8 * t4) = vh;
      *(uint4*)(Plo + rowoff + 8 * t4) = vl;
    }
  }
  // P^T hi/lo
  {
    uint hw[16], lw[16];
#pragma unroll
    for (int t = 0; t < 16; ++t) {
      float p0 = uq[q][2 * t] * kt[2 * t] * vn;
      float p1 = uq[q][2 * t + 1] * kt[2 * t + 1] * vn;
      ushort h0 = f2bf(p0), h1 = f2bf(p1);
      hw[t] = (uint)h0 | ((uint)h1 << 16);
      lw[t] = (uint)f2bf(p0 - bf2f(h0)) | ((uint)f2bf(p1 - bf2f(h1)) << 16);
    }
#pragma unroll
    for (int t4 = 0; t4 < 4; ++t4) {
      uint4 vh = make_uint4(hw[4 * t4], hw[4 * t4 + 1], hw[4 * t4 + 2], hw[4 * t4 + 3]);
      uint4 vl = make_uint4(lw[4 * t4], lw[4 * t4 + 1], lw[4 * t4 + 2], lw[4 * t4 + 3]);
      *(uint4*)(PThi + rowoff + 8 * t4) = vh;
      *(uint4*)(PTlo + rowoff + 8 * t4) = vl;
    }
  }
}

// ---- K7: attend + compare + masked sum as MFMA GEMM (hi/lo 3-term) --------
// R7: K split into two 64-wide passes so G-LDS halves (32KB -> 16KB,
// block LDS ~18.3KB) -> LDS allows 8 blocks/CU (was 4). Per-pass A-fragment
// registers also halve. ~Half the (b,side) pairs have lo<=64 -> single pass.
// Swizzle domain is now 8 16B-blocks/row: phys8 = kb8 ^ (row&7); write side
// spreads 64 lanes evenly over all 32 banks, read side 2-way (free).
__global__ __launch_bounds__(256) void k_att_mfma(
    const ushort* __restrict__ Phi, const ushort* __restrict__ Plo,
    const ushort* __restrict__ PThi, const ushort* __restrict__ PTlo,
    const float* __restrict__ HcB, const int* __restrict__ row_idx,
    const int* __restrict__ col_idx, const int* __restrict__ row_len,
    const int* __restrict__ col_len, const float* __restrict__ bc,
    float* __restrict__ cr, float* __restrict__ cc) {
  int b = blockIdx.y;
  int side = blockIdx.z;
  int c0 = blockIdx.x * 64;
  const int* idx_main = side == 0 ? row_idx : col_idx;
  const int* idx_other = side == 0 ? col_idx : row_idx;
  int lm = side == 0 ? row_len[b] : col_len[b];
  int lo = side == 0 ? col_len[b] : row_len[b];
  const ushort* Ah = (side == 0 ? Phi : PThi) + (size_t)b * (NMAX * MMAX);
  const ushort* Al = (side == 0 ? Plo : PTlo) + (size_t)b * (NMAX * MMAX);
  float* outacc = side == 0 ? cr : cc;

  __shared__ __align__(16) ushort gldh[64][64];  // [d][k-half], swizzled 16B
  __shared__ __align__(16) ushort gldl[64][64];
  __shared__ float red[4][64];
  __shared__ int iox[NMAX];
  __shared__ int imx[NMAX];

  int tid = threadIdx.x;
  int w = tid >> 6, lane = tid & 63;
  int q = lane >> 4, l16 = lane & 15;
  if (tid < 128) iox[tid] = idx_other[b * NMAX + tid];
  else imx[tid - 128] = idx_main[b * NMAX + tid - 128];
  __syncthreads();

  int khmax = (lo > 64) ? 2 : 1;
  int ndt = (300 - c0 + 15) >> 4;
  if (ndt > 4) ndt = 4;
  bool dok = (c0 + lane) < 300;

  int i0a = w * 16;
  int i0b = 64 + w * 16;
  bool act0 = i0a < lm;
  bool act1 = i0b < lm;

  f32x4 zf = {0.f, 0.f, 0.f, 0.f};
  f32x4 acc0[4], acc1[4];
#pragma unroll
  for (int dt = 0; dt < 4; ++dt) { acc0[dt] = zf; acc1[dt] = zf; }

  for (int kh = 0; kh < khmax; ++kh) {
    int kbase = kh * 64;
    // ---- stage G transposed [d][k-local]: lane=row d, wave w covers 16 k --
    {
      float gv[16];
#pragma unroll
      for (int t = 0; t < 16; ++t) {
        int k = kbase + w * 16 + t;
        gv[t] = (k < lo && dok) ? HcB[(size_t)iox[k] * 600 + 300 + c0 + lane]
                                : 0.f;
      }
#pragma unroll
      for (int blk = 0; blk < 2; ++blk) {
        int kb8 = 2 * w + blk;
        int phys = kb8 ^ (lane & 7);
        ushort hb[8], lb[8];
#pragma unroll
        for (int e = 0; e < 8; ++e) {
          float v = gv[blk * 8 + e];
          ushort h = f2bf(v);
          hb[e] = h;
          lb[e] = f2bf(v - bf2f(h));
        }
        *(uint4*)&gldh[lane][phys * 8] = *(uint4*)hb;
        *(uint4*)&gldl[lane][phys * 8] = *(uint4*)lb;
      }
    }
    __syncthreads();

    // ---- A fragments for this K-half (2 chunks of 32) ---------------------
    bf16x8 fa0h[2], fa0l[2], fa1h[2], fa1l[2];
#pragma unroll
    for (int c = 0; c < 2; ++c) {
      size_t oa = (size_t)(i0a + l16) * MMAX + kbase + 32 * c + 8 * q;
      size_t ob = (size_t)(i0b + l16) * MMAX + kbase + 32 * c + 8 * q;
      if (act0) {
        fa0h[c] = *(const bf16x8*)&Ah[oa];
        fa0l[c] = *(const bf16x8*)&Al[oa];
      }
      if (act1) {
        fa1h[c] = *(const bf16x8*)&Ah[ob];
        fa1l[c] = *(const bf16x8*)&Al[ob];
      }
    }

#pragma unroll
    for (int c = 0; c < 2; ++c) {
      int phys = (4 * c + q) ^ (l16 & 7);  // swizzled 16B block (k-local)
#pragma unroll
      for (int dt = 0; dt < 4; ++dt) {
        if (dt < ndt) {
          int d = dt * 16 + l16;
          bf16x8 bh = *(const bf16x8*)&gldh[d][phys * 8];
          bf16x8 bl = *(const bf16x8*)&gldl[d][phys * 8];
          if (act0) {
            acc0[dt] = __builtin_amdgcn_mfma_f32_16x16x32_bf16(fa0h[c], bh, acc0[dt], 0, 0, 0);
            acc0[dt] = __builtin_amdgcn_mfma_f32_16x16x32_bf16(fa0h[c], bl, acc0[dt], 0, 0, 0);
            acc0[dt] = __builtin_amdgcn_mfma_f32_16x16x32_bf16(fa0l[c], bh, acc0[dt], 0, 0, 0);
          }
          if (act1) {
            acc1[dt] = __builtin_amdgcn_mfma_f32_16x16x32_bf16(fa1h[c], bh, acc1[dt], 0, 0, 0);
            acc1[dt] = __builtin_amdgcn_mfma_f32_16x16x32_bf16(fa1h[c], bl, acc1[dt], 0, 0, 0);
            acc1[dt] = __builtin_amdgcn_mfma_f32_16x16x32_bf16(fa1l[c], bh, acc1[dt], 0, 0, 0);
          }
        }
      }
    }
    if (kh + 1 < khmax) __syncthreads();  // protect gld before restage
  }

  // ---- epilogue: + main + bias, relu, column partial sums -----------------
  float psum[4] = {0.f, 0.f, 0.f, 0.f};
  float bcv[4];
#pragma unroll
  for (int dt = 0; dt < 4; ++dt) {
    int col = c0 + dt * 16 + l16;
    bcv[dt] = (col < 300) ? bc[col] : 0.f;
  }
#pragma unroll
  for (int s = 0; s < 2; ++s) {
    bool act = (s == 0) ? act0 : act1;
    if (!act) continue;
    int ibase = ((s == 0) ? i0a : i0b) + q * 4;
#pragma unroll
    for (int r = 0; r < 4; ++r) {
      int i = ibase + r;
      if (i >= lm) continue;
      const float* Mrow = &HcB[(size_t)imx[i] * 600];
#pragma unroll
      for (int dt = 0; dt < 4; ++dt) {
        int col = c0 + dt * 16 + l16;
        if (dt < ndt && col < 300) {
          float av = (s == 0) ? acc0[dt][r] : acc1[dt][r];
          float y = av + Mrow[col] + bcv[dt];
          psum[dt] += y > 0.f ? y : 0.f;
        }
      }
    }
  }
#pragma unroll
  for (int dt = 0; dt < 4; ++dt) {
    psum[dt] += __shfl_xor(psum[dt], 16, 64);
    psum[dt] += __shfl_xor(psum[dt], 32, 64);
  }
  if (lane < 16) {
#pragma unroll
    for (int dt = 0; dt < 4; ++dt) red[w][dt * 16 + lane] = psum[dt];
  }
  __syncthreads();
  if (tid < 64) {
    float s = red[0][tid] + red[1][tid] + red[2][tid] + red[3][tid];
    int col = c0 + tid;
    if (col < 300) outacc[(size_t)b * HDIM + col] = s;
  }
}

// ---------------- K8: classifier head -> out [B,2] -------------------------
__global__ __launch_bounds__(320) void k_cls(
    const float* __restrict__ cr, const float* __restrict__ cc,
    const float* __restrict__ Wcls, const float* __restrict__ bcls,
    const float* __restrict__ Wout, const float* __restrict__ bout,
    float* __restrict__ out) {
  __shared__ __align__(16) float cz[2 * HDIM];
  __shared__ float zz[HDIM];
  int b = blockIdx.x, tid = threadIdx.x;
  if (tid < HDIM) {
    cz[tid] = cr[(size_t)b * HDIM + tid];
    cz[HDIM + tid] = cc[(size_t)b * HDIM + tid];
  }
  __syncthreads();
  if (tid < HDIM) {
    float acc = bcls[tid];
    for (int k4 = 0; k4 < 2 * HDIM; k4 += 4) {
      float4 c = *(const float4*)&cz[k4];
      acc += c.x * Wcls[(size_t)(k4 + 0) * HDIM + tid] +
             c.y * Wcls[(size_t)(k4 + 1) * HDIM + tid] +
             c.z * Wcls[(size_t)(k4 + 2) * HDIM + tid] +
             c.w * Wcls[(size_t)(k4 + 3) * HDIM + tid];
    }
    zz[tid] = acc > 0.f ? acc : 0.f;
  }
  __syncthreads();
  int o = tid >> 6, lane = tid & 63;
  if (o < 2) {
    float p = 0.f;
    for (int j = lane; j < HDIM; j += 64) p += zz[j] * Wout[(size_t)j * 2 + o];
#pragma unroll
    for (int off = 32; off > 0; off >>= 1) p += __shfl_down(p, off, 64);
    if (lane == 0) out[b * 2 + o] = p + bout[o];
  }
}

extern "C" void kernel_launch(void* const* d_in, const int* in_sizes, int n_in,
                              void* d_out, int out_size, void* d_ws, size_t ws_size,
                              hipStream_t stream) {
  (void)in_sizes; (void)n_in; (void)out_size; (void)ws_size;
  const int* data = (const int*)d_in[0];
  const int* row_idx = (const int*)d_in[1];
  const int* col_idx = (const int*)d_in[2];
  const int* row_len = (const int*)d_in[3];
  const int* col_len = (const int*)d_in[4];
  const float* emb = (const float*)d_in[5];
  const float* W1 = (const float*)d_in[6];
  const float* b1 = (const float*)d_in[7];
  const float* W2 = (const float*)d_in[8];
  const float* b2 = (const float*)d_in[9];
  const float* Wc = (const float*)d_in[10];
  const float* bc = (const float*)d_in[11];
  const float* Wcls = (const float*)d_in[12];
  const float* bcls = (const float*)d_in[13];
  const float* Wout = (const float*)d_in[14];
  const float* bout = (const float*)d_in[15];
  float* out = (float*)d_out;

  char* wp = (char*)d_ws;
  auto carve = [&](size_t bytes) {
    char* p = wp; wp += (bytes + 255) & ~(size_t)255; return p;
  };
  ushort* enchi = (ushort*)carve((size_t)NS * KPAD * 2);
  ushort* enclo = (ushort*)carve((size_t)NS * KPAD * 2);
  ushort* h1hi = (ushort*)carve((size_t)NS * KPAD * 2);
  ushort* h1lo = (ushort*)carve((size_t)NS * KPAD * 2);
  ushort* hehi = (ushort*)carve((size_t)NS * KPAD * 2);
  ushort* helo = (ushort*)carve((size_t)NS * KPAD * 2);
  ushort* hnhi = (ushort*)carve((size_t)NS * KPAD * 2);
  ushort* hnlo = (ushort*)carve((size_t)NS * KPAD * 2);
  ushort* W1hi = (ushort*)carve((size_t)NPADW * KPAD * 2);
  ushort* W1lo = (ushort*)carve((size_t)NPADW * KPAD * 2);
  ushort* W2hi = (ushort*)carve((size_t)NPADW * KPAD * 2);
  ushort* W2lo = (ushort*)carve((size_t)NPADW * KPAD * 2);
  ushort* Wchi = (ushort*)carve((size_t)640 * KPAD * 2);
  ushort* Wclo = (ushort*)carve((size_t)640 * KPAD * 2);
  float* HcB = (float*)carve((size_t)NS * 600 * 4);
  float* Km = (float*)carve((size_t)BB * NMAX * MMAX * 4);
  float* cr = (float*)carve((size_t)BB * HDIM * 4);
  float* cc = (float*)carve((size_t)BB * HDIM * 4);

  // bf16 hi/lo P and P^T alias buffers that are DEAD by k_sinkhorn time.
  ushort* Phi = enchi;
  ushort* Plo = h1hi;
  ushort* PThi = hehi;
  ushort* PTlo = hnhi;

  int gM = (NS + 63) / 64;  // 157
  int cvtTotal = 2 * NPADW * KPAD + 640 * KPAD;

  k_embed<<<NS, 256, 0, stream>>>(data, emb, enchi, enclo);
  k_cvt_all<<<(cvtTotal + 255) / 256, 256, 0, stream>>>(
      W1, W2, Wc, W1hi, W1lo, W2hi, W2lo, Wchi, Wclo);
  k_gemm_mfma<<<dim3(gM, 3), 256, 0, stream>>>(
      enchi, enclo, W1hi, W1lo, b1, NS, HDIM, 1, nullptr, h1hi, h1lo);
  k_gemm_mfma<<<dim3(gM, 3), 256, 0, stream>>>(
      h1hi, h1lo, W2hi, W2lo, b2, NS, HDIM, 1, nullptr, hehi, helo);
  k_norm_split<<<(NS + 3) / 4, 256, 0, stream>>>(hehi, helo, hnhi, hnlo);
  k_gemm_mfma<<<dim3(gM, 5), 256, 0, stream>>>(
      hehi, helo, Wchi, Wclo, nullptr, NS, 2 * HDIM, 0, HcB, nullptr, nullptr);
  k_cost_mfma<<<dim3(2, 2, BB), 256, 0, stream>>>(hnhi, hnlo, row_idx, col_idx,
                                                  row_len, col_len, Km);
  k_sinkhorn<<<BB, 512, 0, stream>>>(Km, row_len, col_len, Phi, Plo, PThi, PTlo);
  k_att_mfma<<<dim3(5, BB, 2), 256, 0, stream>>>(
      Phi, Plo, PThi, PTlo, HcB, row_idx, col_idx, row_len, col_len, bc, cr, cc);
  k_cls<<<BB, 320, 0, stream>>>(cr, cc, Wcls, bcls, Wout, bout, out);
}

// Round 8
// 361.384 us; speedup vs baseline: 1.1675x; 1.0647x over previous
//
#include <hip/hip_runtime.h>
#include <math.h>

#define NS 10000
#define LSEQ 32
#define DDIM 300
#define HDIM 300
#define BB 256
#define NMAX 128
#define MMAX 128
#define EPSR 0.1f
#define SITERS 50
#define KPAD 320
#define NPADW 384

typedef __attribute__((ext_vector_type(8))) short bf16x8;
typedef __attribute__((ext_vector_type(4))) float f32x4;

__device__ __forceinline__ ushort f2bf(float x) {
  union { float f; unsigned u; } c; c.f = x;
  unsigned r = (c.u + 0x7fffu + ((c.u >> 16) & 1u)) >> 16;
  return (ushort)r;
}
__device__ __forceinline__ float bf2f(ushort h) {
  union { unsigned u; float f; } c; c.u = ((unsigned)h) << 16;
  return c.f;
}

// ------- K1: embedding + masked mean pool -> enc hi/lo [NS][KPAD] bf16 -----
__global__ __launch_bounds__(256) void k_embed(const int* __restrict__ data,
                                               const float* __restrict__ emb,
                                               ushort* __restrict__ enchi,
                                               ushort* __restrict__ enclo) {
  __shared__ int ids[LSEQ];
  __shared__ __align__(16) float4 part[3][76];
  int s = blockIdx.x;
  int tid = threadIdx.x;
  if (tid < LSEQ) ids[tid] = data[s * LSEQ + tid];
  __syncthreads();
  int cnt = 0;
#pragma unroll
  for (int t = 0; t < LSEQ; ++t) cnt += (ids[t] != 0) ? 1 : 0;
  int g = tid / 75, d = tid - g * 75;
  const float4* emb4 = (const float4*)emb;
  if (g < 3) {
    float4 acc = make_float4(0.f, 0.f, 0.f, 0.f);
    for (int t = g; t < LSEQ; t += 3) {
      int id = ids[t];
      if (id != 0) {
        float4 e = emb4[(size_t)id * 75 + d];
        acc.x += e.x; acc.y += e.y; acc.z += e.z; acc.w += e.w;
      }
    }
    part[g][d] = acc;
  }
  __syncthreads();
  if (g == 0) {
    float4 a = part[0][d], b = part[1][d], c = part[2][d];
    float inv = 1.f / (float)(cnt > 0 ? cnt : 1);
    float v[4] = {(a.x + b.x + c.x) * inv, (a.y + b.y + c.y) * inv,
                  (a.z + b.z + c.z) * inv, (a.w + b.w + c.w) * inv};
    ushort4 h, l;
    h.x = f2bf(v[0]); l.x = f2bf(v[0] - bf2f(h.x));
    h.y = f2bf(v[1]); l.y = f2bf(v[1] - bf2f(h.y));
    h.z = f2bf(v[2]); l.z = f2bf(v[2] - bf2f(h.z));
    h.w = f2bf(v[3]); l.w = f2bf(v[3] - bf2f(h.w));
    *(ushort4*)&enchi[(size_t)s * KPAD + d * 4] = h;
    *(ushort4*)&enclo[(size_t)s * KPAD + d * 4] = l;
  } else if (g == 1 && d < 5) {
    ushort4 z; z.x = z.y = z.z = z.w = 0;
    *(ushort4*)&enchi[(size_t)s * KPAD + 300 + d * 4] = z;
    *(ushort4*)&enclo[(size_t)s * KPAD + 300 + d * 4] = z;
  }
}

// ------- K2: all weight converts in one dispatch ---------------------------
__global__ __launch_bounds__(256) void k_cvt_all(
    const float* __restrict__ W1, const float* __restrict__ W2,
    const float* __restrict__ Wc, ushort* __restrict__ W1hi,
    ushort* __restrict__ W1lo, ushort* __restrict__ W2hi,
    ushort* __restrict__ W2lo, ushort* __restrict__ Wchi,
    ushort* __restrict__ Wclo) {
  int i = blockIdx.x * 256 + threadIdx.x;
  const int SA = NPADW * KPAD;
  const int SC = 640 * KPAD;
  float v = 0.f;
  ushort *ph, *pl;
  int idx;
  if (i < SA) {
    idx = i;
    int n = idx / KPAD, k = idx - n * KPAD;
    if (n < HDIM && k < DDIM) v = W1[(size_t)k * HDIM + n];
    ph = W1hi; pl = W1lo;
  } else if (i < 2 * SA) {
    idx = i - SA;
    int n = idx / KPAD, k = idx - n * KPAD;
    if (n < HDIM && k < HDIM) v = W2[(size_t)k * HDIM + n];
    ph = W2hi; pl = W2lo;
  } else if (i < 2 * SA + SC) {
    idx = i - 2 * SA;
    int n = idx / KPAD, k = idx - n * KPAD;
    if (k < HDIM && n < 2 * HDIM)
      v = (n < HDIM) ? Wc[(size_t)k * HDIM + n]
                     : Wc[(size_t)(HDIM + k) * HDIM + (n - HDIM)];
    ph = Wchi; pl = Wclo;
  } else {
    return;
  }
  ushort h = f2bf(v);
  ph[idx] = h;
  pl[idx] = f2bf(v - bf2f(h));
}

// ------- K3: MFMA GEMM, hi/lo 3-term, 64x128 tile, wave = 32x64 ------------
__global__ __launch_bounds__(256) void k_gemm_mfma(
    const ushort* __restrict__ Ahi, const ushort* __restrict__ Alo,
    const ushort* __restrict__ BhiT, const ushort* __restrict__ BloT,
    const float* __restrict__ bias, int M, int N, int relu,
    float* __restrict__ Cf, ushort* __restrict__ Chi,
    ushort* __restrict__ Clo) {
  __shared__ __align__(16) ushort ldsA[2][64][40];
  __shared__ __align__(16) ushort ldsB[2][128][40];
  int tid = threadIdx.x;
  int m0 = blockIdx.x * 64, n0 = blockIdx.y * 128;
  int rowA = tid >> 2, chA = (tid & 3) * 8;
  int rowB = tid >> 1, chB = (tid & 1) * 16;
  bool mok = (m0 + rowA) < M;
  const ushort* pAh = Ahi + (size_t)(m0 + rowA) * KPAD + chA;
  const ushort* pAl = Alo + (size_t)(m0 + rowA) * KPAD + chA;
  const ushort* pBh = BhiT + (size_t)(n0 + rowB) * KPAD + chB;
  const ushort* pBl = BloT + (size_t)(n0 + rowB) * KPAD + chB;
  uint4 rAh, rAl, rBh0, rBh1, rBl0, rBl1;
  uint4 z4; z4.x = z4.y = z4.z = z4.w = 0;
  auto ld = [&](int c) {
    int o = c * 32;
    rAh = mok ? *(const uint4*)(pAh + o) : z4;
    rAl = mok ? *(const uint4*)(pAl + o) : z4;
    rBh0 = *(const uint4*)(pBh + o);
    rBh1 = *(const uint4*)(pBh + o + 8);
    rBl0 = *(const uint4*)(pBl + o);
    rBl1 = *(const uint4*)(pBl + o + 8);
  };
  auto st = [&]() {
    *(uint4*)&ldsA[0][rowA][chA] = rAh;
    *(uint4*)&ldsA[1][rowA][chA] = rAl;
    *(uint4*)&ldsB[0][rowB][chB] = rBh0;
    *(uint4*)&ldsB[0][rowB][chB + 8] = rBh1;
    *(uint4*)&ldsB[1][rowB][chB] = rBl0;
    *(uint4*)&ldsB[1][rowB][chB + 8] = rBl1;
  };
  int w = tid >> 6, lane = tid & 63;
  int q = lane >> 4, l16 = lane & 15;
  int mh = w >> 1, nh = w & 1;
  f32x4 zf = {0.f, 0.f, 0.f, 0.f};
  f32x4 acc[2][4];
#pragma unroll
  for (int s = 0; s < 2; ++s)
#pragma unroll
    for (int t = 0; t < 4; ++t) acc[s][t] = zf;
  ld(0); st(); __syncthreads();
  for (int c = 0; c < 10; ++c) {
    if (c < 9) ld(c + 1);
    bf16x8 ah0 = *(const bf16x8*)&ldsA[0][mh * 32 + l16][q * 8];
    bf16x8 ah1 = *(const bf16x8*)&ldsA[0][mh * 32 + 16 + l16][q * 8];
    bf16x8 al0 = *(const bf16x8*)&ldsA[1][mh * 32 + l16][q * 8];
    bf16x8 al1 = *(const bf16x8*)&ldsA[1][mh * 32 + 16 + l16][q * 8];
#pragma unroll
    for (int t = 0; t < 4; ++t) {
      int brow = nh * 64 + t * 16 + l16;
      bf16x8 bh = *(const bf16x8*)&ldsB[0][brow][q * 8];
      bf16x8 bl = *(const bf16x8*)&ldsB[1][brow][q * 8];
      acc[0][t] = __builtin_amdgcn_mfma_f32_16x16x32_bf16(ah0, bh, acc[0][t], 0, 0, 0);
      acc[0][t] = __builtin_amdgcn_mfma_f32_16x16x32_bf16(ah0, bl, acc[0][t], 0, 0, 0);
      acc[0][t] = __builtin_amdgcn_mfma_f32_16x16x32_bf16(al0, bh, acc[0][t], 0, 0, 0);
      acc[1][t] = __builtin_amdgcn_mfma_f32_16x16x32_bf16(ah1, bh, acc[1][t], 0, 0, 0);
      acc[1][t] = __builtin_amdgcn_mfma_f32_16x16x32_bf16(ah1, bl, acc[1][t], 0, 0, 0);
      acc[1][t] = __builtin_amdgcn_mfma_f32_16x16x32_bf16(al1, bh, acc[1][t], 0, 0, 0);
    }
    __syncthreads();
    if (c < 9) st();
    __syncthreads();
  }
#pragma unroll
  for (int t = 0; t < 4; ++t) {
    int n = n0 + nh * 64 + t * 16 + l16;
    bool nin = n < N;
    float bz = (bias && nin) ? bias[n] : 0.f;
#pragma unroll
    for (int s = 0; s < 2; ++s) {
#pragma unroll
      for (int r = 0; r < 4; ++r) {
        int m = m0 + mh * 32 + s * 16 + q * 4 + r;
        if (m >= M) continue;
        float v = acc[s][t][r] + bz;
        if (relu) v = v > 0.f ? v : 0.f;
        if (Cf && nin) Cf[(size_t)m * N + n] = v;
        if (Chi && n < KPAD) {
          ushort h = 0, l = 0;
          if (nin) { h = f2bf(v); l = f2bf(v - bf2f(h)); }
          Chi[(size_t)m * KPAD + n] = h;
          Clo[(size_t)m * KPAD + n] = l;
        }
      }
    }
  }
}

// --- K4: normalize henc (hi/lo) -> hn hi/lo [NS][KPAD] (unit rows) ---------
__global__ __launch_bounds__(256) void k_norm_split(
    const ushort* __restrict__ hehi, const ushort* __restrict__ helo,
    ushort* __restrict__ hnhi, ushort* __restrict__ hnlo) {
  int s = blockIdx.x * 4 + (threadIdx.x >> 6);
  int lane = threadIdx.x & 63;
  if (s >= NS) return;
  const ushort* ph = hehi + (size_t)s * KPAD;
  const ushort* pl = helo + (size_t)s * KPAD;
  float x[5];
  float ss = 0.f;
#pragma unroll
  for (int q = 0; q < 5; ++q) {
    int d = lane + q * 64;
    x[q] = bf2f(ph[d]) + bf2f(pl[d]);
    ss += x[q] * x[q];
  }
#pragma unroll
  for (int off = 32; off > 0; off >>= 1) ss += __shfl_down(ss, off, 64);
  ss = __shfl(ss, 0, 64);
  float inv = 1.f / (sqrtf(ss) + 1e-8f);
  ushort* qh = hnhi + (size_t)s * KPAD;
  ushort* ql = hnlo + (size_t)s * KPAD;
#pragma unroll
  for (int q = 0; q < 5; ++q) {
    int d = lane + q * 64;
    float v = x[q] * inv;
    ushort h = f2bf(v);
    qh[d] = h;
    ql[d] = f2bf(v - bf2f(h));
  }
}

// --- K5: cost as gathered MFMA GEMM (hn·hn^T) + fused exp, wave = 32x32 ----
__global__ __launch_bounds__(256) void k_cost_mfma(
    const ushort* __restrict__ hnhi, const ushort* __restrict__ hnlo,
    const int* __restrict__ ridx, const int* __restrict__ cidx,
    const int* __restrict__ rlen, const int* __restrict__ clen,
    float* __restrict__ Kmat) {
  int b = blockIdx.z;
  int r0 = blockIdx.x * 64, c0 = blockIdx.y * 64;
  int rl = rlen[b], cl = clen[b];
  float* Kg = Kmat + (size_t)b * NMAX * MMAX;
  int tid = threadIdx.x;
  if (r0 >= rl || c0 >= cl) {
    for (int l = tid; l < 64 * 16; l += 256) {
      int i = l >> 4, j = (l & 15) << 2;
      *(float4*)&Kg[(size_t)(r0 + i) * MMAX + c0 + j] =
          make_float4(0.f, 0.f, 0.f, 0.f);
    }
    return;
  }
  __shared__ int rix[64], cix[64];
  __shared__ __align__(16) ushort lds[4][64][40];  // Rhi,Rlo,Chi,Clo
  if (tid < 64) rix[tid] = ridx[b * NMAX + r0 + tid];
  else if (tid < 128) cix[tid - 64] = cidx[b * MMAX + c0 + tid - 64];
  __syncthreads();
  int row = tid >> 2, ch = tid & 3;
  const ushort* pRh = hnhi + (size_t)rix[row] * KPAD + ch * 8;
  const ushort* pRl = hnlo + (size_t)rix[row] * KPAD + ch * 8;
  const ushort* pCh = hnhi + (size_t)cix[row] * KPAD + ch * 8;
  const ushort* pCl = hnlo + (size_t)cix[row] * KPAD + ch * 8;
  uint4 rRh, rRl, rCh, rCl;
  auto ld = [&](int c) {
    int o = c * 32;
    rRh = *(const uint4*)(pRh + o);
    rRl = *(const uint4*)(pRl + o);
    rCh = *(const uint4*)(pCh + o);
    rCl = *(const uint4*)(pCl + o);
  };
  auto st = [&]() {
    *(uint4*)&lds[0][row][ch * 8] = rRh;
    *(uint4*)&lds[1][row][ch * 8] = rRl;
    *(uint4*)&lds[2][row][ch * 8] = rCh;
    *(uint4*)&lds[3][row][ch * 8] = rCl;
  };
  int w = tid >> 6, lane = tid & 63;
  int q = lane >> 4, l16 = lane & 15;
  int mh = w >> 1, nh = w & 1;
  f32x4 zf = {0.f, 0.f, 0.f, 0.f};
  f32x4 acc[2][2];
#pragma unroll
  for (int s = 0; s < 2; ++s)
#pragma unroll
    for (int t = 0; t < 2; ++t) acc[s][t] = zf;
  ld(0); st(); __syncthreads();
  for (int c = 0; c < 10; ++c) {
    if (c < 9) ld(c + 1);
    bf16x8 ah0 = *(const bf16x8*)&lds[0][mh * 32 + l16][q * 8];
    bf16x8 ah1 = *(const bf16x8*)&lds[0][mh * 32 + 16 + l16][q * 8];
    bf16x8 al0 = *(const bf16x8*)&lds[1][mh * 32 + l16][q * 8];
    bf16x8 al1 = *(const bf16x8*)&lds[1][mh * 32 + 16 + l16][q * 8];
#pragma unroll
    for (int t = 0; t < 2; ++t) {
      int brow = nh * 32 + t * 16 + l16;
      bf16x8 bh = *(const bf16x8*)&lds[2][brow][q * 8];
      bf16x8 bl = *(const bf16x8*)&lds[3][brow][q * 8];
      acc[0][t] = __builtin_amdgcn_mfma_f32_16x16x32_bf16(ah0, bh, acc[0][t], 0, 0, 0);
      acc[0][t] = __builtin_amdgcn_mfma_f32_16x16x32_bf16(ah0, bl, acc[0][t], 0, 0, 0);
      acc[0][t] = __builtin_amdgcn_mfma_f32_16x16x32_bf16(al0, bh, acc[0][t], 0, 0, 0);
      acc[1][t] = __builtin_amdgcn_mfma_f32_16x16x32_bf16(ah1, bh, acc[1][t], 0, 0, 0);
      acc[1][t] = __builtin_amdgcn_mfma_f32_16x16x32_bf16(ah1, bl, acc[1][t], 0, 0, 0);
      acc[1][t] = __builtin_amdgcn_mfma_f32_16x16x32_bf16(al1, bh, acc[1][t], 0, 0, 0);
    }
    __syncthreads();
    if (c < 9) st();
    __syncthreads();
  }
#pragma unroll
  for (int t = 0; t < 2; ++t) {
    int n = c0 + nh * 32 + t * 16 + l16;
#pragma unroll
    for (int s = 0; s < 2; ++s) {
#pragma unroll
      for (int r = 0; r < 4; ++r) {
        int m = r0 + mh * 32 + s * 16 + q * 4 + r;
        float kv = (m < rl && n < cl) ? expf((acc[s][t][r] - 1.f) / EPSR) : 0.f;
        Kg[(size_t)m * MMAX + n] = kv;
      }
    }
  }
}

// --------- K6: Sinkhorn; emits P and P^T directly as hi/lo bf16 ------------
__global__ __launch_bounds__(512) void k_sinkhorn(
    float* __restrict__ Kmat, const int* __restrict__ rlen,
    const int* __restrict__ clen, ushort* __restrict__ Phi,
    ushort* __restrict__ Plo, ushort* __restrict__ PThi,
    ushort* __restrict__ PTlo) {
  __shared__ __align__(16) float vq[4][36];
  __shared__ __align__(16) float uq[4][36];
  int b = blockIdx.x;
  int tid = threadIdx.x;
  int n = tid >> 2, q = tid & 3;
  int rl = rlen[b], cl = clen[b];
  float* Kg = Kmat + (size_t)b * NMAX * MMAX;
  float kr[32], kt[32];
  const float4* Kg4 = (const float4*)(Kg + (size_t)n * MMAX + 32 * q);
#pragma unroll
  for (int t = 0; t < 8; ++t) *(float4*)&kr[4 * t] = Kg4[t];
#pragma unroll
  for (int j = 0; j < 32; ++j) kt[j] = Kg[(size_t)(32 * q + j) * MMAX + n];
  if (tid < 128) vq[tid >> 5][tid & 31] = (tid < cl) ? 1.f : 0.f;
  float av = (n < rl) ? 1.f / (float)rl : 0.f;
  float bv = (n < cl) ? 1.f / (float)cl : 0.f;
  float un = 0.f;
  __syncthreads();
  for (int it = 0; it < SITERS; ++it) {
    float s = 0.f;
#pragma unroll
    for (int t = 0; t < 8; ++t) {
      float4 vv = *(const float4*)&vq[q][4 * t];
      s += kr[4 * t + 0] * vv.x + kr[4 * t + 1] * vv.y +
           kr[4 * t + 2] * vv.z + kr[4 * t + 3] * vv.w;
    }
    s += __shfl_xor(s, 1, 64);
    s += __shfl_xor(s, 2, 64);
    un = (n < rl) ? av / s : 0.f;
    if (q == 0) uq[n >> 5][n & 31] = un;
    __syncthreads();
    float s2 = 0.f;
#pragma unroll
    for (int t = 0; t < 8; ++t) {
      float4 uu = *(const float4*)&uq[q][4 * t];
      s2 += kt[4 * t + 0] * uu.x + kt[4 * t + 1] * uu.y +
            kt[4 * t + 2] * uu.z + kt[4 * t + 3] * uu.w;
    }
    s2 += __shfl_xor(s2, 1, 64);
    s2 += __shfl_xor(s2, 2, 64);
    float vm = (n < cl) ? bv / s2 : 0.f;
    if (q == 0) vq[n >> 5][n & 31] = vm;
    __syncthreads();
  }
  float vn = vq[n >> 5][n & 31];
  size_t rowoff = (size_t)b * (NMAX * MMAX) + (size_t)n * MMAX + 32 * q;
  // P hi/lo
  {
    uint hw[16], lw[16];
#pragma unroll
    for (int t = 0; t < 16; ++t) {
      float p0 = un * kr[2 * t] * vq[q][2 * t];
      float p1 = un * kr[2 * t + 1] * vq[q][2 * t + 1];
      ushort h0 = f2bf(p0), h1 = f2bf(p1);
      hw[t] = (uint)h0 | ((uint)h1 << 16);
      lw[t] = (uint)f2bf(p0 - bf2f(h0)) | ((uint)f2bf(p1 - bf2f(h1)) << 16);
    }
#pragma unroll
    for (int t4 = 0; t4 < 4; ++t4) {
      uint4 vh = make_uint4(hw[4 * t4], hw[4 * t4 + 1], hw[4 * t4 + 2], hw[4 * t4 + 3]);
      uint4 vl = make_uint4(lw[4 * t4], lw[4 * t4 + 1], lw[4 * t4 + 2], lw[4 * t4 + 3]);
      *(uint4*)(Phi + rowoff + 8 * t4) = vh;
      *(uint4*)(Plo + rowoff + 8 * t4) = vl;
    }
  }
  // P^T hi/lo
  {
    uint hw[16], lw[16];
#pragma unroll
    for (int t = 0; t < 16; ++t) {
      float p0 = uq[q][2 * t] * kt[2 * t] * vn;
      float p1 = uq[q][2 * t + 1] * kt[2 * t + 1] * vn;
      ushort h0 = f2bf(p0), h1 = f2bf(p1);
      hw[t] = (uint)h0 | ((uint)h1 << 16);
      lw[t] = (uint)f2bf(p0 - bf2f(h0)) | ((uint)f2bf(p1 - bf2f(h1)) << 16);
    }
#pragma unroll
    for (int t4 = 0; t4 < 4; ++t4) {
      uint4 vh = make_uint4(hw[4 * t4], hw[4 * t4 + 1], hw[4 * t4 + 2], hw[4 * t4 + 3]);
      uint4 vl = make_uint4(lw[4 * t4], lw[4 * t4 + 1], lw[4 * t4 + 2], lw[4 * t4 + 3]);
      *(uint4*)(PThi + rowoff + 8 * t4) = vh;
      *(uint4*)(PTlo + rowoff + 8 * t4) = vl;
    }
  }
}

// ---- K7: attend + compare + masked sum as MFMA GEMM (hi/lo 3-term) --------
// R8: revert to R6 single-pass (R7's 2-pass A/B-regressed 63.5->71.7; LDS
// halving left occupancy unchanged -> LDS wasn't the binder). NEW: the
// epilogue's 32 scattered main-row loads are ISSUED UP FRONT (mpre), right
// after the G-gather issues, so both ~900cy scatter latencies overlap under
// pack+barrier+frags+MFMA (T14 issue-early). A-fragments load in two halves
// (#pragma unroll 1) to cap VGPR (~110 peak vs ~140 naive; R2 lesson).
__global__ __launch_bounds__(256) void k_att_mfma(
    const ushort* __restrict__ Phi, const ushort* __restrict__ Plo,
    const ushort* __restrict__ PThi, const ushort* __restrict__ PTlo,
    const float* __restrict__ HcB, const int* __restrict__ row_idx,
    const int* __restrict__ col_idx, const int* __restrict__ row_len,
    const int* __restrict__ col_len, const float* __restrict__ bc,
    float* __restrict__ cr, float* __restrict__ cc) {
  int b = blockIdx.y;
  int side = blockIdx.z;
  int c0 = blockIdx.x * 64;
  const int* idx_main = side == 0 ? row_idx : col_idx;
  const int* idx_other = side == 0 ? col_idx : row_idx;
  int lm = side == 0 ? row_len[b] : col_len[b];
  int lo = side == 0 ? col_len[b] : row_len[b];
  const ushort* Ah = (side == 0 ? Phi : PThi) + (size_t)b * (NMAX * MMAX);
  const ushort* Al = (side == 0 ? Plo : PTlo) + (size_t)b * (NMAX * MMAX);
  float* outacc = side == 0 ? cr : cc;

  __shared__ __align__(16) ushort gldh[64][128];  // [d][k], 16B-blk swizzled
  __shared__ __align__(16) ushort gldl[64][128];
  __shared__ float red[4][64];
  __shared__ int iox[NMAX];
  __shared__ int imx[NMAX];

  int tid = threadIdx.x;
  int w = tid >> 6, lane = tid & 63;
  int q = lane >> 4, l16 = lane & 15;
  if (tid < 128) iox[tid] = idx_other[b * NMAX + tid];
  else imx[tid - 128] = idx_main[b * NMAX + tid - 128];
  __syncthreads();

  int nkc = (lo + 31) >> 5;  // K chunks of 32
  int ndt = (300 - c0 + 15) >> 4;
  if (ndt > 4) ndt = 4;
  bool dok = (c0 + lane) < 300;

  int i0a = w * 16;
  int i0b = 64 + w * 16;
  bool act0 = i0a < lm;
  bool act1 = i0b < lm;

  // ---- issue G gathers (lane = row d, wave w covers k in [32w,32w+32)) ----
  float gv[32];
#pragma unroll
  for (int t = 0; t < 32; ++t) {
    int k = w * 32 + t;
    gv[t] = (k < lo && dok) ? HcB[(size_t)iox[k] * 600 + 300 + c0 + lane]
                            : 0.f;
  }
  // ---- issue main-row prefetch: overlaps the G-gather latency -------------
  float mpre[2][4][4];
#pragma unroll
  for (int s = 0; s < 2; ++s) {
    int ib = ((s == 0) ? i0a : i0b) + q * 4;
#pragma unroll
    for (int r = 0; r < 4; ++r) {
      int i = ib + r;
      int hrow = imx[i];
#pragma unroll
      for (int dt = 0; dt < 4; ++dt) {
        int col = c0 + dt * 16 + l16;
        mpre[s][r][dt] =
            (i < lm && col < 300) ? HcB[(size_t)hrow * 600 + col] : 0.f;
      }
    }
  }
  float bcv[4];
#pragma unroll
  for (int dt = 0; dt < 4; ++dt) {
    int col = c0 + dt * 16 + l16;
    bcv[dt] = (col < 300) ? bc[col] : 0.f;
  }

  // ---- pack + swizzled store of G (waits gv; mpre stays in flight) --------
  if (w < nkc) {
#pragma unroll
    for (int blk = 0; blk < 4; ++blk) {
      int kb8 = 4 * w + blk;
      int phys = kb8 ^ (lane & 15);
      ushort hb[8], lb[8];
#pragma unroll
      for (int e = 0; e < 8; ++e) {
        float v = gv[blk * 8 + e];
        ushort h = f2bf(v);
        hb[e] = h;
        lb[e] = f2bf(v - bf2f(h));
      }
      *(uint4*)&gldh[lane][phys * 8] = *(uint4*)hb;
      *(uint4*)&gldl[lane][phys * 8] = *(uint4*)lb;
    }
  }
  __syncthreads();

  f32x4 zf = {0.f, 0.f, 0.f, 0.f};
  f32x4 acc0[4], acc1[4];
#pragma unroll
  for (int dt = 0; dt < 4; ++dt) { acc0[dt] = zf; acc1[dt] = zf; }

  // ---- MFMA in two chunk-halves to cap fragment liveness ------------------
#pragma unroll 1
  for (int ch = 0; ch < 2; ++ch) {
    if (ch * 2 >= nkc) break;
    bf16x8 f0h[2], f0l[2], f1h[2], f1l[2];
#pragma unroll
    for (int u = 0; u < 2; ++u) {
      int c = ch * 2 + u;
      if (c < nkc) {
        size_t oa = (size_t)(i0a + l16) * MMAX + 32 * c + 8 * q;
        size_t ob = (size_t)(i0b + l16) * MMAX + 32 * c + 8 * q;
        if (act0) {
          f0h[u] = *(const bf16x8*)&Ah[oa];
          f0l[u] = *(const bf16x8*)&Al[oa];
        }
        if (act1) {
          f1h[u] = *(const bf16x8*)&Ah[ob];
          f1l[u] = *(const bf16x8*)&Al[ob];
        }
      }
    }
#pragma unroll
    for (int u = 0; u < 2; ++u) {
      int c = ch * 2 + u;
      if (c < nkc) {
        int phys = (4 * c + q) ^ l16;  // swizzled 16B block index
#pragma unroll
        for (int dt = 0; dt < 4; ++dt) {
          if (dt < ndt) {
            int d = dt * 16 + l16;
            bf16x8 bh = *(const bf16x8*)&gldh[d][phys * 8];
            bf16x8 bl = *(const bf16x8*)&gldl[d][phys * 8];
            if (act0) {
              acc0[dt] = __builtin_amdgcn_mfma_f32_16x16x32_bf16(f0h[u], bh, acc0[dt], 0, 0, 0);
              acc0[dt] = __builtin_amdgcn_mfma_f32_16x16x32_bf16(f0h[u], bl, acc0[dt], 0, 0, 0);
              acc0[dt] = __builtin_amdgcn_mfma_f32_16x16x32_bf16(f0l[u], bh, acc0[dt], 0, 0, 0);
            }
            if (act1) {
              acc1[dt] = __builtin_amdgcn_mfma_f32_16x16x32_bf16(f1h[u], bh, acc1[dt], 0, 0, 0);
              acc1[dt] = __builtin_amdgcn_mfma_f32_16x16x32_bf16(f1h[u], bl, acc1[dt], 0, 0, 0);
              acc1[dt] = __builtin_amdgcn_mfma_f32_16x16x32_bf16(f1l[u], bh, acc1[dt], 0, 0, 0);
            }
          }
        }
      }
    }
  }

  // ---- epilogue: + main(prefetched) + bias, relu, column partial sums -----
  float psum[4] = {0.f, 0.f, 0.f, 0.f};
#pragma unroll
  for (int s = 0; s < 2; ++s) {
    bool act = (s == 0) ? act0 : act1;
    if (!act) continue;
    int ibase = ((s == 0) ? i0a : i0b) + q * 4;
#pragma unroll
    for (int r = 0; r < 4; ++r) {
      int i = ibase + r;
      if (i >= lm) continue;
#pragma unroll
      for (int dt = 0; dt < 4; ++dt) {
        int col = c0 + dt * 16 + l16;
        if (dt < ndt && col < 300) {
          float av = (s == 0) ? acc0[dt][r] : acc1[dt][r];
          float y = av + mpre[s][r][dt] + bcv[dt];
          psum[dt] += y > 0.f ? y : 0.f;
        }
      }
    }
  }
#pragma unroll
  for (int dt = 0; dt < 4; ++dt) {
    psum[dt] += __shfl_xor(psum[dt], 16, 64);
    psum[dt] += __shfl_xor(psum[dt], 32, 64);
  }
  if (lane < 16) {
#pragma unroll
    for (int dt = 0; dt < 4; ++dt) red[w][dt * 16 + lane] = psum[dt];
  }
  __syncthreads();
  if (tid < 64) {
    float s = red[0][tid] + red[1][tid] + red[2][tid] + red[3][tid];
    int col = c0 + tid;
    if (col < 300) outacc[(size_t)b * HDIM + col] = s;
  }
}

// ---------------- K8: classifier head -> out [B,2] -------------------------
__global__ __launch_bounds__(320) void k_cls(
    const float* __restrict__ cr, const float* __restrict__ cc,
    const float* __restrict__ Wcls, const float* __restrict__ bcls,
    const float* __restrict__ Wout, const float* __restrict__ bout,
    float* __restrict__ out) {
  __shared__ __align__(16) float cz[2 * HDIM];
  __shared__ float zz[HDIM];
  int b = blockIdx.x, tid = threadIdx.x;
  if (tid < HDIM) {
    cz[tid] = cr[(size_t)b * HDIM + tid];
    cz[HDIM + tid] = cc[(size_t)b * HDIM + tid];
  }
  __syncthreads();
  if (tid < HDIM) {
    float acc = bcls[tid];
    for (int k4 = 0; k4 < 2 * HDIM; k4 += 4) {
      float4 c = *(const float4*)&cz[k4];
      acc += c.x * Wcls[(size_t)(k4 + 0) * HDIM + tid] +
             c.y * Wcls[(size_t)(k4 + 1) * HDIM + tid] +
             c.z * Wcls[(size_t)(k4 + 2) * HDIM + tid] +
             c.w * Wcls[(size_t)(k4 + 3) * HDIM + tid];
    }
    zz[tid] = acc > 0.f ? acc : 0.f;
  }
  __syncthreads();
  int o = tid >> 6, lane = tid & 63;
  if (o < 2) {
    float p = 0.f;
    for (int j = lane; j < HDIM; j += 64) p += zz[j] * Wout[(size_t)j * 2 + o];
#pragma unroll
    for (int off = 32; off > 0; off >>= 1) p += __shfl_down(p, off, 64);
    if (lane == 0) out[b * 2 + o] = p + bout[o];
  }
}

extern "C" void kernel_launch(void* const* d_in, const int* in_sizes, int n_in,
                              void* d_out, int out_size, void* d_ws, size_t ws_size,
                              hipStream_t stream) {
  (void)in_sizes; (void)n_in; (void)out_size; (void)ws_size;
  const int* data = (const int*)d_in[0];
  const int* row_idx = (const int*)d_in[1];
  const int* col_idx = (const int*)d_in[2];
  const int* row_len = (const int*)d_in[3];
  const int* col_len = (const int*)d_in[4];
  const float* emb = (const float*)d_in[5];
  const float* W1 = (const float*)d_in[6];
  const float* b1 = (const float*)d_in[7];
  const float* W2 = (const float*)d_in[8];
  const float* b2 = (const float*)d_in[9];
  const float* Wc = (const float*)d_in[10];
  const float* bc = (const float*)d_in[11];
  const float* Wcls = (const float*)d_in[12];
  const float* bcls = (const float*)d_in[13];
  const float* Wout = (const float*)d_in[14];
  const float* bout = (const float*)d_in[15];
  float* out = (float*)d_out;

  char* wp = (char*)d_ws;
  auto carve = [&](size_t bytes) {
    char* p = wp; wp += (bytes + 255) & ~(size_t)255; return p;
  };
  ushort* enchi = (ushort*)carve((size_t)NS * KPAD * 2);
  ushort* enclo = (ushort*)carve((size_t)NS * KPAD * 2);
  ushort* h1hi = (ushort*)carve((size_t)NS * KPAD * 2);
  ushort* h1lo = (ushort*)carve((size_t)NS * KPAD * 2);
  ushort* hehi = (ushort*)carve((size_t)NS * KPAD * 2);
  ushort* helo = (ushort*)carve((size_t)NS * KPAD * 2);
  ushort* hnhi = (ushort*)carve((size_t)NS * KPAD * 2);
  ushort* hnlo = (ushort*)carve((size_t)NS * KPAD * 2);
  ushort* W1hi = (ushort*)carve((size_t)NPADW * KPAD * 2);
  ushort* W1lo = (ushort*)carve((size_t)NPADW * KPAD * 2);
  ushort* W2hi = (ushort*)carve((size_t)NPADW * KPAD * 2);
  ushort* W2lo = (ushort*)carve((size_t)NPADW * KPAD * 2);
  ushort* Wchi = (ushort*)carve((size_t)640 * KPAD * 2);
  ushort* Wclo = (ushort*)carve((size_t)640 * KPAD * 2);
  float* HcB = (float*)carve((size_t)NS * 600 * 4);
  float* Km = (float*)carve((size_t)BB * NMAX * MMAX * 4);
  float* cr = (float*)carve((size_t)BB * HDIM * 4);
  float* cc = (float*)carve((size_t)BB * HDIM * 4);

  // bf16 hi/lo P and P^T alias buffers that are DEAD by k_sinkhorn time.
  ushort* Phi = enchi;
  ushort* Plo = h1hi;
  ushort* PThi = hehi;
  ushort* PTlo = hnhi;

  int gM = (NS + 63) / 64;  // 157
  int cvtTotal = 2 * NPADW * KPAD + 640 * KPAD;

  k_embed<<<NS, 256, 0, stream>>>(data, emb, enchi, enclo);
  k_cvt_all<<<(cvtTotal + 255) / 256, 256, 0, stream>>>(
      W1, W2, Wc, W1hi, W1lo, W2hi, W2lo, Wchi, Wclo);
  k_gemm_mfma<<<dim3(gM, 3), 256, 0, stream>>>(
      enchi, enclo, W1hi, W1lo, b1, NS, HDIM, 1, nullptr, h1hi, h1lo);
  k_gemm_mfma<<<dim3(gM, 3), 256, 0, stream>>>(
      h1hi, h1lo, W2hi, W2lo, b2, NS, HDIM, 1, nullptr, hehi, helo);
  k_norm_split<<<(NS + 3) / 4, 256, 0, stream>>>(hehi, helo, hnhi, hnlo);
  k_gemm_mfma<<<dim3(gM, 5), 256, 0, stream>>>(
      hehi, helo, Wchi, Wclo, nullptr, NS, 2 * HDIM, 0, HcB, nullptr, nullptr);
  k_cost_mfma<<<dim3(2, 2, BB), 256, 0, stream>>>(hnhi, hnlo, row_idx, col_idx,
                                                  row_len, col_len, Km);
  k_sinkhorn<<<BB, 512, 0, stream>>>(Km, row_len, col_len, Phi, Plo, PThi, PTlo);
  k_att_mfma<<<dim3(5, BB, 2), 256, 0, stream>>>(
      Phi, Plo, PThi, PTlo, HcB, row_idx, col_idx, row_len, col_len, bc, cr, cc);
  k_cls<<<BB, 320, 0, stream>>>(cr, cc, Wcls, bcls, Wout, bout, out);
}